// Round 1
// baseline (807.042 us; speedup 1.0000x reference)
//
#include <hip/hip_runtime.h>
#include <math.h>

#define HD 64
#define HNUM 128
#define NMLP 2

__device__ __forceinline__ float lrelu(float x){ return fmaxf(x, 0.2f*x); }

// ---------------- CSR build ----------------
__global__ __launch_bounds__(256) void k_hist(const int* __restrict__ dst, int* __restrict__ cnt, int E){
    int e = blockIdx.x*256 + threadIdx.x;
    if(e < E) atomicAdd(&cnt[dst[e]], 1);
}

__global__ __launch_bounds__(1024) void k_scan1(const int* __restrict__ deg, int* __restrict__ rp1,
                                                int* __restrict__ bsum, int n){
    __shared__ int s[1024];
    int t = threadIdx.x;
    int i = blockIdx.x*1024 + t;
    int v = (i < n) ? deg[i] : 0;
    s[t] = v; __syncthreads();
    for(int o=1;o<1024;o<<=1){
        int u = (t >= o) ? s[t-o] : 0;
        __syncthreads();
        s[t] += u;
        __syncthreads();
    }
    if(i < n) rp1[i] = s[t];              // inclusive scan -> rowptr[i+1]
    if(t == 1023) bsum[blockIdx.x] = s[t];
}

__global__ __launch_bounds__(1024) void k_scan2(int* __restrict__ bsum, int nb){
    __shared__ int s[1024];
    int t = threadIdx.x;
    int v = (t < nb) ? bsum[t] : 0;
    s[t] = v; __syncthreads();
    for(int o=1;o<1024;o<<=1){
        int u = (t >= o) ? s[t-o] : 0;
        __syncthreads();
        s[t] += u;
        __syncthreads();
    }
    if(t < nb) bsum[t] = (t > 0) ? s[t-1] : 0;   // exclusive block offsets
}

__global__ __launch_bounds__(1024) void k_scan3(int* __restrict__ rp, const int* __restrict__ boff, int n){
    int i = blockIdx.x*1024 + threadIdx.x;
    if(i < n) rp[i+1] += boff[blockIdx.x];
    if(i == 0) rp[0] = 0;
}

__global__ __launch_bounds__(256) void k_scatter(const int* __restrict__ src, const int* __restrict__ dst,
                                                 const int* __restrict__ rp, int* __restrict__ fill,
                                                 int* __restrict__ col, int E){
    int e = blockIdx.x*256 + threadIdx.x;
    if(e < E){
        int d = dst[e];
        int pos = rp[d] + atomicAdd(&fill[d], 1);
        col[pos] = src[e];
    }
}

// ---------------- fused GEMM (h = IN @ W) + attention scalars ----------------
// wave-per-row; addrow: uniform row add (vn broadcast); addtab: gathered row add (vn table)
__global__ __launch_bounds__(256) void k_gemm(
    const float* __restrict__ IN, const float* __restrict__ addrow,
    const float* __restrict__ addtab, const int* __restrict__ hb,
    const float* __restrict__ W, const float* __restrict__ asr,
    const float* __restrict__ adt, float* __restrict__ Hout,
    float* __restrict__ AS, float* __restrict__ AD, int n)
{
    __shared__ float sW[HD*HD];
    int t = threadIdx.x;
    #pragma unroll
    for(int i=0;i<16;i++) sW[t + 256*i] = W[t + 256*i];
    __syncthreads();
    int row = blockIdx.x*4 + (t>>6);
    if(row >= n) return;
    int lane = t & 63;
    float xv = IN[(size_t)row*HD + lane];
    if(addrow) xv += addrow[lane];
    if(addtab) xv += addtab[hb[row]*HD + lane];
    float acc = 0.f;
    #pragma unroll
    for(int k=0;k<HD;k++) acc = fmaf(__shfl(xv, k, 64), sW[k*HD + lane], acc);
    Hout[(size_t)row*HD + lane] = acc;
    float t1 = acc*asr[lane], t2 = acc*adt[lane];
    #pragma unroll
    for(int o=32;o;o>>=1){ t1 += __shfl_xor(t1,o,64); t2 += __shfl_xor(t2,o,64); }
    if(lane == 0){ AS[row] = t1; AD[row] = t2; }
}

// ---------------- wave-per-dst GAT aggregate with online softmax ----------------
__global__ __launch_bounds__(256) void k_agg(
    const float* __restrict__ H, const float* __restrict__ AS, const float* __restrict__ AD,
    const int* __restrict__ rp, const int* __restrict__ col,
    const float* __restrict__ bias, float* __restrict__ OUT, int n)
{
    int t = threadIdx.x, lane = t & 63;
    int dst = blockIdx.x*4 + (t>>6);
    if(dst >= n) return;
    float ad = AD[dst];
    float e0 = lrelu(AS[dst] + ad);       // self loop
    float m = e0, s = 1.f;
    float acc = H[(size_t)dst*HD + lane]; // w_self = exp(e0 - m) = 1
    int beg = rp[dst], end = rp[dst+1];
    for(int base = beg; base < end; base += 64){
        int j = base + lane;
        int sj = 0; float ej = -INFINITY;
        if(j < end){ sj = col[j]; ej = lrelu(AS[sj] + ad); }
        float mc = ej;
        #pragma unroll
        for(int o=32;o;o>>=1) mc = fmaxf(mc, __shfl_xor(mc,o,64));
        float mn = fmaxf(m, mc);
        float r  = __expf(m - mn);
        float wj = (j < end) ? __expf(ej - mn) : 0.f;
        float sc = wj;
        #pragma unroll
        for(int o=32;o;o>>=1) sc += __shfl_xor(sc,o,64);
        s = s*r + sc;
        acc *= r;
        int cnt = min(64, end - base);
        int q = 0;
        for(; q + 4 <= cnt; q += 4){
            float w0=__shfl(wj,q,64), w1=__shfl(wj,q+1,64), w2=__shfl(wj,q+2,64), w3=__shfl(wj,q+3,64);
            int   s0=__shfl(sj,q,64), s1=__shfl(sj,q+1,64), s2=__shfl(sj,q+2,64), s3=__shfl(sj,q+3,64);
            float h0 = H[(size_t)s0*HD + lane];
            float h1 = H[(size_t)s1*HD + lane];
            float h2 = H[(size_t)s2*HD + lane];
            float h3 = H[(size_t)s3*HD + lane];
            acc = fmaf(w0,h0, fmaf(w1,h1, fmaf(w2,h2, fmaf(w3,h3, acc))));
        }
        for(; q < cnt; q++){
            float wq = __shfl(wj,q,64);
            int   sq = __shfl(sj,q,64);
            acc = fmaf(wq, H[(size_t)sq*HD + lane], acc);
        }
        m = mn;
    }
    OUT[(size_t)dst*HD + lane] = acc/(s + 1e-16f) + bias[lane];
}

// ---------------- virtual-node segment sum (LDS-staged atomics) ----------------
__global__ __launch_bounds__(256) void k_vnseg(const float* __restrict__ OUT, const int* __restrict__ hb,
                                               float* __restrict__ vnS, int n){
    __shared__ float acc[HNUM*HD];
    int t = threadIdx.x;
    for(int i=t;i<HNUM*HD;i+=256) acc[i] = 0.f;
    __syncthreads();
    int total = n*HD;
    for(int idx = blockIdx.x*256 + t; idx < total; idx += gridDim.x*256){
        int node = idx >> 6, c = idx & 63;
        atomicAdd(&acc[hb[node]*HD + c], OUT[idx]);
    }
    __syncthreads();
    for(int i=t;i<HNUM*HD;i+=256) atomicAdd(&vnS[i], acc[i]);
}

// ---------------- vn update + both MLPs, fully in registers ----------------
// grid: 8 blocks x 256 -> 32 waves, 4 rows each (HNUM=128)
__global__ __launch_bounds__(256) void k_vn(
    const float* __restrict__ vnS, const float* __restrict__ vne,
    const float* __restrict__ W1, const float* __restrict__ B1,
    const float* __restrict__ W2, const float* __restrict__ B2,
    float* __restrict__ vnD)
{
    int lane = threadIdx.x & 63;
    int w = (blockIdx.x*256 + threadIdx.x) >> 6;   // 0..31
    const int R = HNUM/32;                         // 4 rows per wave
    float a[R], br[R];
    float ve = vne[lane];
    #pragma unroll
    for(int r=0;r<R;r++){
        int b = w*R + r;
        // vn_direct = segsum + vn_direct0 + vn_root0 = vnS + vne + vne
        a[r] = vnS[b*HD + lane] + ve + ve;
    }
    for(int j=0;j<NMLP;j++){
        const float* w1 = W1 + j*HD*HD; const float* b1 = B1 + j*HD;
        const float* w2 = W2 + j*HD*HD; const float* b2 = B2 + j*HD;
        #pragma unroll
        for(int r=0;r<R;r++){
            float tacc = b1[lane];
            #pragma unroll
            for(int in=0;in<HD;in++) tacc = fmaf(__shfl(a[r], in, 64), w1[in*HD + lane], tacc);
            br[r] = fmaxf(tacc, 0.f);
        }
        #pragma unroll
        for(int r=0;r<R;r++){
            float tacc = b2[lane];
            #pragma unroll
            for(int in=0;in<HD;in++) tacc = fmaf(__shfl(br[r], in, 64), w2[in*HD + lane], tacc);
            a[r] = fmaxf(tacc, 0.f);
        }
    }
    #pragma unroll
    for(int r=0;r<R;r++){
        int b = w*R + r;
        vnD[b*HD + lane] = a[r];
    }
}

extern "C" void kernel_launch(void* const* d_in, const int* in_sizes, int n_in,
                              void* d_out, int out_size, void* d_ws, size_t ws_size,
                              hipStream_t stream)
{
    const float* x   = (const float*)d_in[0];
    const int*   ei  = (const int*)d_in[1];
    const int*   hb  = (const int*)d_in[2];
    const float* W0  = (const float*)d_in[5];
    const float* as0 = (const float*)d_in[6];
    const float* ad0 = (const float*)d_in[7];
    const float* b0  = (const float*)d_in[8];
    const float* Wl  = (const float*)d_in[9];
    const float* asl = (const float*)d_in[10];
    const float* adl = (const float*)d_in[11];
    const float* bl  = (const float*)d_in[12];
    const float* vne = (const float*)d_in[13];
    const float* mW1 = (const float*)d_in[14];
    const float* mb1 = (const float*)d_in[15];
    const float* mW2 = (const float*)d_in[16];
    const float* mb2 = (const float*)d_in[17];

    int N = in_sizes[0]/HD;
    int E = in_sizes[1]/2;
    const int* src = ei;
    const int* dst = ei + E;

    char* p = (char*)d_ws;
    float* f_h   = (float*)p; p += (size_t)N*HD*4;
    float* f_as  = (float*)p; p += (size_t)N*4;
    float* f_ad  = (float*)p; p += (size_t)N*4;
    float* f_vnD = (float*)p; p += HNUM*HD*4;
    float* f_vnS = (float*)p; p += HNUM*HD*4;
    int*   i_rp  = (int*)p;   p += (size_t)(N+1)*4;
    int*   i_fill= (int*)p;   p += (size_t)N*4;
    int*   i_col = (int*)p;   p += (size_t)E*4;
    int*   i_bs  = (int*)p;   p += 4096;

    float* outb = (float*)d_out;   // ping buffer for conv outputs

    int nb = (N + 1023)/1024;
    // CSR by destination
    hipMemsetAsync(i_fill, 0, (size_t)N*4, stream);
    k_hist<<<(E+255)/256, 256, 0, stream>>>(dst, i_fill, E);
    k_scan1<<<nb, 1024, 0, stream>>>(i_fill, i_rp + 1, i_bs, N);
    k_scan2<<<1, 1024, 0, stream>>>(i_bs, nb);
    k_scan3<<<nb, 1024, 0, stream>>>(i_rp, i_bs, N);
    hipMemsetAsync(i_fill, 0, (size_t)N*4, stream);
    k_scatter<<<(E+255)/256, 256, 0, stream>>>(src, dst, i_rp, i_fill, i_col, E);

    int gn = (N + 3)/4;
    // conv0: GAT(x, W0)
    k_gemm<<<gn, 256, 0, stream>>>(x, nullptr, nullptr, hb, W0, as0, ad0, f_h, f_as, f_ad, N);
    k_agg <<<gn, 256, 0, stream>>>(f_h, f_as, f_ad, i_rp, i_col, b0, outb, N);
    // conv1: GAT(out0 + vn_emb, Wl[0])   (vn_direct0 is a broadcast of vn_emb)
    k_gemm<<<gn, 256, 0, stream>>>(outb, vne, nullptr, hb, Wl, asl, adl, f_h, f_as, f_ad, N);
    k_agg <<<gn, 256, 0, stream>>>(f_h, f_as, f_ad, i_rp, i_col, bl, outb, N);
    // vn update after conv1 (the only live one): vnD = MLPs(segsum(out1) + 2*vne)
    hipMemsetAsync(f_vnS, 0, HNUM*HD*4, stream);
    k_vnseg<<<256, 256, 0, stream>>>(outb, hb, f_vnS, N);
    k_vn  <<<8, 256, 0, stream>>>(f_vnS, vne, mW1, mb1, mW2, mb2, f_vnD);
    // conv2: GAT(out1 + vnD[hb], Wl[1])  -> final output
    k_gemm<<<gn, 256, 0, stream>>>(outb, nullptr, f_vnD, hb, Wl + HD*HD, asl + HD, adl + HD, f_h, f_as, f_ad, N);
    k_agg <<<gn, 256, 0, stream>>>(f_h, f_as, f_ad, i_rp, i_col, bl + HD, outb, N);
}

// Round 2
// 755.208 us; speedup vs baseline: 1.0686x; 1.0686x over previous
//
#include <hip/hip_runtime.h>
#include <math.h>

#define HD 64
#define HNUM 128
#define NMLP 2

__device__ __forceinline__ float lrelu(float x){ return fmaxf(x, 0.2f*x); }

// ---------------- CSR build ----------------
__global__ __launch_bounds__(256) void k_hist(const int* __restrict__ dst, int* __restrict__ cnt, int E){
    int e = blockIdx.x*256 + threadIdx.x;
    if(e < E) atomicAdd(&cnt[dst[e]], 1);
}

__global__ __launch_bounds__(1024) void k_scan1(const int* __restrict__ deg, int* __restrict__ rp1,
                                                int* __restrict__ bsum, int n){
    __shared__ int s[1024];
    int t = threadIdx.x;
    int i = blockIdx.x*1024 + t;
    int v = (i < n) ? deg[i] : 0;
    s[t] = v; __syncthreads();
    for(int o=1;o<1024;o<<=1){
        int u = (t >= o) ? s[t-o] : 0;
        __syncthreads();
        s[t] += u;
        __syncthreads();
    }
    if(i < n) rp1[i] = s[t];              // inclusive scan -> rowptr[i+1]
    if(t == 1023) bsum[blockIdx.x] = s[t];
}

__global__ __launch_bounds__(1024) void k_scan2(int* __restrict__ bsum, int nb){
    __shared__ int s[1024];
    int t = threadIdx.x;
    int v = (t < nb) ? bsum[t] : 0;
    s[t] = v; __syncthreads();
    for(int o=1;o<1024;o<<=1){
        int u = (t >= o) ? s[t-o] : 0;
        __syncthreads();
        s[t] += u;
        __syncthreads();
    }
    if(t < nb) bsum[t] = (t > 0) ? s[t-1] : 0;   // exclusive block offsets
}

__global__ __launch_bounds__(1024) void k_scan3(int* __restrict__ rp, const int* __restrict__ boff, int n){
    int i = blockIdx.x*1024 + threadIdx.x;
    if(i < n) rp[i+1] += boff[blockIdx.x];
    if(i == 0) rp[0] = 0;
}

__global__ __launch_bounds__(256) void k_scatter(const int* __restrict__ src, const int* __restrict__ dst,
                                                 const int* __restrict__ rp, int* __restrict__ fill,
                                                 int* __restrict__ col, int E){
    int e = blockIdx.x*256 + threadIdx.x;
    if(e < E){
        int d = dst[e];
        int pos = rp[d] + atomicAdd(&fill[d], 1);
        col[pos] = src[e];
    }
}

// ---------------- fused GEMM (h = IN @ W) + attention scalars ----------------
// W column per lane held in 64 VGPRs; grid-stride over rows; 2 rows x 2 chains ILP.
__global__ __launch_bounds__(256) void k_gemm(
    const float* __restrict__ IN, const float* __restrict__ addrow,
    const float* __restrict__ addtab, const int* __restrict__ hb,
    const float* __restrict__ W, const float* __restrict__ asr,
    const float* __restrict__ adt, float* __restrict__ Hout,
    float* __restrict__ AS, float* __restrict__ AD, int n)
{
    int lane = threadIdx.x & 63;
    float w[HD];
    #pragma unroll
    for(int k=0;k<HD;k++) w[k] = W[k*HD + lane];   // coalesced: wave reads 256B/iter
    float vas = asr[lane], vad = adt[lane];
    float ar = addrow ? addrow[lane] : 0.f;

    int wid = (blockIdx.x*256 + threadIdx.x) >> 6;
    int nw  = gridDim.x*4;
    for(int row = wid*2; row < n; row += nw*2){
        int r1ok = (row + 1 < n);
        float x0 = IN[(size_t)row*HD + lane] + ar;
        float x1 = r1ok ? (IN[(size_t)(row+1)*HD + lane] + ar) : 0.f;
        if(addtab){
            x0 += addtab[hb[row]*HD + lane];
            if(r1ok) x1 += addtab[hb[row+1]*HD + lane];
        }
        float a0=0.f, b0=0.f, a1=0.f, b1=0.f;   // 4 independent FMA chains
        #pragma unroll
        for(int k=0;k<HD;k+=2){
            float s00 = __shfl(x0, k,   64);
            float s01 = __shfl(x0, k+1, 64);
            float s10 = __shfl(x1, k,   64);
            float s11 = __shfl(x1, k+1, 64);
            a0 = fmaf(s00, w[k],   a0);
            b0 = fmaf(s01, w[k+1], b0);
            a1 = fmaf(s10, w[k],   a1);
            b1 = fmaf(s11, w[k+1], b1);
        }
        float h0 = a0 + b0, h1 = a1 + b1;

        Hout[(size_t)row*HD + lane] = h0;
        float t1 = h0*vas, t2 = h0*vad;
        #pragma unroll
        for(int o=32;o;o>>=1){ t1 += __shfl_xor(t1,o,64); t2 += __shfl_xor(t2,o,64); }
        if(lane == 0){ AS[row] = t1; AD[row] = t2; }

        if(r1ok){
            Hout[(size_t)(row+1)*HD + lane] = h1;
            float u1 = h1*vas, u2 = h1*vad;
            #pragma unroll
            for(int o=32;o;o>>=1){ u1 += __shfl_xor(u1,o,64); u2 += __shfl_xor(u2,o,64); }
            if(lane == 0){ AS[row+1] = u1; AD[row+1] = u2; }
        }
    }
}

// ---------------- wave-per-dst GAT aggregate with online softmax ----------------
__global__ __launch_bounds__(256) void k_agg(
    const float* __restrict__ H, const float* __restrict__ AS, const float* __restrict__ AD,
    const int* __restrict__ rp, const int* __restrict__ col,
    const float* __restrict__ bias, float* __restrict__ OUT, int n)
{
    int t = threadIdx.x, lane = t & 63;
    int dst = blockIdx.x*4 + (t>>6);
    if(dst >= n) return;
    float ad = AD[dst];
    float e0 = lrelu(AS[dst] + ad);       // self loop
    float m = e0, s = 1.f;
    float acc = H[(size_t)dst*HD + lane]; // w_self = exp(e0 - m) = 1
    int beg = rp[dst], end = rp[dst+1];
    for(int base = beg; base < end; base += 64){
        int j = base + lane;
        int sj = 0; float ej = -INFINITY;
        if(j < end){ sj = col[j]; ej = lrelu(AS[sj] + ad); }
        float mc = ej;
        #pragma unroll
        for(int o=32;o;o>>=1) mc = fmaxf(mc, __shfl_xor(mc,o,64));
        float mn = fmaxf(m, mc);
        float r  = __expf(m - mn);
        float wj = (j < end) ? __expf(ej - mn) : 0.f;
        float sc = wj;
        #pragma unroll
        for(int o=32;o;o>>=1) sc += __shfl_xor(sc,o,64);
        s = s*r + sc;
        acc *= r;
        int cnt = min(64, end - base);
        int q = 0;
        for(; q + 4 <= cnt; q += 4){
            float w0=__shfl(wj,q,64), w1=__shfl(wj,q+1,64), w2=__shfl(wj,q+2,64), w3=__shfl(wj,q+3,64);
            int   s0=__shfl(sj,q,64), s1=__shfl(sj,q+1,64), s2=__shfl(sj,q+2,64), s3=__shfl(sj,q+3,64);
            float h0 = H[(size_t)s0*HD + lane];
            float h1 = H[(size_t)s1*HD + lane];
            float h2 = H[(size_t)s2*HD + lane];
            float h3 = H[(size_t)s3*HD + lane];
            acc = fmaf(w0,h0, fmaf(w1,h1, fmaf(w2,h2, fmaf(w3,h3, acc))));
        }
        for(; q < cnt; q++){
            float wq = __shfl(wj,q,64);
            int   sq = __shfl(sj,q,64);
            acc = fmaf(wq, H[(size_t)sq*HD + lane], acc);
        }
        m = mn;
    }
    OUT[(size_t)dst*HD + lane] = acc/(s + 1e-16f) + bias[lane];
}

// ---------------- virtual-node segment sum (LDS-staged atomics) ----------------
__global__ __launch_bounds__(256) void k_vnseg(const float* __restrict__ OUT, const int* __restrict__ hb,
                                               float* __restrict__ vnS, int n){
    __shared__ float acc[HNUM*HD];
    int t = threadIdx.x;
    for(int i=t;i<HNUM*HD;i+=256) acc[i] = 0.f;
    __syncthreads();
    int total = n*HD;
    for(int idx = blockIdx.x*256 + t; idx < total; idx += gridDim.x*256){
        int node = idx >> 6, c = idx & 63;
        atomicAdd(&acc[hb[node]*HD + c], OUT[idx]);
    }
    __syncthreads();
    for(int i=t;i<HNUM*HD;i+=256) atomicAdd(&vnS[i], acc[i]);
}

// ---------------- vn update + both MLPs, fully in registers ----------------
__global__ __launch_bounds__(256) void k_vn(
    const float* __restrict__ vnS, const float* __restrict__ vne,
    const float* __restrict__ W1, const float* __restrict__ B1,
    const float* __restrict__ W2, const float* __restrict__ B2,
    float* __restrict__ vnD)
{
    int lane = threadIdx.x & 63;
    int w = (blockIdx.x*256 + threadIdx.x) >> 6;   // 0..31
    const int R = HNUM/32;                         // 4 rows per wave
    float a[R], br[R];
    float ve = vne[lane];
    #pragma unroll
    for(int r=0;r<R;r++){
        int b = w*R + r;
        a[r] = vnS[b*HD + lane] + ve + ve;   // segsum + vn_direct0 + vn_root0
    }
    for(int j=0;j<NMLP;j++){
        const float* w1 = W1 + j*HD*HD; const float* b1 = B1 + j*HD;
        const float* w2 = W2 + j*HD*HD; const float* b2 = B2 + j*HD;
        #pragma unroll
        for(int r=0;r<R;r++){
            float tacc = b1[lane];
            #pragma unroll
            for(int in=0;in<HD;in++) tacc = fmaf(__shfl(a[r], in, 64), w1[in*HD + lane], tacc);
            br[r] = fmaxf(tacc, 0.f);
        }
        #pragma unroll
        for(int r=0;r<R;r++){
            float tacc = b2[lane];
            #pragma unroll
            for(int in=0;in<HD;in++) tacc = fmaf(__shfl(br[r], in, 64), w2[in*HD + lane], tacc);
            a[r] = fmaxf(tacc, 0.f);
        }
    }
    #pragma unroll
    for(int r=0;r<R;r++){
        int b = w*R + r;
        vnD[b*HD + lane] = a[r];
    }
}

extern "C" void kernel_launch(void* const* d_in, const int* in_sizes, int n_in,
                              void* d_out, int out_size, void* d_ws, size_t ws_size,
                              hipStream_t stream)
{
    const float* x   = (const float*)d_in[0];
    const int*   ei  = (const int*)d_in[1];
    const int*   hb  = (const int*)d_in[2];
    const float* W0  = (const float*)d_in[5];
    const float* as0 = (const float*)d_in[6];
    const float* ad0 = (const float*)d_in[7];
    const float* b0  = (const float*)d_in[8];
    const float* Wl  = (const float*)d_in[9];
    const float* asl = (const float*)d_in[10];
    const float* adl = (const float*)d_in[11];
    const float* bl  = (const float*)d_in[12];
    const float* vne = (const float*)d_in[13];
    const float* mW1 = (const float*)d_in[14];
    const float* mb1 = (const float*)d_in[15];
    const float* mW2 = (const float*)d_in[16];
    const float* mb2 = (const float*)d_in[17];

    int N = in_sizes[0]/HD;
    int E = in_sizes[1]/2;
    const int* src = ei;
    const int* dst = ei + E;

    char* p = (char*)d_ws;
    float* f_h   = (float*)p; p += (size_t)N*HD*4;
    float* f_as  = (float*)p; p += (size_t)N*4;
    float* f_ad  = (float*)p; p += (size_t)N*4;
    float* f_vnD = (float*)p; p += HNUM*HD*4;
    float* f_vnS = (float*)p; p += HNUM*HD*4;
    int*   i_rp  = (int*)p;   p += (size_t)(N+1)*4;
    int*   i_fill= (int*)p;   p += (size_t)N*4;
    int*   i_col = (int*)p;   p += (size_t)E*4;
    int*   i_bs  = (int*)p;   p += 4096;

    float* outb = (float*)d_out;   // ping buffer for conv outputs

    int nb = (N + 1023)/1024;
    // CSR by destination
    hipMemsetAsync(i_fill, 0, (size_t)N*4, stream);
    k_hist<<<(E+255)/256, 256, 0, stream>>>(dst, i_fill, E);
    k_scan1<<<nb, 1024, 0, stream>>>(i_fill, i_rp + 1, i_bs, N);
    k_scan2<<<1, 1024, 0, stream>>>(i_bs, nb);
    k_scan3<<<nb, 1024, 0, stream>>>(i_rp, i_bs, N);
    hipMemsetAsync(i_fill, 0, (size_t)N*4, stream);
    k_scatter<<<(E+255)/256, 256, 0, stream>>>(src, dst, i_rp, i_fill, i_col, E);

    int gn = (N + 3)/4;
    int gg = 1024;   // grid-stride gemm: 4096 waves, ~24 rows/wave
    // conv0: GAT(x, W0)
    k_gemm<<<gg, 256, 0, stream>>>(x, nullptr, nullptr, hb, W0, as0, ad0, f_h, f_as, f_ad, N);
    k_agg <<<gn, 256, 0, stream>>>(f_h, f_as, f_ad, i_rp, i_col, b0, outb, N);
    // conv1: GAT(out0 + vn_emb, Wl[0])   (vn_direct0 is a broadcast of vn_emb)
    k_gemm<<<gg, 256, 0, stream>>>(outb, vne, nullptr, hb, Wl, asl, adl, f_h, f_as, f_ad, N);
    k_agg <<<gn, 256, 0, stream>>>(f_h, f_as, f_ad, i_rp, i_col, bl, outb, N);
    // vn update after conv1 (the only live one): vnD = MLPs(segsum(out1) + 2*vne)
    hipMemsetAsync(f_vnS, 0, HNUM*HD*4, stream);
    k_vnseg<<<256, 256, 0, stream>>>(outb, hb, f_vnS, N);
    k_vn  <<<8, 256, 0, stream>>>(f_vnS, vne, mW1, mb1, mW2, mb2, f_vnD);
    // conv2: GAT(out1 + vnD[hb], Wl[1])  -> final output
    k_gemm<<<gg, 256, 0, stream>>>(outb, nullptr, f_vnD, hb, Wl + HD*HD, asl + HD, adl + HD, f_h, f_as, f_ad, N);
    k_agg <<<gn, 256, 0, stream>>>(f_h, f_as, f_ad, i_rp, i_col, bl + HD, outb, N);
}

// Round 3
// 571.846 us; speedup vs baseline: 1.4113x; 1.3206x over previous
//
#include <hip/hip_runtime.h>
#include <math.h>

#define HD 64
#define HNUM 128
#define NMLP 2
#define BSH 8              // 256 dst-nodes per bucket
#define MAXNB 512
#define EPB 2048           // edges per k_bin block

__device__ __forceinline__ float lrelu(float x){ return fmaxf(x, 0.2f*x); }

// ---------------- CSR build: bucketed counting sort ----------------
// count edges per bucket (LDS hist -> global)
__global__ __launch_bounds__(256) void k_bcnt(const int* __restrict__ dst, int* __restrict__ gb,
                                              int E, int NB){
    __shared__ int h[MAXNB];
    int t = threadIdx.x;
    for(int i=t;i<NB;i+=256) h[i] = 0;
    __syncthreads();
    for(int e = blockIdx.x*256 + t; e < E; e += gridDim.x*256)
        atomicAdd(&h[dst[e]>>BSH], 1);
    __syncthreads();
    for(int i=t;i<NB;i+=256) if(h[i]) atomicAdd(&gb[i], h[i]);
}

// exclusive scan of bucket counts -> bucket bases + write cursors
__global__ __launch_bounds__(512) void k_bscan(const int* __restrict__ gb, int* __restrict__ bbase,
                                               int* __restrict__ gcur, int NB){
    __shared__ int s[512];
    int t = threadIdx.x;
    int v = (t < NB) ? gb[t] : 0;
    s[t] = v; __syncthreads();
    for(int o=1;o<512;o<<=1){
        int u = (t >= o) ? s[t-o] : 0;
        __syncthreads();
        s[t] += u;
        __syncthreads();
    }
    if(t < NB){ int ex = s[t] - v; bbase[t] = ex; gcur[t] = ex; }
}

// bin edges: per-block LDS counts, one cursor claim per bucket, grouped writes
__global__ __launch_bounds__(256) void k_bin(const int* __restrict__ src, const int* __restrict__ dst,
                                             int* __restrict__ gcur, int2* __restrict__ bdata,
                                             int E, int NB){
    __shared__ int cnt[MAXNB];
    __shared__ int base[MAXNB];
    int t = threadIdx.x;
    for(int i=t;i<NB;i+=256) cnt[i] = 0;
    __syncthreads();
    int s0 = blockIdx.x*EPB;
    int sv[8], dv[8], off[8];
    #pragma unroll
    for(int i=0;i<8;i++){
        int e = s0 + i*256 + t;
        if(e < E){
            sv[i] = src[e]; dv[i] = dst[e];
            off[i] = atomicAdd(&cnt[dv[i]>>BSH], 1);
        }
    }
    __syncthreads();
    for(int i=t;i<NB;i+=256) base[i] = cnt[i] ? atomicAdd(&gcur[i], cnt[i]) : 0;
    __syncthreads();
    #pragma unroll
    for(int i=0;i<8;i++){
        int e = s0 + i*256 + t;
        if(e < E) bdata[base[dv[i]>>BSH] + off[i]] = make_int2(sv[i], dv[i]);
    }
}

// per-bucket degree histogram in LDS (no global atomics)
__global__ __launch_bounds__(256) void k_bhist(const int2* __restrict__ bdata, const int* __restrict__ bbase,
                                               const int* __restrict__ gb, int* __restrict__ deg, int n){
    __shared__ int h[256];
    int b = blockIdx.x, t = threadIdx.x;
    h[t] = 0; __syncthreads();
    int beg = bbase[b], cnt = gb[b];
    for(int i=t;i<cnt;i+=256) atomicAdd(&h[bdata[beg+i].y & 255], 1);
    __syncthreads();
    int node = (b<<BSH) + t;
    if(node < n) deg[node] = h[t];
}

// per-bucket scatter: col/fill writes confined to small L1/L2-resident windows
__global__ __launch_bounds__(256) void k_bscat(const int2* __restrict__ bdata, const int* __restrict__ bbase,
                                               const int* __restrict__ gb, const int* __restrict__ rp,
                                               int* __restrict__ fill, int* __restrict__ col){
    int b = blockIdx.x, t = threadIdx.x;
    int beg = bbase[b], cnt = gb[b];
    for(int i=t;i<cnt;i+=256){
        int2 e = bdata[beg+i];
        int pos = rp[e.y] + atomicAdd(&fill[e.y], 1);
        col[pos] = e.x;
    }
}

// ---------------- node-degree scan -> rowptr ----------------
__global__ __launch_bounds__(1024) void k_scan1(const int* __restrict__ deg, int* __restrict__ rp1,
                                                int* __restrict__ bsum, int n){
    __shared__ int s[1024];
    int t = threadIdx.x;
    int i = blockIdx.x*1024 + t;
    int v = (i < n) ? deg[i] : 0;
    s[t] = v; __syncthreads();
    for(int o=1;o<1024;o<<=1){
        int u = (t >= o) ? s[t-o] : 0;
        __syncthreads();
        s[t] += u;
        __syncthreads();
    }
    if(i < n) rp1[i] = s[t];
    if(t == 1023) bsum[blockIdx.x] = s[t];
}

__global__ __launch_bounds__(1024) void k_scan2(int* __restrict__ bsum, int nb){
    __shared__ int s[1024];
    int t = threadIdx.x;
    int v = (t < nb) ? bsum[t] : 0;
    s[t] = v; __syncthreads();
    for(int o=1;o<1024;o<<=1){
        int u = (t >= o) ? s[t-o] : 0;
        __syncthreads();
        s[t] += u;
        __syncthreads();
    }
    if(t < nb) bsum[t] = (t > 0) ? s[t-1] : 0;
}

__global__ __launch_bounds__(1024) void k_scan3(int* __restrict__ rp, const int* __restrict__ boff, int n){
    int i = blockIdx.x*1024 + threadIdx.x;
    if(i < n) rp[i+1] += boff[blockIdx.x];
    if(i == 0) rp[0] = 0;
}

// ---------------- fused GEMM (h = IN @ W) + attention scalars ----------------
// W column per lane in 64 VGPRs; x rows staged in LDS, broadcast via ds_read_b128.
__global__ __launch_bounds__(256) void k_gemm(
    const float* __restrict__ IN, const float* __restrict__ addrow,
    const float* __restrict__ addtab, const int* __restrict__ hb,
    const float* __restrict__ W, const float* __restrict__ asr,
    const float* __restrict__ adt, float* __restrict__ Hout,
    float* __restrict__ AS, float* __restrict__ AD, int n)
{
    __shared__ float sx[8][HD];
    int t = threadIdx.x, lane = t & 63, ws = (t>>6)*2;
    float w[HD];
    #pragma unroll
    for(int k=0;k<HD;k++) w[k] = W[k*HD + lane];
    float vas = asr[lane], vad = adt[lane];
    float ar = addrow ? addrow[lane] : 0.f;

    int wid = (blockIdx.x*256 + t) >> 6;
    int nw  = gridDim.x*4;
    for(int row = wid*2; row < n; row += nw*2){
        bool r1 = (row + 1 < n);
        float x0 = IN[(size_t)row*HD + lane] + ar;
        float x1 = r1 ? (IN[(size_t)(row+1)*HD + lane] + ar) : 0.f;
        if(addtab){
            x0 += addtab[hb[row]*HD + lane];
            if(r1) x1 += addtab[hb[row+1]*HD + lane];
        }
        sx[ws  ][lane] = x0;
        sx[ws+1][lane] = x1;
        // wave-synchronous: compiler inserts lgkmcnt waits on the LDS dependence
        float a00=0.f,a01=0.f,a02=0.f,a03=0.f, a10=0.f,a11=0.f,a12=0.f,a13=0.f;
        #pragma unroll
        for(int k=0;k<HD;k+=4){
            float4 q0 = *(const float4*)&sx[ws  ][k];   // broadcast read, conflict-free
            float4 q1 = *(const float4*)&sx[ws+1][k];
            a00 = fmaf(q0.x, w[k],   a00);
            a01 = fmaf(q0.y, w[k+1], a01);
            a02 = fmaf(q0.z, w[k+2], a02);
            a03 = fmaf(q0.w, w[k+3], a03);
            a10 = fmaf(q1.x, w[k],   a10);
            a11 = fmaf(q1.y, w[k+1], a11);
            a12 = fmaf(q1.z, w[k+2], a12);
            a13 = fmaf(q1.w, w[k+3], a13);
        }
        float h0 = (a00+a01)+(a02+a03);
        float h1 = (a10+a11)+(a12+a13);

        Hout[(size_t)row*HD + lane] = h0;
        float t1 = h0*vas, t2 = h0*vad;
        #pragma unroll
        for(int o=32;o;o>>=1){ t1 += __shfl_xor(t1,o,64); t2 += __shfl_xor(t2,o,64); }
        if(lane == 0){ AS[row] = t1; AD[row] = t2; }

        if(r1){
            Hout[(size_t)(row+1)*HD + lane] = h1;
            float u1 = h1*vas, u2 = h1*vad;
            #pragma unroll
            for(int o=32;o;o>>=1){ u1 += __shfl_xor(u1,o,64); u2 += __shfl_xor(u2,o,64); }
            if(lane == 0){ AS[row+1] = u1; AD[row+1] = u2; }
        }
    }
}

// ---------------- wave-per-dst GAT aggregate (no-max softmax: scores bounded) ----------------
__global__ __launch_bounds__(256) void k_agg(
    const float* __restrict__ H, const float* __restrict__ AS, const float* __restrict__ AD,
    const int* __restrict__ rp, const int* __restrict__ col,
    const float* __restrict__ bias, float* __restrict__ OUT, int n)
{
    int t = threadIdx.x, lane = t & 63;
    int dst = blockIdx.x*4 + (t>>6);
    if(dst >= n) return;
    float ad = AD[dst];
    float s = __expf(lrelu(AS[dst] + ad));        // self loop weight
    float acc = H[(size_t)dst*HD + lane] * s;
    int beg = rp[dst], end = rp[dst+1];
    for(int base = beg; base < end; base += 64){
        int j = base + lane;
        int sj = 0; float wj = 0.f;
        if(j < end){ sj = col[j]; wj = __expf(lrelu(AS[sj] + ad)); }
        float sc = wj;
        #pragma unroll
        for(int o=32;o;o>>=1) sc += __shfl_xor(sc,o,64);
        s += sc;
        int cnt = min(64, end - base);
        int q = 0;
        for(; q + 4 <= cnt; q += 4){
            float w0=__shfl(wj,q,64), w1=__shfl(wj,q+1,64), w2=__shfl(wj,q+2,64), w3=__shfl(wj,q+3,64);
            int   s0=__shfl(sj,q,64), s1=__shfl(sj,q+1,64), s2=__shfl(sj,q+2,64), s3=__shfl(sj,q+3,64);
            float h0 = H[(size_t)s0*HD + lane];
            float h1 = H[(size_t)s1*HD + lane];
            float h2 = H[(size_t)s2*HD + lane];
            float h3 = H[(size_t)s3*HD + lane];
            acc = fmaf(w0,h0, fmaf(w1,h1, fmaf(w2,h2, fmaf(w3,h3, acc))));
        }
        for(; q < cnt; q++){
            float wq = __shfl(wj,q,64);
            int   sq = __shfl(sj,q,64);
            acc = fmaf(wq, H[(size_t)sq*HD + lane], acc);
        }
    }
    OUT[(size_t)dst*HD + lane] = acc/(s + 1e-16f) + bias[lane];
}

// ---------------- virtual-node segment sum (LDS-staged atomics) ----------------
__global__ __launch_bounds__(256) void k_vnseg(const float* __restrict__ OUT, const int* __restrict__ hb,
                                               float* __restrict__ vnS, int n){
    __shared__ float acc[HNUM*HD];
    int t = threadIdx.x;
    for(int i=t;i<HNUM*HD;i+=256) acc[i] = 0.f;
    __syncthreads();
    int total = n*HD;
    for(int idx = blockIdx.x*256 + t; idx < total; idx += gridDim.x*256){
        int node = idx >> 6, c = idx & 63;
        atomicAdd(&acc[hb[node]*HD + c], OUT[idx]);
    }
    __syncthreads();
    for(int i=t;i<HNUM*HD;i+=256) atomicAdd(&vnS[i], acc[i]);
}

// ---------------- vn update + both MLPs, fully in registers ----------------
__global__ __launch_bounds__(256) void k_vn(
    const float* __restrict__ vnS, const float* __restrict__ vne,
    const float* __restrict__ W1, const float* __restrict__ B1,
    const float* __restrict__ W2, const float* __restrict__ B2,
    float* __restrict__ vnD)
{
    int lane = threadIdx.x & 63;
    int w = (blockIdx.x*256 + threadIdx.x) >> 6;
    const int R = HNUM/32;
    float a[R], br[R];
    float ve = vne[lane];
    #pragma unroll
    for(int r=0;r<R;r++){
        int b = w*R + r;
        a[r] = vnS[b*HD + lane] + ve + ve;
    }
    for(int j=0;j<NMLP;j++){
        const float* w1 = W1 + j*HD*HD; const float* b1 = B1 + j*HD;
        const float* w2 = W2 + j*HD*HD; const float* b2 = B2 + j*HD;
        #pragma unroll
        for(int r=0;r<R;r++){
            float tacc = b1[lane];
            #pragma unroll
            for(int in=0;in<HD;in++) tacc = fmaf(__shfl(a[r], in, 64), w1[in*HD + lane], tacc);
            br[r] = fmaxf(tacc, 0.f);
        }
        #pragma unroll
        for(int r=0;r<R;r++){
            float tacc = b2[lane];
            #pragma unroll
            for(int in=0;in<HD;in++) tacc = fmaf(__shfl(br[r], in, 64), w2[in*HD + lane], tacc);
            a[r] = fmaxf(tacc, 0.f);
        }
    }
    #pragma unroll
    for(int r=0;r<R;r++){
        int b = w*R + r;
        vnD[b*HD + lane] = a[r];
    }
}

extern "C" void kernel_launch(void* const* d_in, const int* in_sizes, int n_in,
                              void* d_out, int out_size, void* d_ws, size_t ws_size,
                              hipStream_t stream)
{
    const float* x   = (const float*)d_in[0];
    const int*   ei  = (const int*)d_in[1];
    const int*   hb  = (const int*)d_in[2];
    const float* W0  = (const float*)d_in[5];
    const float* as0 = (const float*)d_in[6];
    const float* ad0 = (const float*)d_in[7];
    const float* b0  = (const float*)d_in[8];
    const float* Wl  = (const float*)d_in[9];
    const float* asl = (const float*)d_in[10];
    const float* adl = (const float*)d_in[11];
    const float* bl  = (const float*)d_in[12];
    const float* vne = (const float*)d_in[13];
    const float* mW1 = (const float*)d_in[14];
    const float* mb1 = (const float*)d_in[15];
    const float* mW2 = (const float*)d_in[16];
    const float* mb2 = (const float*)d_in[17];

    int N = in_sizes[0]/HD;
    int E = in_sizes[1]/2;
    const int* src = ei;
    const int* dst = ei + E;
    int NB = (N + (1<<BSH) - 1) >> BSH;          // 391 buckets (<= MAXNB)

    char* p = (char*)d_ws;
    float* f_h   = (float*)p; p += (size_t)N*HD*4;
    float* f_as  = (float*)p; p += (size_t)N*4;
    float* f_ad  = (float*)p; p += (size_t)N*4;
    float* f_vnD = (float*)p; p += HNUM*HD*4;
    float* f_vnS = (float*)p; p += HNUM*HD*4;
    int*   i_rp  = (int*)p;   p += (size_t)(N+1)*4;
    int*   i_deg = (int*)p;   p += (size_t)N*4;
    int*   i_fill= (int*)p;   p += (size_t)N*4;
    int*   i_gb  = (int*)p;   p += MAXNB*4;      // fill + gb zeroed in ONE memset
    int*   i_bb  = (int*)p;   p += MAXNB*4;
    int*   i_gc  = (int*)p;   p += MAXNB*4;
    int*   i_col = (int*)p;   p += (size_t)E*4;
    int*   i_bs  = (int*)p;   p += 4096;
    int2*  bdata = (int2*)f_h;                   // alias: f_h not live during CSR build

    float* outb = (float*)d_out;

    int nb = (N + 1023)/1024;
    // ---- CSR by destination (bucketed counting sort) ----
    hipMemsetAsync(i_fill, 0, (size_t)N*4 + MAXNB*4, stream);   // fill + gb
    k_bcnt <<<512, 256, 0, stream>>>(dst, i_gb, E, NB);
    k_bscan<<<1, 512, 0, stream>>>(i_gb, i_bb, i_gc, NB);
    k_bin  <<<(E+EPB-1)/EPB, 256, 0, stream>>>(src, dst, i_gc, bdata, E, NB);
    k_bhist<<<NB, 256, 0, stream>>>(bdata, i_bb, i_gb, i_deg, N);
    k_scan1<<<nb, 1024, 0, stream>>>(i_deg, i_rp + 1, i_bs, N);
    k_scan2<<<1, 1024, 0, stream>>>(i_bs, nb);
    k_scan3<<<nb, 1024, 0, stream>>>(i_rp, i_bs, N);
    k_bscat<<<NB, 256, 0, stream>>>(bdata, i_bb, i_gb, i_rp, i_fill, i_col);

    int gn = (N + 3)/4;
    int gg = 1024;
    // conv0: GAT(x, W0)
    k_gemm<<<gg, 256, 0, stream>>>(x, nullptr, nullptr, hb, W0, as0, ad0, f_h, f_as, f_ad, N);
    k_agg <<<gn, 256, 0, stream>>>(f_h, f_as, f_ad, i_rp, i_col, b0, outb, N);
    // conv1: GAT(out0 + vn_emb, Wl[0])
    k_gemm<<<gg, 256, 0, stream>>>(outb, vne, nullptr, hb, Wl, asl, adl, f_h, f_as, f_ad, N);
    k_agg <<<gn, 256, 0, stream>>>(f_h, f_as, f_ad, i_rp, i_col, bl, outb, N);
    // vn update (only live one): vnD = MLPs(segsum(out1) + 2*vne)
    hipMemsetAsync(f_vnS, 0, HNUM*HD*4, stream);
    k_vnseg<<<128, 256, 0, stream>>>(outb, hb, f_vnS, N);
    k_vn  <<<8, 256, 0, stream>>>(f_vnS, vne, mW1, mb1, mW2, mb2, f_vnD);
    // conv2: GAT(out1 + vnD[hb], Wl[1]) -> final output
    k_gemm<<<gg, 256, 0, stream>>>(outb, nullptr, f_vnD, hb, Wl + HD*HD, asl + HD, adl + HD, f_h, f_as, f_ad, N);
    k_agg <<<gn, 256, 0, stream>>>(f_h, f_as, f_ad, i_rp, i_col, bl + HD, outb, N);
}

// Round 4
// 546.321 us; speedup vs baseline: 1.4772x; 1.0467x over previous
//
#include <hip/hip_runtime.h>
#include <math.h>

#define HD 64
#define HNUM 128
#define NMLP 2
#define BSH 8              // 256 dst-nodes per bucket
#define MAXNB 512
#define EPB 2048           // edges per k_bin block

__device__ __forceinline__ float lrelu(float x){ return fmaxf(x, 0.2f*x); }

// ---------------- CSR build: bucketed counting sort ----------------
__global__ __launch_bounds__(256) void k_bcnt(const int* __restrict__ dst, int* __restrict__ gb,
                                              int E, int NB){
    __shared__ int h[MAXNB];
    int t = threadIdx.x;
    for(int i=t;i<NB;i+=256) h[i] = 0;
    __syncthreads();
    for(int e = blockIdx.x*256 + t; e < E; e += gridDim.x*256)
        atomicAdd(&h[dst[e]>>BSH], 1);
    __syncthreads();
    for(int i=t;i<NB;i+=256) if(h[i]) atomicAdd(&gb[i], h[i]);
}

__global__ __launch_bounds__(512) void k_bscan(const int* __restrict__ gb, int* __restrict__ bbase,
                                               int* __restrict__ gcur, int NB){
    __shared__ int s[512];
    int t = threadIdx.x;
    int v = (t < NB) ? gb[t] : 0;
    s[t] = v; __syncthreads();
    for(int o=1;o<512;o<<=1){
        int u = (t >= o) ? s[t-o] : 0;
        __syncthreads();
        s[t] += u;
        __syncthreads();
    }
    if(t < NB){ int ex = s[t] - v; bbase[t] = ex; gcur[t] = ex; }
}

__global__ __launch_bounds__(256) void k_bin(const int* __restrict__ src, const int* __restrict__ dst,
                                             int* __restrict__ gcur, int2* __restrict__ bdata,
                                             int E, int NB){
    __shared__ int cnt[MAXNB];
    __shared__ int base[MAXNB];
    int t = threadIdx.x;
    for(int i=t;i<NB;i+=256) cnt[i] = 0;
    __syncthreads();
    int s0 = blockIdx.x*EPB;
    int sv[8], dv[8], off[8];
    #pragma unroll
    for(int i=0;i<8;i++){
        int e = s0 + i*256 + t;
        if(e < E){
            sv[i] = src[e]; dv[i] = dst[e];
            off[i] = atomicAdd(&cnt[dv[i]>>BSH], 1);
        }
    }
    __syncthreads();
    for(int i=t;i<NB;i+=256) base[i] = cnt[i] ? atomicAdd(&gcur[i], cnt[i]) : 0;
    __syncthreads();
    #pragma unroll
    for(int i=0;i<8;i++){
        int e = s0 + i*256 + t;
        if(e < E) bdata[base[dv[i]>>BSH] + off[i]] = make_int2(sv[i], dv[i]);
    }
}

__global__ __launch_bounds__(256) void k_bhist(const int2* __restrict__ bdata, const int* __restrict__ bbase,
                                               const int* __restrict__ gb, int* __restrict__ deg, int n){
    __shared__ int h[256];
    int b = blockIdx.x, t = threadIdx.x;
    h[t] = 0; __syncthreads();
    int beg = bbase[b], cnt = gb[b];
    for(int i=t;i<cnt;i+=256) atomicAdd(&h[bdata[beg+i].y & 255], 1);
    __syncthreads();
    int node = (b<<BSH) + t;
    if(node < n) deg[node] = h[t];
}

__global__ __launch_bounds__(256) void k_bscat(const int2* __restrict__ bdata, const int* __restrict__ bbase,
                                               const int* __restrict__ gb, const int* __restrict__ rp,
                                               int* __restrict__ fill, int* __restrict__ col){
    int b = blockIdx.x, t = threadIdx.x;
    int beg = bbase[b], cnt = gb[b];
    for(int i=t;i<cnt;i+=256){
        int2 e = bdata[beg+i];
        int pos = rp[e.y] + atomicAdd(&fill[e.y], 1);
        col[pos] = e.x;
    }
}

// ---------------- node-degree scan -> rowptr ----------------
__global__ __launch_bounds__(1024) void k_scan1(const int* __restrict__ deg, int* __restrict__ rp1,
                                                int* __restrict__ bsum, int n){
    __shared__ int s[1024];
    int t = threadIdx.x;
    int i = blockIdx.x*1024 + t;
    int v = (i < n) ? deg[i] : 0;
    s[t] = v; __syncthreads();
    for(int o=1;o<1024;o<<=1){
        int u = (t >= o) ? s[t-o] : 0;
        __syncthreads();
        s[t] += u;
        __syncthreads();
    }
    if(i < n) rp1[i] = s[t];
    if(t == 1023) bsum[blockIdx.x] = s[t];
}

__global__ __launch_bounds__(1024) void k_scan2(int* __restrict__ bsum, int nb){
    __shared__ int s[1024];
    int t = threadIdx.x;
    int v = (t < nb) ? bsum[t] : 0;
    s[t] = v; __syncthreads();
    for(int o=1;o<1024;o<<=1){
        int u = (t >= o) ? s[t-o] : 0;
        __syncthreads();
        s[t] += u;
        __syncthreads();
    }
    if(t < nb) bsum[t] = (t > 0) ? s[t-1] : 0;
}

__global__ __launch_bounds__(1024) void k_scan3(int* __restrict__ rp, const int* __restrict__ boff, int n){
    int i = blockIdx.x*1024 + threadIdx.x;
    if(i < n) rp[i+1] += boff[blockIdx.x];
    if(i == 0) rp[0] = 0;
}

// ---------------- fused GEMM (h = IN @ W) + attention scalars ----------------
__global__ __launch_bounds__(256) void k_gemm(
    const float* __restrict__ IN, const float* __restrict__ addrow,
    const float* __restrict__ addtab, const int* __restrict__ hb,
    const float* __restrict__ W, const float* __restrict__ asr,
    const float* __restrict__ adt, float* __restrict__ Hout,
    float* __restrict__ AS, float* __restrict__ AD, int n)
{
    __shared__ float sx[8][HD];
    int t = threadIdx.x, lane = t & 63, ws = (t>>6)*2;
    float w[HD];
    #pragma unroll
    for(int k=0;k<HD;k++) w[k] = W[k*HD + lane];
    float vas = asr[lane], vad = adt[lane];
    float ar = addrow ? addrow[lane] : 0.f;

    int wid = (blockIdx.x*256 + t) >> 6;
    int nw  = gridDim.x*4;
    for(int row = wid*2; row < n; row += nw*2){
        bool r1 = (row + 1 < n);
        float x0 = IN[(size_t)row*HD + lane] + ar;
        float x1 = r1 ? (IN[(size_t)(row+1)*HD + lane] + ar) : 0.f;
        if(addtab){
            x0 += addtab[hb[row]*HD + lane];
            if(r1) x1 += addtab[hb[row+1]*HD + lane];
        }
        sx[ws  ][lane] = x0;
        sx[ws+1][lane] = x1;
        float a00=0.f,a01=0.f,a02=0.f,a03=0.f, a10=0.f,a11=0.f,a12=0.f,a13=0.f;
        #pragma unroll
        for(int k=0;k<HD;k+=4){
            float4 q0 = *(const float4*)&sx[ws  ][k];
            float4 q1 = *(const float4*)&sx[ws+1][k];
            a00 = fmaf(q0.x, w[k],   a00);
            a01 = fmaf(q0.y, w[k+1], a01);
            a02 = fmaf(q0.z, w[k+2], a02);
            a03 = fmaf(q0.w, w[k+3], a03);
            a10 = fmaf(q1.x, w[k],   a10);
            a11 = fmaf(q1.y, w[k+1], a11);
            a12 = fmaf(q1.z, w[k+2], a12);
            a13 = fmaf(q1.w, w[k+3], a13);
        }
        float h0 = (a00+a01)+(a02+a03);
        float h1 = (a10+a11)+(a12+a13);

        Hout[(size_t)row*HD + lane] = h0;
        float t1 = h0*vas, t2 = h0*vad;
        #pragma unroll
        for(int o=32;o;o>>=1){ t1 += __shfl_xor(t1,o,64); t2 += __shfl_xor(t2,o,64); }
        if(lane == 0){ AS[row] = t1; AD[row] = t2; }

        if(r1){
            Hout[(size_t)(row+1)*HD + lane] = h1;
            float u1 = h1*vas, u2 = h1*vad;
            #pragma unroll
            for(int o=32;o;o>>=1){ u1 += __shfl_xor(u1,o,64); u2 += __shfl_xor(u2,o,64); }
            if(lane == 0){ AS[row+1] = u1; AD[row+1] = u2; }
        }
    }
}

// ---------------- wave-per-dst GAT aggregate (no-max softmax: scores bounded) ----------------
__global__ __launch_bounds__(256) void k_agg(
    const float* __restrict__ H, const float* __restrict__ AS, const float* __restrict__ AD,
    const int* __restrict__ rp, const int* __restrict__ col,
    const float* __restrict__ bias, float* __restrict__ OUT, int n)
{
    int t = threadIdx.x, lane = t & 63;
    int dst = blockIdx.x*4 + (t>>6);
    if(dst >= n) return;
    float ad = AD[dst];
    float s = __expf(lrelu(AS[dst] + ad));
    float acc = H[(size_t)dst*HD + lane] * s;
    int beg = rp[dst], end = rp[dst+1];
    for(int base = beg; base < end; base += 64){
        int j = base + lane;
        int sj = 0; float wj = 0.f;
        if(j < end){ sj = col[j]; wj = __expf(lrelu(AS[sj] + ad)); }
        float sc = wj;
        #pragma unroll
        for(int o=32;o;o>>=1) sc += __shfl_xor(sc,o,64);
        s += sc;
        int cnt = min(64, end - base);
        int q = 0;
        for(; q + 4 <= cnt; q += 4){
            float w0=__shfl(wj,q,64), w1=__shfl(wj,q+1,64), w2=__shfl(wj,q+2,64), w3=__shfl(wj,q+3,64);
            int   s0=__shfl(sj,q,64), s1=__shfl(sj,q+1,64), s2=__shfl(sj,q+2,64), s3=__shfl(sj,q+3,64);
            float h0 = H[(size_t)s0*HD + lane];
            float h1 = H[(size_t)s1*HD + lane];
            float h2 = H[(size_t)s2*HD + lane];
            float h3 = H[(size_t)s3*HD + lane];
            acc = fmaf(w0,h0, fmaf(w1,h1, fmaf(w2,h2, fmaf(w3,h3, acc))));
        }
        for(; q < cnt; q++){
            float wq = __shfl(wj,q,64);
            int   sq = __shfl(sj,q,64);
            acc = fmaf(wq, H[(size_t)sq*HD + lane], acc);
        }
    }
    OUT[(size_t)dst*HD + lane] = acc/(s + 1e-16f) + bias[lane];
}

// ---------------- virtual-node segment sum: 1024-thread blocks, unroll-4 ----------------
__global__ __launch_bounds__(1024) void k_vnseg(const float* __restrict__ OUT, const int* __restrict__ hb,
                                                float* __restrict__ vnS, int n){
    __shared__ float acc[HNUM*HD];
    int t = threadIdx.x, lane = t & 63;
    for(int i=t;i<HNUM*HD;i+=1024) acc[i] = 0.f;
    __syncthreads();
    int wv  = (blockIdx.x*1024 + t) >> 6;     // global wave id
    int nwv = gridDim.x*16;
    for(int node = wv*4; node < n; node += nwv*4){
        bool o1 = node+1 < n, o2 = node+2 < n, o3 = node+3 < n;
        float v0 = OUT[(size_t)node*HD + lane];
        float v1 = o1 ? OUT[(size_t)(node+1)*HD + lane] : 0.f;
        float v2 = o2 ? OUT[(size_t)(node+2)*HD + lane] : 0.f;
        float v3 = o3 ? OUT[(size_t)(node+3)*HD + lane] : 0.f;
        int b0 = hb[node];
        int b1 = o1 ? hb[node+1] : 0;
        int b2 = o2 ? hb[node+2] : 0;
        int b3 = o3 ? hb[node+3] : 0;
        atomicAdd(&acc[b0*HD + lane], v0);
        if(o1) atomicAdd(&acc[b1*HD + lane], v1);
        if(o2) atomicAdd(&acc[b2*HD + lane], v2);
        if(o3) atomicAdd(&acc[b3*HD + lane], v3);
    }
    __syncthreads();
    for(int i=t;i<HNUM*HD;i+=1024) atomicAdd(&vnS[i], acc[i]);
}

// ---------------- vn update + both MLPs, fully in registers ----------------
__global__ __launch_bounds__(256) void k_vn(
    const float* __restrict__ vnS, const float* __restrict__ vne,
    const float* __restrict__ W1, const float* __restrict__ B1,
    const float* __restrict__ W2, const float* __restrict__ B2,
    float* __restrict__ vnD)
{
    int lane = threadIdx.x & 63;
    int w = (blockIdx.x*256 + threadIdx.x) >> 6;
    const int R = HNUM/32;
    float a[R], br[R];
    float ve = vne[lane];
    #pragma unroll
    for(int r=0;r<R;r++){
        int b = w*R + r;
        a[r] = vnS[b*HD + lane] + ve + ve;
    }
    for(int j=0;j<NMLP;j++){
        const float* w1 = W1 + j*HD*HD; const float* b1 = B1 + j*HD;
        const float* w2 = W2 + j*HD*HD; const float* b2 = B2 + j*HD;
        #pragma unroll
        for(int r=0;r<R;r++){
            float tacc = b1[lane];
            #pragma unroll
            for(int in=0;in<HD;in++) tacc = fmaf(__shfl(a[r], in, 64), w1[in*HD + lane], tacc);
            br[r] = fmaxf(tacc, 0.f);
        }
        #pragma unroll
        for(int r=0;r<R;r++){
            float tacc = b2[lane];
            #pragma unroll
            for(int in=0;in<HD;in++) tacc = fmaf(__shfl(br[r], in, 64), w2[in*HD + lane], tacc);
            a[r] = fmaxf(tacc, 0.f);
        }
    }
    #pragma unroll
    for(int r=0;r<R;r++){
        int b = w*R + r;
        vnD[b*HD + lane] = a[r];
    }
}

extern "C" void kernel_launch(void* const* d_in, const int* in_sizes, int n_in,
                              void* d_out, int out_size, void* d_ws, size_t ws_size,
                              hipStream_t stream)
{
    const float* x   = (const float*)d_in[0];
    const int*   ei  = (const int*)d_in[1];
    const int*   hb  = (const int*)d_in[2];
    const float* W0  = (const float*)d_in[5];
    const float* as0 = (const float*)d_in[6];
    const float* ad0 = (const float*)d_in[7];
    const float* b0  = (const float*)d_in[8];
    const float* Wl  = (const float*)d_in[9];
    const float* asl = (const float*)d_in[10];
    const float* adl = (const float*)d_in[11];
    const float* bl  = (const float*)d_in[12];
    const float* vne = (const float*)d_in[13];
    const float* mW1 = (const float*)d_in[14];
    const float* mb1 = (const float*)d_in[15];
    const float* mW2 = (const float*)d_in[16];
    const float* mb2 = (const float*)d_in[17];

    int N = in_sizes[0]/HD;
    int E = in_sizes[1]/2;
    const int* src = ei;
    const int* dst = ei + E;
    int NB = (N + (1<<BSH) - 1) >> BSH;

    char* p = (char*)d_ws;
    float* f_h   = (float*)p; p += (size_t)N*HD*4;
    float* f_as  = (float*)p; p += (size_t)N*4;
    float* f_ad  = (float*)p; p += (size_t)N*4;
    float* f_vnD = (float*)p; p += HNUM*HD*4;
    float* f_vnS = (float*)p; p += HNUM*HD*4;
    int*   i_rp  = (int*)p;   p += (size_t)(N+1)*4;
    int*   i_deg = (int*)p;   p += (size_t)N*4;
    int*   i_fill= (int*)p;   p += (size_t)N*4;
    int*   i_gb  = (int*)p;   p += MAXNB*4;
    int*   i_bb  = (int*)p;   p += MAXNB*4;
    int*   i_gc  = (int*)p;   p += MAXNB*4;
    int*   i_col = (int*)p;   p += (size_t)E*4;
    int*   i_bs  = (int*)p;   p += 4096;
    int2*  bdata = (int2*)f_h;

    float* outb = (float*)d_out;

    int nb = (N + 1023)/1024;
    hipMemsetAsync(i_fill, 0, (size_t)N*4 + MAXNB*4, stream);
    k_bcnt <<<512, 256, 0, stream>>>(dst, i_gb, E, NB);
    k_bscan<<<1, 512, 0, stream>>>(i_gb, i_bb, i_gc, NB);
    k_bin  <<<(E+EPB-1)/EPB, 256, 0, stream>>>(src, dst, i_gc, bdata, E, NB);
    k_bhist<<<NB, 256, 0, stream>>>(bdata, i_bb, i_gb, i_deg, N);
    k_scan1<<<nb, 1024, 0, stream>>>(i_deg, i_rp + 1, i_bs, N);
    k_scan2<<<1, 1024, 0, stream>>>(i_bs, nb);
    k_scan3<<<nb, 1024, 0, stream>>>(i_rp, i_bs, N);
    k_bscat<<<NB, 256, 0, stream>>>(bdata, i_bb, i_gb, i_rp, i_fill, i_col);

    int gn = (N + 3)/4;
    int gg = 1024;
    // conv0: GAT(x, W0)
    k_gemm<<<gg, 256, 0, stream>>>(x, nullptr, nullptr, hb, W0, as0, ad0, f_h, f_as, f_ad, N);
    k_agg <<<gn, 256, 0, stream>>>(f_h, f_as, f_ad, i_rp, i_col, b0, outb, N);
    // conv1: GAT(out0 + vn_emb, Wl[0])
    k_gemm<<<gg, 256, 0, stream>>>(outb, vne, nullptr, hb, Wl, asl, adl, f_h, f_as, f_ad, N);
    k_agg <<<gn, 256, 0, stream>>>(f_h, f_as, f_ad, i_rp, i_col, bl, outb, N);
    // vn update: vnD = MLPs(segsum(out1) + 2*vne)
    hipMemsetAsync(f_vnS, 0, HNUM*HD*4, stream);
    k_vnseg<<<256, 1024, 0, stream>>>(outb, hb, f_vnS, N);
    k_vn  <<<8, 256, 0, stream>>>(f_vnS, vne, mW1, mb1, mW2, mb2, f_vnD);
    // conv2: GAT(out1 + vnD[hb], Wl[1]) -> final output
    k_gemm<<<gg, 256, 0, stream>>>(outb, nullptr, f_vnD, hb, Wl + HD*HD, asl + HD, adl + HD, f_h, f_as, f_ad, N);
    k_agg <<<gn, 256, 0, stream>>>(f_h, f_as, f_ad, i_rp, i_col, bl + HD, outb, N);
}

// Round 5
// 526.712 us; speedup vs baseline: 1.5322x; 1.0372x over previous
//
#include <hip/hip_runtime.h>
#include <hip/hip_fp16.h>
#include <math.h>

#define HD 64
#define HNUM 128
#define NMLP 2
#define BSH 8              // 256 dst-nodes per bucket
#define MAXNB 512
#define EPB 2048           // edges per k_bin block

typedef unsigned int uint_t;
typedef unsigned short ushort_t;

__device__ __forceinline__ float lrelu(float x){ return fmaxf(x, 0.2f*x); }

// extract fp16 at half-position sh (0 or 16) of packed word, convert to f32
__device__ __forceinline__ float cvt_h(uint_t wv, uint_t sh){
    __half_raw hr; hr.x = (ushort_t)(wv >> sh);
    return __half2float((__half)hr);
}

// ---------------- CSR build: bucketed counting sort ----------------
__global__ __launch_bounds__(256) void k_bcnt(const int* __restrict__ dst, int* __restrict__ gb,
                                              int E, int NB){
    __shared__ int h[MAXNB];
    int t = threadIdx.x;
    for(int i=t;i<NB;i+=256) h[i] = 0;
    __syncthreads();
    for(int e = blockIdx.x*256 + t; e < E; e += gridDim.x*256)
        atomicAdd(&h[dst[e]>>BSH], 1);
    __syncthreads();
    for(int i=t;i<NB;i+=256) if(h[i]) atomicAdd(&gb[i], h[i]);
}

__global__ __launch_bounds__(512) void k_bscan(const int* __restrict__ gb, int* __restrict__ bbase,
                                               int* __restrict__ gcur, int NB){
    __shared__ int s[512];
    int t = threadIdx.x;
    int v = (t < NB) ? gb[t] : 0;
    s[t] = v; __syncthreads();
    for(int o=1;o<512;o<<=1){
        int u = (t >= o) ? s[t-o] : 0;
        __syncthreads();
        s[t] += u;
        __syncthreads();
    }
    if(t < NB){ int ex = s[t] - v; bbase[t] = ex; gcur[t] = ex; }
}

__global__ __launch_bounds__(256) void k_bin(const int* __restrict__ src, const int* __restrict__ dst,
                                             int* __restrict__ gcur, int2* __restrict__ bdata,
                                             int E, int NB){
    __shared__ int cnt[MAXNB];
    __shared__ int base[MAXNB];
    int t = threadIdx.x;
    for(int i=t;i<NB;i+=256) cnt[i] = 0;
    __syncthreads();
    int s0 = blockIdx.x*EPB;
    int sv[8], dv[8], off[8];
    #pragma unroll
    for(int i=0;i<8;i++){
        int e = s0 + i*256 + t;
        if(e < E){
            sv[i] = src[e]; dv[i] = dst[e];
            off[i] = atomicAdd(&cnt[dv[i]>>BSH], 1);
        }
    }
    __syncthreads();
    for(int i=t;i<NB;i+=256) base[i] = cnt[i] ? atomicAdd(&gcur[i], cnt[i]) : 0;
    __syncthreads();
    #pragma unroll
    for(int i=0;i<8;i++){
        int e = s0 + i*256 + t;
        if(e < E) bdata[base[dv[i]>>BSH] + off[i]] = make_int2(sv[i], dv[i]);
    }
}

__global__ __launch_bounds__(256) void k_bhist(const int2* __restrict__ bdata, const int* __restrict__ bbase,
                                               const int* __restrict__ gb, int* __restrict__ deg, int n){
    __shared__ int h[256];
    int b = blockIdx.x, t = threadIdx.x;
    h[t] = 0; __syncthreads();
    int beg = bbase[b], cnt = gb[b];
    for(int i=t;i<cnt;i+=256) atomicAdd(&h[bdata[beg+i].y & 255], 1);
    __syncthreads();
    int node = (b<<BSH) + t;
    if(node < n) deg[node] = h[t];
}

__global__ __launch_bounds__(256) void k_bscat(const int2* __restrict__ bdata, const int* __restrict__ bbase,
                                               const int* __restrict__ gb, const int* __restrict__ rp,
                                               int* __restrict__ fill, int* __restrict__ col){
    int b = blockIdx.x, t = threadIdx.x;
    int beg = bbase[b], cnt = gb[b];
    for(int i=t;i<cnt;i+=256){
        int2 e = bdata[beg+i];
        int pos = rp[e.y] + atomicAdd(&fill[e.y], 1);
        col[pos] = e.x;
    }
}

// ---------------- node-degree scan -> rowptr ----------------
__global__ __launch_bounds__(1024) void k_scan1(const int* __restrict__ deg, int* __restrict__ rp1,
                                                int* __restrict__ bsum, int n){
    __shared__ int s[1024];
    int t = threadIdx.x;
    int i = blockIdx.x*1024 + t;
    int v = (i < n) ? deg[i] : 0;
    s[t] = v; __syncthreads();
    for(int o=1;o<1024;o<<=1){
        int u = (t >= o) ? s[t-o] : 0;
        __syncthreads();
        s[t] += u;
        __syncthreads();
    }
    if(i < n) rp1[i] = s[t];
    if(t == 1023) bsum[blockIdx.x] = s[t];
}

__global__ __launch_bounds__(1024) void k_scan2(int* __restrict__ bsum, int nb){
    __shared__ int s[1024];
    int t = threadIdx.x;
    int v = (t < nb) ? bsum[t] : 0;
    s[t] = v; __syncthreads();
    for(int o=1;o<1024;o<<=1){
        int u = (t >= o) ? s[t-o] : 0;
        __syncthreads();
        s[t] += u;
        __syncthreads();
    }
    if(t < nb) bsum[t] = (t > 0) ? s[t-1] : 0;
}

__global__ __launch_bounds__(1024) void k_scan3(int* __restrict__ rp, const int* __restrict__ boff, int n){
    int i = blockIdx.x*1024 + threadIdx.x;
    if(i < n) rp[i+1] += boff[blockIdx.x];
    if(i == 0) rp[0] = 0;
}

// ---------------- fused GEMM (h = IN @ W) + attention scalars; H stored fp16 ----------------
__global__ __launch_bounds__(256) void k_gemm(
    const float* __restrict__ IN, const float* __restrict__ addrow,
    const float* __restrict__ addtab, const int* __restrict__ hb,
    const float* __restrict__ W, const float* __restrict__ asr,
    const float* __restrict__ adt, __half* __restrict__ Hh,
    float* __restrict__ AS, float* __restrict__ AD, int n)
{
    __shared__ float sx[8][HD];
    int t = threadIdx.x, lane = t & 63, ws = (t>>6)*2;
    float w[HD];
    #pragma unroll
    for(int k=0;k<HD;k++) w[k] = W[k*HD + lane];
    float vas = asr[lane], vad = adt[lane];
    float ar = addrow ? addrow[lane] : 0.f;

    int wid = (blockIdx.x*256 + t) >> 6;
    int nw  = gridDim.x*4;
    for(int row = wid*2; row < n; row += nw*2){
        bool r1 = (row + 1 < n);
        float x0 = IN[(size_t)row*HD + lane] + ar;
        float x1 = r1 ? (IN[(size_t)(row+1)*HD + lane] + ar) : 0.f;
        if(addtab){
            x0 += addtab[hb[row]*HD + lane];
            if(r1) x1 += addtab[hb[row+1]*HD + lane];
        }
        sx[ws  ][lane] = x0;
        sx[ws+1][lane] = x1;
        float a00=0.f,a01=0.f,a02=0.f,a03=0.f, a10=0.f,a11=0.f,a12=0.f,a13=0.f;
        #pragma unroll
        for(int k=0;k<HD;k+=4){
            float4 q0 = *(const float4*)&sx[ws  ][k];
            float4 q1 = *(const float4*)&sx[ws+1][k];
            a00 = fmaf(q0.x, w[k],   a00);
            a01 = fmaf(q0.y, w[k+1], a01);
            a02 = fmaf(q0.z, w[k+2], a02);
            a03 = fmaf(q0.w, w[k+3], a03);
            a10 = fmaf(q1.x, w[k],   a10);
            a11 = fmaf(q1.y, w[k+1], a11);
            a12 = fmaf(q1.z, w[k+2], a12);
            a13 = fmaf(q1.w, w[k+3], a13);
        }
        float h0 = (a00+a01)+(a02+a03);
        float h1 = (a10+a11)+(a12+a13);

        Hh[(size_t)row*HD + lane] = __float2half_rn(h0);
        float t1 = h0*vas, t2 = h0*vad;
        #pragma unroll
        for(int o=32;o;o>>=1){ t1 += __shfl_xor(t1,o,64); t2 += __shfl_xor(t2,o,64); }
        if(lane == 0){ AS[row] = t1; AD[row] = t2; }

        if(r1){
            Hh[(size_t)(row+1)*HD + lane] = __float2half_rn(h1);
            float u1 = h1*vas, u2 = h1*vad;
            #pragma unroll
            for(int o=32;o;o>>=1){ u1 += __shfl_xor(u1,o,64); u2 += __shfl_xor(u2,o,64); }
            if(lane == 0){ AS[row+1] = u1; AD[row+1] = u2; }
        }
    }
}

// ---------------- wave-per-dst GAT aggregate; fp16 H gather (128B/row) ----------------
__global__ __launch_bounds__(256) void k_agg(
    const uint_t* __restrict__ Hb, const float* __restrict__ AS, const float* __restrict__ AD,
    const int* __restrict__ rp, const int* __restrict__ col,
    const float* __restrict__ bias, float* __restrict__ OUT, int n)
{
    int t = threadIdx.x, lane = t & 63;
    int dst = blockIdx.x*4 + (t>>6);
    if(dst >= n) return;
    uint_t wi = lane >> 1;          // packed word index within row (32 words)
    uint_t sh = (lane & 1) << 4;    // 0 or 16
    float ad = AD[dst];
    float s = __expf(lrelu(AS[dst] + ad));
    float acc = cvt_h(Hb[(size_t)dst*32 + wi], sh) * s;
    int beg = rp[dst], end = rp[dst+1];
    for(int base = beg; base < end; base += 64){
        int j = base + lane;
        int sj = 0; float wj = 0.f;
        if(j < end){ sj = col[j]; wj = __expf(lrelu(AS[sj] + ad)); }
        float sc = wj;
        #pragma unroll
        for(int o=32;o;o>>=1) sc += __shfl_xor(sc,o,64);
        s += sc;
        int cnt = min(64, end - base);
        int q = 0;
        for(; q + 4 <= cnt; q += 4){
            float w0=__shfl(wj,q,64), w1=__shfl(wj,q+1,64), w2=__shfl(wj,q+2,64), w3=__shfl(wj,q+3,64);
            int   s0=__shfl(sj,q,64), s1=__shfl(sj,q+1,64), s2=__shfl(sj,q+2,64), s3=__shfl(sj,q+3,64);
            uint_t v0 = Hb[(size_t)s0*32 + wi];
            uint_t v1 = Hb[(size_t)s1*32 + wi];
            uint_t v2 = Hb[(size_t)s2*32 + wi];
            uint_t v3 = Hb[(size_t)s3*32 + wi];
            acc = fmaf(w0, cvt_h(v0,sh), fmaf(w1, cvt_h(v1,sh),
                  fmaf(w2, cvt_h(v2,sh), fmaf(w3, cvt_h(v3,sh), acc))));
        }
        for(; q < cnt; q++){
            float wq = __shfl(wj,q,64);
            int   sq = __shfl(sj,q,64);
            acc = fmaf(wq, cvt_h(Hb[(size_t)sq*32 + wi], sh), acc);
        }
    }
    OUT[(size_t)dst*HD + lane] = acc/(s + 1e-16f) + bias[lane];
}

// ---------------- virtual-node segment sum: 1024-thread blocks, unroll-4 ----------------
__global__ __launch_bounds__(1024) void k_vnseg(const float* __restrict__ OUT, const int* __restrict__ hb,
                                                float* __restrict__ vnS, int n){
    __shared__ float acc[HNUM*HD];
    int t = threadIdx.x, lane = t & 63;
    for(int i=t;i<HNUM*HD;i+=1024) acc[i] = 0.f;
    __syncthreads();
    int wv  = (blockIdx.x*1024 + t) >> 6;
    int nwv = gridDim.x*16;
    for(int node = wv*4; node < n; node += nwv*4){
        bool o1 = node+1 < n, o2 = node+2 < n, o3 = node+3 < n;
        float v0 = OUT[(size_t)node*HD + lane];
        float v1 = o1 ? OUT[(size_t)(node+1)*HD + lane] : 0.f;
        float v2 = o2 ? OUT[(size_t)(node+2)*HD + lane] : 0.f;
        float v3 = o3 ? OUT[(size_t)(node+3)*HD + lane] : 0.f;
        int b0 = hb[node];
        int b1 = o1 ? hb[node+1] : 0;
        int b2 = o2 ? hb[node+2] : 0;
        int b3 = o3 ? hb[node+3] : 0;
        atomicAdd(&acc[b0*HD + lane], v0);
        if(o1) atomicAdd(&acc[b1*HD + lane], v1);
        if(o2) atomicAdd(&acc[b2*HD + lane], v2);
        if(o3) atomicAdd(&acc[b3*HD + lane], v3);
    }
    __syncthreads();
    for(int i=t;i<HNUM*HD;i+=1024) atomicAdd(&vnS[i], acc[i]);
}

// ---------------- vn update + both MLPs, fully in registers ----------------
__global__ __launch_bounds__(256) void k_vn(
    const float* __restrict__ vnS, const float* __restrict__ vne,
    const float* __restrict__ W1, const float* __restrict__ B1,
    const float* __restrict__ W2, const float* __restrict__ B2,
    float* __restrict__ vnD)
{
    int lane = threadIdx.x & 63;
    int w = (blockIdx.x*256 + threadIdx.x) >> 6;
    const int R = HNUM/32;
    float a[R], br[R];
    float ve = vne[lane];
    #pragma unroll
    for(int r=0;r<R;r++){
        int b = w*R + r;
        a[r] = vnS[b*HD + lane] + ve + ve;
    }
    for(int j=0;j<NMLP;j++){
        const float* w1 = W1 + j*HD*HD; const float* b1 = B1 + j*HD;
        const float* w2 = W2 + j*HD*HD; const float* b2 = B2 + j*HD;
        #pragma unroll
        for(int r=0;r<R;r++){
            float tacc = b1[lane];
            #pragma unroll
            for(int in=0;in<HD;in++) tacc = fmaf(__shfl(a[r], in, 64), w1[in*HD + lane], tacc);
            br[r] = fmaxf(tacc, 0.f);
        }
        #pragma unroll
        for(int r=0;r<R;r++){
            float tacc = b2[lane];
            #pragma unroll
            for(int in=0;in<HD;in++) tacc = fmaf(__shfl(br[r], in, 64), w2[in*HD + lane], tacc);
            a[r] = fmaxf(tacc, 0.f);
        }
    }
    #pragma unroll
    for(int r=0;r<R;r++){
        int b = w*R + r;
        vnD[b*HD + lane] = a[r];
    }
}

extern "C" void kernel_launch(void* const* d_in, const int* in_sizes, int n_in,
                              void* d_out, int out_size, void* d_ws, size_t ws_size,
                              hipStream_t stream)
{
    const float* x   = (const float*)d_in[0];
    const int*   ei  = (const int*)d_in[1];
    const int*   hb  = (const int*)d_in[2];
    const float* W0  = (const float*)d_in[5];
    const float* as0 = (const float*)d_in[6];
    const float* ad0 = (const float*)d_in[7];
    const float* b0  = (const float*)d_in[8];
    const float* Wl  = (const float*)d_in[9];
    const float* asl = (const float*)d_in[10];
    const float* adl = (const float*)d_in[11];
    const float* bl  = (const float*)d_in[12];
    const float* vne = (const float*)d_in[13];
    const float* mW1 = (const float*)d_in[14];
    const float* mb1 = (const float*)d_in[15];
    const float* mW2 = (const float*)d_in[16];
    const float* mb2 = (const float*)d_in[17];

    int N = in_sizes[0]/HD;
    int E = in_sizes[1]/2;
    const int* src = ei;
    const int* dst = ei + E;
    int NB = (N + (1<<BSH) - 1) >> BSH;

    char* p = (char*)d_ws;
    float* f_h   = (float*)p; p += (size_t)N*HD*4;   // used as fp16 H (half the region) + CSR alias
    float* f_as  = (float*)p; p += (size_t)N*4;
    float* f_ad  = (float*)p; p += (size_t)N*4;
    float* f_vnD = (float*)p; p += HNUM*HD*4;
    float* f_vnS = (float*)p; p += HNUM*HD*4;
    int*   i_rp  = (int*)p;   p += (size_t)(N+1)*4;
    int*   i_deg = (int*)p;   p += (size_t)N*4;
    int*   i_fill= (int*)p;   p += (size_t)N*4;
    int*   i_gb  = (int*)p;   p += MAXNB*4;
    int*   i_bb  = (int*)p;   p += MAXNB*4;
    int*   i_gc  = (int*)p;   p += MAXNB*4;
    int*   i_col = (int*)p;   p += (size_t)E*4;
    int*   i_bs  = (int*)p;   p += 4096;
    int2*  bdata = (int2*)f_h;                       // alias: f_h not live during CSR build
    __half* Hh   = (__half*)f_h;
    uint_t* Hb   = (uint_t*)f_h;

    float* outb = (float*)d_out;

    int nb = (N + 1023)/1024;
    hipMemsetAsync(i_fill, 0, (size_t)N*4 + MAXNB*4, stream);
    k_bcnt <<<512, 256, 0, stream>>>(dst, i_gb, E, NB);
    k_bscan<<<1, 512, 0, stream>>>(i_gb, i_bb, i_gc, NB);
    k_bin  <<<(E+EPB-1)/EPB, 256, 0, stream>>>(src, dst, i_gc, bdata, E, NB);
    k_bhist<<<NB, 256, 0, stream>>>(bdata, i_bb, i_gb, i_deg, N);
    k_scan1<<<nb, 1024, 0, stream>>>(i_deg, i_rp + 1, i_bs, N);
    k_scan2<<<1, 1024, 0, stream>>>(i_bs, nb);
    k_scan3<<<nb, 1024, 0, stream>>>(i_rp, i_bs, N);
    k_bscat<<<NB, 256, 0, stream>>>(bdata, i_bb, i_gb, i_rp, i_fill, i_col);

    int gn = (N + 3)/4;
    int gg = 1024;
    // conv0: GAT(x, W0)
    k_gemm<<<gg, 256, 0, stream>>>(x, nullptr, nullptr, hb, W0, as0, ad0, Hh, f_as, f_ad, N);
    k_agg <<<gn, 256, 0, stream>>>(Hb, f_as, f_ad, i_rp, i_col, b0, outb, N);
    // conv1: GAT(out0 + vn_emb, Wl[0])
    k_gemm<<<gg, 256, 0, stream>>>(outb, vne, nullptr, hb, Wl, asl, adl, Hh, f_as, f_ad, N);
    k_agg <<<gn, 256, 0, stream>>>(Hb, f_as, f_ad, i_rp, i_col, bl, outb, N);
    // vn update: vnD = MLPs(segsum(out1) + 2*vne)
    hipMemsetAsync(f_vnS, 0, HNUM*HD*4, stream);
    k_vnseg<<<256, 1024, 0, stream>>>(outb, hb, f_vnS, N);
    k_vn  <<<8, 256, 0, stream>>>(f_vnS, vne, mW1, mb1, mW2, mb2, f_vnD);
    // conv2: GAT(out1 + vnD[hb], Wl[1]) -> final output
    k_gemm<<<gg, 256, 0, stream>>>(outb, nullptr, f_vnD, hb, Wl + HD*HD, asl + HD, adl + HD, Hh, f_as, f_ad, N);
    k_agg <<<gn, 256, 0, stream>>>(Hb, f_as, f_ad, i_rp, i_col, bl + HD, outb, N);
}

// Round 6
// 497.824 us; speedup vs baseline: 1.6211x; 1.0580x over previous
//
#include <hip/hip_runtime.h>
#include <hip/hip_fp16.h>
#include <math.h>

#define HD 64
#define HNUM 128
#define NMLP 2
#define BSH 8              // 256 dst-nodes per bucket
#define MAXNB 512
#define EPB 2048           // edges per k_bin block

typedef unsigned int uint_t;
typedef unsigned short ushort_t;

__device__ __forceinline__ float lrelu(float x){ return fmaxf(x, 0.2f*x); }

// extract fp16 at half-position sh (0 or 16) of packed word, convert to f32
__device__ __forceinline__ float cvt_h(uint_t wv, uint_t sh){
    __half_raw hr; hr.x = (ushort_t)(wv >> sh);
    return __half2float((__half)hr);
}

// ---------------- CSR build: bucketed counting sort ----------------
__global__ __launch_bounds__(256) void k_bcnt(const int* __restrict__ dst, int* __restrict__ gb,
                                              int E, int NB){
    __shared__ int h[MAXNB];
    int t = threadIdx.x;
    for(int i=t;i<NB;i+=256) h[i] = 0;
    __syncthreads();
    for(int e = blockIdx.x*256 + t; e < E; e += gridDim.x*256)
        atomicAdd(&h[dst[e]>>BSH], 1);
    __syncthreads();
    for(int i=t;i<NB;i+=256) if(h[i]) atomicAdd(&gb[i], h[i]);
}

__global__ __launch_bounds__(512) void k_bscan(const int* __restrict__ gb, int* __restrict__ bbase,
                                               int* __restrict__ gcur, int NB){
    __shared__ int s[512];
    int t = threadIdx.x;
    int v = (t < NB) ? gb[t] : 0;
    s[t] = v; __syncthreads();
    for(int o=1;o<512;o<<=1){
        int u = (t >= o) ? s[t-o] : 0;
        __syncthreads();
        s[t] += u;
        __syncthreads();
    }
    if(t < NB){ int ex = s[t] - v; bbase[t] = ex; gcur[t] = ex; }
}

__global__ __launch_bounds__(256) void k_bin(const int* __restrict__ src, const int* __restrict__ dst,
                                             int* __restrict__ gcur, int2* __restrict__ bdata,
                                             int E, int NB){
    __shared__ int cnt[MAXNB];
    __shared__ int base[MAXNB];
    int t = threadIdx.x;
    for(int i=t;i<NB;i+=256) cnt[i] = 0;
    __syncthreads();
    int s0 = blockIdx.x*EPB;
    int sv[8], dv[8], off[8];
    #pragma unroll
    for(int i=0;i<8;i++){
        int e = s0 + i*256 + t;
        if(e < E){
            sv[i] = src[e]; dv[i] = dst[e];
            off[i] = atomicAdd(&cnt[dv[i]>>BSH], 1);
        }
    }
    __syncthreads();
    for(int i=t;i<NB;i+=256) base[i] = cnt[i] ? atomicAdd(&gcur[i], cnt[i]) : 0;
    __syncthreads();
    #pragma unroll
    for(int i=0;i<8;i++){
        int e = s0 + i*256 + t;
        if(e < E) bdata[base[dv[i]>>BSH] + off[i]] = make_int2(sv[i], dv[i]);
    }
}

__global__ __launch_bounds__(256) void k_bhist(const int2* __restrict__ bdata, const int* __restrict__ bbase,
                                               const int* __restrict__ gb, int* __restrict__ deg, int n){
    __shared__ int h[256];
    int b = blockIdx.x, t = threadIdx.x;
    h[t] = 0; __syncthreads();
    int beg = bbase[b], cnt = gb[b];
    for(int i=t;i<cnt;i+=256) atomicAdd(&h[bdata[beg+i].y & 255], 1);
    __syncthreads();
    int node = (b<<BSH) + t;
    if(node < n) deg[node] = h[t];
}

__global__ __launch_bounds__(256) void k_bscat(const int2* __restrict__ bdata, const int* __restrict__ bbase,
                                               const int* __restrict__ gb, const int* __restrict__ rp,
                                               int* __restrict__ fill, int* __restrict__ col){
    int b = blockIdx.x, t = threadIdx.x;
    int beg = bbase[b], cnt = gb[b];
    for(int i=t;i<cnt;i+=256){
        int2 e = bdata[beg+i];
        int pos = rp[e.y] + atomicAdd(&fill[e.y], 1);
        col[pos] = e.x;
    }
}

// ---------------- node-degree scan -> rowptr ----------------
__global__ __launch_bounds__(1024) void k_scan1(const int* __restrict__ deg, int* __restrict__ rp1,
                                                int* __restrict__ bsum, int n){
    __shared__ int s[1024];
    int t = threadIdx.x;
    int i = blockIdx.x*1024 + t;
    int v = (i < n) ? deg[i] : 0;
    s[t] = v; __syncthreads();
    for(int o=1;o<1024;o<<=1){
        int u = (t >= o) ? s[t-o] : 0;
        __syncthreads();
        s[t] += u;
        __syncthreads();
    }
    if(i < n) rp1[i] = s[t];
    if(t == 1023) bsum[blockIdx.x] = s[t];
}

__global__ __launch_bounds__(1024) void k_scan2(int* __restrict__ bsum, int nb){
    __shared__ int s[1024];
    int t = threadIdx.x;
    int v = (t < nb) ? bsum[t] : 0;
    s[t] = v; __syncthreads();
    for(int o=1;o<1024;o<<=1){
        int u = (t >= o) ? s[t-o] : 0;
        __syncthreads();
        s[t] += u;
        __syncthreads();
    }
    if(t < nb) bsum[t] = (t > 0) ? s[t-1] : 0;
}

__global__ __launch_bounds__(1024) void k_scan3(int* __restrict__ rp, const int* __restrict__ boff, int n){
    int i = blockIdx.x*1024 + threadIdx.x;
    if(i < n) rp[i+1] += boff[blockIdx.x];
    if(i == 0) rp[0] = 0;
}

// ---------------- fused GEMM (h = IN @ W) + attention scalars; H stored fp16 ----------------
__global__ __launch_bounds__(256) void k_gemm(
    const float* __restrict__ IN, const float* __restrict__ addrow,
    const float* __restrict__ addtab, const int* __restrict__ hb,
    const float* __restrict__ W, const float* __restrict__ asr,
    const float* __restrict__ adt, __half* __restrict__ Hh,
    float* __restrict__ AS, float* __restrict__ AD, int n)
{
    __shared__ float sx[8][HD];
    int t = threadIdx.x, lane = t & 63, ws = (t>>6)*2;
    float w[HD];
    #pragma unroll
    for(int k=0;k<HD;k++) w[k] = W[k*HD + lane];
    float vas = asr[lane], vad = adt[lane];
    float ar = addrow ? addrow[lane] : 0.f;

    int wid = (blockIdx.x*256 + t) >> 6;
    int nw  = gridDim.x*4;
    for(int row = wid*2; row < n; row += nw*2){
        bool r1 = (row + 1 < n);
        float x0 = IN[(size_t)row*HD + lane] + ar;
        float x1 = r1 ? (IN[(size_t)(row+1)*HD + lane] + ar) : 0.f;
        if(addtab){
            x0 += addtab[hb[row]*HD + lane];
            if(r1) x1 += addtab[hb[row+1]*HD + lane];
        }
        sx[ws  ][lane] = x0;
        sx[ws+1][lane] = x1;
        float a00=0.f,a01=0.f,a02=0.f,a03=0.f, a10=0.f,a11=0.f,a12=0.f,a13=0.f;
        #pragma unroll
        for(int k=0;k<HD;k+=4){
            float4 q0 = *(const float4*)&sx[ws  ][k];
            float4 q1 = *(const float4*)&sx[ws+1][k];
            a00 = fmaf(q0.x, w[k],   a00);
            a01 = fmaf(q0.y, w[k+1], a01);
            a02 = fmaf(q0.z, w[k+2], a02);
            a03 = fmaf(q0.w, w[k+3], a03);
            a10 = fmaf(q1.x, w[k],   a10);
            a11 = fmaf(q1.y, w[k+1], a11);
            a12 = fmaf(q1.z, w[k+2], a12);
            a13 = fmaf(q1.w, w[k+3], a13);
        }
        float h0 = (a00+a01)+(a02+a03);
        float h1 = (a10+a11)+(a12+a13);

        Hh[(size_t)row*HD + lane] = __float2half_rn(h0);
        float t1 = h0*vas, t2 = h0*vad;
        #pragma unroll
        for(int o=32;o;o>>=1){ t1 += __shfl_xor(t1,o,64); t2 += __shfl_xor(t2,o,64); }
        if(lane == 0){ AS[row] = t1; AD[row] = t2; }

        if(r1){
            Hh[(size_t)(row+1)*HD + lane] = __float2half_rn(h1);
            float u1 = h1*vas, u2 = h1*vad;
            #pragma unroll
            for(int o=32;o;o>>=1){ u1 += __shfl_xor(u1,o,64); u2 += __shfl_xor(u2,o,64); }
            if(lane == 0){ AS[row+1] = u1; AD[row+1] = u2; }
        }
    }
}

// ---------------- wave-per-dst GAT aggregate; half-wave dual-edge, float2 cols ----------------
// Lane owns one packed fp16 dword (2 columns); lanes 0-31 process even edges, 32-63 odd edges.
__global__ __launch_bounds__(256) void k_agg(
    const uint_t* __restrict__ Hb, const float* __restrict__ AS, const float* __restrict__ AD,
    const int* __restrict__ rp, const int* __restrict__ col,
    const float* __restrict__ bias, float* __restrict__ OUT, int n)
{
    int t = threadIdx.x, lane = t & 63;
    int half = lane >> 5;           // which edge of the pair
    int wl = lane & 31;             // dword index within row
    float2 bs = *(const float2*)&bias[2*wl];
    int wv  = (blockIdx.x*256 + t) >> 6;
    int nwv = gridDim.x*4;
    for(int dst = wv; dst < n; dst += nwv){
        float ad = AD[dst];
        float wself = __expf(lrelu(AS[dst] + ad));
        float s = wself;
        uint_t hw = Hb[(size_t)dst*32 + wl];
        float2 acc;
        if(half == 0){ acc.x = cvt_h(hw,0)*wself; acc.y = cvt_h(hw,16)*wself; }
        else         { acc.x = 0.f;               acc.y = 0.f; }
        int beg = rp[dst], end = rp[dst+1];
        for(int base = beg; base < end; base += 64){
            int j = base + lane;
            int sj = 0; float wj = 0.f;
            if(j < end){ sj = col[j]; wj = __expf(lrelu(AS[sj] + ad)); }
            float sc = wj;
            #pragma unroll
            for(int o=32;o;o>>=1) sc += __shfl_xor(sc,o,64);
            s += sc;
            int cnt = min(64, end - base);
            int it = (cnt + 1) >> 1;       // pairs of edges
            int i = 0;
            for(; i + 4 <= it; i += 4){
                int q0 = 2*i + half, q1 = q0+2, q2 = q0+4, q3 = q0+6;
                float w0=__shfl(wj,q0,64), w1=__shfl(wj,q1,64), w2=__shfl(wj,q2,64), w3=__shfl(wj,q3,64);
                int   s0=__shfl(sj,q0,64), s1=__shfl(sj,q1,64), s2=__shfl(sj,q2,64), s3=__shfl(sj,q3,64);
                uint_t v0 = Hb[(size_t)s0*32 + wl];
                uint_t v1 = Hb[(size_t)s1*32 + wl];
                uint_t v2 = Hb[(size_t)s2*32 + wl];
                uint_t v3 = Hb[(size_t)s3*32 + wl];
                acc.x = fmaf(w0, cvt_h(v0,0),  acc.x);
                acc.y = fmaf(w0, cvt_h(v0,16), acc.y);
                acc.x = fmaf(w1, cvt_h(v1,0),  acc.x);
                acc.y = fmaf(w1, cvt_h(v1,16), acc.y);
                acc.x = fmaf(w2, cvt_h(v2,0),  acc.x);
                acc.y = fmaf(w2, cvt_h(v2,16), acc.y);
                acc.x = fmaf(w3, cvt_h(v3,0),  acc.x);
                acc.y = fmaf(w3, cvt_h(v3,16), acc.y);
            }
            for(; i < it; i++){
                int q = 2*i + half;
                float wq = __shfl(wj,q,64);    // lanes with q >= cnt get wj==0
                int   sq = __shfl(sj,q,64);
                uint_t v = Hb[(size_t)sq*32 + wl];
                acc.x = fmaf(wq, cvt_h(v,0),  acc.x);
                acc.y = fmaf(wq, cvt_h(v,16), acc.y);
            }
        }
        acc.x += __shfl_xor(acc.x, 32, 64);   // combine the two halves
        acc.y += __shfl_xor(acc.y, 32, 64);
        if(half == 0){
            float inv = 1.f/(s + 1e-16f);
            float2 o; o.x = fmaf(acc.x, inv, bs.x); o.y = fmaf(acc.y, inv, bs.y);
            *(float2*)&OUT[(size_t)dst*HD + 2*wl] = o;
        }
    }
}

// ---------------- virtual-node segment sum: 1024-thread blocks, unroll-4 ----------------
__global__ __launch_bounds__(1024) void k_vnseg(const float* __restrict__ OUT, const int* __restrict__ hb,
                                                float* __restrict__ vnS, int n){
    __shared__ float acc[HNUM*HD];
    int t = threadIdx.x, lane = t & 63;
    for(int i=t;i<HNUM*HD;i+=1024) acc[i] = 0.f;
    __syncthreads();
    int wv  = (blockIdx.x*1024 + t) >> 6;
    int nwv = gridDim.x*16;
    for(int node = wv*4; node < n; node += nwv*4){
        bool o1 = node+1 < n, o2 = node+2 < n, o3 = node+3 < n;
        float v0 = OUT[(size_t)node*HD + lane];
        float v1 = o1 ? OUT[(size_t)(node+1)*HD + lane] : 0.f;
        float v2 = o2 ? OUT[(size_t)(node+2)*HD + lane] : 0.f;
        float v3 = o3 ? OUT[(size_t)(node+3)*HD + lane] : 0.f;
        int b0 = hb[node];
        int b1 = o1 ? hb[node+1] : 0;
        int b2 = o2 ? hb[node+2] : 0;
        int b3 = o3 ? hb[node+3] : 0;
        atomicAdd(&acc[b0*HD + lane], v0);
        if(o1) atomicAdd(&acc[b1*HD + lane], v1);
        if(o2) atomicAdd(&acc[b2*HD + lane], v2);
        if(o3) atomicAdd(&acc[b3*HD + lane], v3);
    }
    __syncthreads();
    for(int i=t;i<HNUM*HD;i+=1024) atomicAdd(&vnS[i], acc[i]);
}

// ---------------- vn update + both MLPs, fully in registers ----------------
__global__ __launch_bounds__(256) void k_vn(
    const float* __restrict__ vnS, const float* __restrict__ vne,
    const float* __restrict__ W1, const float* __restrict__ B1,
    const float* __restrict__ W2, const float* __restrict__ B2,
    float* __restrict__ vnD)
{
    int lane = threadIdx.x & 63;
    int w = (blockIdx.x*256 + threadIdx.x) >> 6;
    const int R = HNUM/32;
    float a[R], br[R];
    float ve = vne[lane];
    #pragma unroll
    for(int r=0;r<R;r++){
        int b = w*R + r;
        a[r] = vnS[b*HD + lane] + ve + ve;
    }
    for(int j=0;j<NMLP;j++){
        const float* w1 = W1 + j*HD*HD; const float* b1 = B1 + j*HD;
        const float* w2 = W2 + j*HD*HD; const float* b2 = B2 + j*HD;
        #pragma unroll
        for(int r=0;r<R;r++){
            float tacc = b1[lane];
            #pragma unroll
            for(int in=0;in<HD;in++) tacc = fmaf(__shfl(a[r], in, 64), w1[in*HD + lane], tacc);
            br[r] = fmaxf(tacc, 0.f);
        }
        #pragma unroll
        for(int r=0;r<R;r++){
            float tacc = b2[lane];
            #pragma unroll
            for(int in=0;in<HD;in++) tacc = fmaf(__shfl(br[r], in, 64), w2[in*HD + lane], tacc);
            a[r] = fmaxf(tacc, 0.f);
        }
    }
    #pragma unroll
    for(int r=0;r<R;r++){
        int b = w*R + r;
        vnD[b*HD + lane] = a[r];
    }
}

extern "C" void kernel_launch(void* const* d_in, const int* in_sizes, int n_in,
                              void* d_out, int out_size, void* d_ws, size_t ws_size,
                              hipStream_t stream)
{
    const float* x   = (const float*)d_in[0];
    const int*   ei  = (const int*)d_in[1];
    const int*   hb  = (const int*)d_in[2];
    const float* W0  = (const float*)d_in[5];
    const float* as0 = (const float*)d_in[6];
    const float* ad0 = (const float*)d_in[7];
    const float* b0  = (const float*)d_in[8];
    const float* Wl  = (const float*)d_in[9];
    const float* asl = (const float*)d_in[10];
    const float* adl = (const float*)d_in[11];
    const float* bl  = (const float*)d_in[12];
    const float* vne = (const float*)d_in[13];
    const float* mW1 = (const float*)d_in[14];
    const float* mb1 = (const float*)d_in[15];
    const float* mW2 = (const float*)d_in[16];
    const float* mb2 = (const float*)d_in[17];

    int N = in_sizes[0]/HD;
    int E = in_sizes[1]/2;
    const int* src = ei;
    const int* dst = ei + E;
    int NB = (N + (1<<BSH) - 1) >> BSH;

    char* p = (char*)d_ws;
    float* f_h   = (float*)p; p += (size_t)N*HD*4;   // fp16 H region + CSR alias
    float* f_as  = (float*)p; p += (size_t)N*4;
    float* f_ad  = (float*)p; p += (size_t)N*4;
    float* f_vnD = (float*)p; p += HNUM*HD*4;
    float* f_vnS = (float*)p; p += HNUM*HD*4;
    int*   i_rp  = (int*)p;   p += (size_t)(N+1)*4;
    int*   i_deg = (int*)p;   p += (size_t)N*4;
    int*   i_fill= (int*)p;   p += (size_t)N*4;
    int*   i_gb  = (int*)p;   p += MAXNB*4;
    int*   i_bb  = (int*)p;   p += MAXNB*4;
    int*   i_gc  = (int*)p;   p += MAXNB*4;
    int*   i_col = (int*)p;   p += (size_t)E*4;
    int*   i_bs  = (int*)p;   p += 4096;
    int2*  bdata = (int2*)f_h;
    __half* Hh   = (__half*)f_h;
    uint_t* Hb   = (uint_t*)f_h;

    float* outb = (float*)d_out;

    int nb = (N + 1023)/1024;
    hipMemsetAsync(i_fill, 0, (size_t)N*4 + MAXNB*4, stream);
    k_bcnt <<<512, 256, 0, stream>>>(dst, i_gb, E, NB);
    k_bscan<<<1, 512, 0, stream>>>(i_gb, i_bb, i_gc, NB);
    k_bin  <<<(E+EPB-1)/EPB, 256, 0, stream>>>(src, dst, i_gc, bdata, E, NB);
    k_bhist<<<NB, 256, 0, stream>>>(bdata, i_bb, i_gb, i_deg, N);
    k_scan1<<<nb, 1024, 0, stream>>>(i_deg, i_rp + 1, i_bs, N);
    k_scan2<<<1, 1024, 0, stream>>>(i_bs, nb);
    k_scan3<<<nb, 1024, 0, stream>>>(i_rp, i_bs, N);
    k_bscat<<<NB, 256, 0, stream>>>(bdata, i_bb, i_gb, i_rp, i_fill, i_col);

    int ga = 4096;   // persistent k_agg: 16384 waves, ~6 dsts each
    int gg = 1024;
    // conv0: GAT(x, W0)
    k_gemm<<<gg, 256, 0, stream>>>(x, nullptr, nullptr, hb, W0, as0, ad0, Hh, f_as, f_ad, N);
    k_agg <<<ga, 256, 0, stream>>>(Hb, f_as, f_ad, i_rp, i_col, b0, outb, N);
    // conv1: GAT(out0 + vn_emb, Wl[0])
    k_gemm<<<gg, 256, 0, stream>>>(outb, vne, nullptr, hb, Wl, asl, adl, Hh, f_as, f_ad, N);
    k_agg <<<ga, 256, 0, stream>>>(Hb, f_as, f_ad, i_rp, i_col, bl, outb, N);
    // vn update: vnD = MLPs(segsum(out1) + 2*vne)
    hipMemsetAsync(f_vnS, 0, HNUM*HD*4, stream);
    k_vnseg<<<256, 1024, 0, stream>>>(outb, hb, f_vnS, N);
    k_vn  <<<8, 256, 0, stream>>>(f_vnS, vne, mW1, mb1, mW2, mb2, f_vnD);
    // conv2: GAT(out1 + vnD[hb], Wl[1]) -> final output
    k_gemm<<<gg, 256, 0, stream>>>(outb, nullptr, f_vnD, hb, Wl + HD*HD, asl + HD, adl + HD, Hh, f_as, f_ad, N);
    k_agg <<<ga, 256, 0, stream>>>(Hb, f_as, f_ad, i_rp, i_col, bl + HD, outb, N);
}

// Round 7
// 390.956 us; speedup vs baseline: 2.0643x; 1.2734x over previous
//
#include <hip/hip_runtime.h>
#include <hip/hip_fp16.h>
#include <math.h>

#define HD 64
#define HNUM 128
#define NMLP 2
#define BSH 8              // 256 dst-nodes per bucket
#define MAXNB 512
#define EPB 2048           // edges per k_bin block

typedef unsigned int uint_t;
typedef unsigned short ushort_t;
typedef _Float16 h8 __attribute__((ext_vector_type(8)));
typedef _Float16 h2v __attribute__((ext_vector_type(2)));
typedef float vf4 __attribute__((ext_vector_type(4)));

union H8U { h8 v; uint_t u[4]; };

__device__ __forceinline__ float lrelu(float x){ return fmaxf(x, 0.2f*x); }

__device__ __forceinline__ float cvt_h(uint_t wv, uint_t sh){
    __half_raw hr; hr.x = (ushort_t)(wv >> sh);
    return __half2float((__half)hr);
}
__device__ __forceinline__ uint_t pk2(float a, float b){
    return (uint_t)__half_as_ushort(__float2half_rn(a)) |
           ((uint_t)__half_as_ushort(__float2half_rn(b)) << 16);
}

// ---------------- CSR build: bucketed counting sort ----------------
__global__ __launch_bounds__(256) void k_bcnt(const int* __restrict__ dst, int* __restrict__ gb,
                                              int E, int NB){
    __shared__ int h[MAXNB];
    int t = threadIdx.x;
    for(int i=t;i<NB;i+=256) h[i] = 0;
    __syncthreads();
    for(int e = blockIdx.x*256 + t; e < E; e += gridDim.x*256)
        atomicAdd(&h[dst[e]>>BSH], 1);
    __syncthreads();
    for(int i=t;i<NB;i+=256) if(h[i]) atomicAdd(&gb[i], h[i]);
}

__global__ __launch_bounds__(512) void k_bscan(const int* __restrict__ gb, int* __restrict__ bbase,
                                               int* __restrict__ gcur, int NB){
    __shared__ int s[512];
    int t = threadIdx.x;
    int v = (t < NB) ? gb[t] : 0;
    s[t] = v; __syncthreads();
    for(int o=1;o<512;o<<=1){
        int u = (t >= o) ? s[t-o] : 0;
        __syncthreads();
        s[t] += u;
        __syncthreads();
    }
    if(t < NB){ int ex = s[t] - v; bbase[t] = ex; gcur[t] = ex; }
}

__global__ __launch_bounds__(256) void k_bin(const int* __restrict__ src, const int* __restrict__ dst,
                                             int* __restrict__ gcur, int2* __restrict__ bdata,
                                             int E, int NB){
    __shared__ int cnt[MAXNB];
    __shared__ int base[MAXNB];
    int t = threadIdx.x;
    for(int i=t;i<NB;i+=256) cnt[i] = 0;
    __syncthreads();
    int s0 = blockIdx.x*EPB;
    int sv[8], dv[8], off[8];
    #pragma unroll
    for(int i=0;i<8;i++){
        int e = s0 + i*256 + t;
        if(e < E){
            sv[i] = src[e]; dv[i] = dst[e];
            off[i] = atomicAdd(&cnt[dv[i]>>BSH], 1);
        }
    }
    __syncthreads();
    for(int i=t;i<NB;i+=256) base[i] = cnt[i] ? atomicAdd(&gcur[i], cnt[i]) : 0;
    __syncthreads();
    #pragma unroll
    for(int i=0;i<8;i++){
        int e = s0 + i*256 + t;
        if(e < E) bdata[base[dv[i]>>BSH] + off[i]] = make_int2(sv[i], dv[i]);
    }
}

__global__ __launch_bounds__(256) void k_bhist(const int2* __restrict__ bdata, const int* __restrict__ bbase,
                                               const int* __restrict__ gb, int* __restrict__ deg, int n){
    __shared__ int h[256];
    int b = blockIdx.x, t = threadIdx.x;
    h[t] = 0; __syncthreads();
    int beg = bbase[b], cnt = gb[b];
    for(int i=t;i<cnt;i+=256) atomicAdd(&h[bdata[beg+i].y & 255], 1);
    __syncthreads();
    int node = (b<<BSH) + t;
    if(node < n) deg[node] = h[t];
}

__global__ __launch_bounds__(256) void k_bscat(const int2* __restrict__ bdata, const int* __restrict__ bbase,
                                               const int* __restrict__ gb, const int* __restrict__ rp,
                                               int* __restrict__ fill, int* __restrict__ col){
    int b = blockIdx.x, t = threadIdx.x;
    int beg = bbase[b], cnt = gb[b];
    for(int i=t;i<cnt;i+=256){
        int2 e = bdata[beg+i];
        int pos = rp[e.y] + atomicAdd(&fill[e.y], 1);
        col[pos] = e.x;
    }
}

// ---------------- node-degree scan -> rowptr ----------------
__global__ __launch_bounds__(1024) void k_scan1(const int* __restrict__ deg, int* __restrict__ rp1,
                                                int* __restrict__ bsum, int n){
    __shared__ int s[1024];
    int t = threadIdx.x;
    int i = blockIdx.x*1024 + t;
    int v = (i < n) ? deg[i] : 0;
    s[t] = v; __syncthreads();
    for(int o=1;o<1024;o<<=1){
        int u = (t >= o) ? s[t-o] : 0;
        __syncthreads();
        s[t] += u;
        __syncthreads();
    }
    if(i < n) rp1[i] = s[t];
    if(t == 1023) bsum[blockIdx.x] = s[t];
}

__global__ __launch_bounds__(1024) void k_scan2(int* __restrict__ bsum, int nb){
    __shared__ int s[1024];
    int t = threadIdx.x;
    int v = (t < nb) ? bsum[t] : 0;
    s[t] = v; __syncthreads();
    for(int o=1;o<1024;o<<=1){
        int u = (t >= o) ? s[t-o] : 0;
        __syncthreads();
        s[t] += u;
        __syncthreads();
    }
    if(t < nb) bsum[t] = (t > 0) ? s[t-1] : 0;
}

__global__ __launch_bounds__(1024) void k_scan3(int* __restrict__ rp, const int* __restrict__ boff, int n){
    int i = blockIdx.x*1024 + threadIdx.x;
    if(i < n) rp[i+1] += boff[blockIdx.x];
    if(i == 0) rp[0] = 0;
}

// ---------------- one-time weight fragment pack + W@a precompute ----------------
// block b = layer b: b0 -> (W0,as0,ad0); b1/b2 -> Wl[b-1] etc.
__global__ __launch_bounds__(256) void k_wcvt(
    const float* __restrict__ W0, const float* __restrict__ as0, const float* __restrict__ ad0,
    const float* __restrict__ Wl, const float* __restrict__ asl, const float* __restrict__ adl,
    uint4* __restrict__ Wf3, float* __restrict__ waf3)
{
    __shared__ float wa[2][64];
    int L = blockIdx.x, t = threadIdx.x;
    const float* W  = (L==0) ? W0  : Wl  + (L-1)*HD*HD;
    const float* as = (L==0) ? as0 : asl + (L-1)*HD;
    const float* ad = (L==0) ? ad0 : adl + (L-1)*HD;
    if(t < 128){
        int sd = t>>6, k = t&63;
        const float* av = sd ? ad : as;
        float acc = 0.f;
        for(int c=0;c<HD;c++) acc = fmaf(W[k*HD+c], av[c], acc);
        wa[sd][k] = acc;
    }
    __syncthreads();
    // W fragments: tile(4) x s(2) x lane(64)
    for(int it = t; it < 512; it += 256){
        int lane = it&63, s = (it>>6)&1, tile = it>>7;
        int g = lane>>4, m = lane&15, c = tile*16 + m;
        ushort_t h[8];
        #pragma unroll
        for(int i=0;i<8;i++){
            int k = s*32 + g*4 + (i&3) + 16*(i>>2);
            h[i] = __half_as_ushort(__float2half_rn(W[k*HD + c]));
        }
        uint4 q;
        q.x = (uint_t)h[0] | ((uint_t)h[1]<<16);
        q.y = (uint_t)h[2] | ((uint_t)h[3]<<16);
        q.z = (uint_t)h[4] | ((uint_t)h[5]<<16);
        q.w = (uint_t)h[6] | ((uint_t)h[7]<<16);
        Wf3[(size_t)L*512 + (tile*2+s)*64 + lane] = q;
    }
    // wa fragments (f32, A-frag order): sd(2) x j4(4) x lane(64) float4
    if(t < 128){
        int lane = t&63, sd = t>>6, g = lane>>4;
        #pragma unroll
        for(int j4=0;j4<4;j4++){
            float v[4];
            #pragma unroll
            for(int e=0;e<4;e++){
                int j = j4*4 + e;
                int k = (j>>3)*32 + g*4 + (j&3) + 16*((j>>2)&1);
                v[e] = wa[sd][k];
            }
            float* dstp = waf3 + ((size_t)L*8 + sd*4 + j4)*64*4 + lane*4;
            dstp[0]=v[0]; dstp[1]=v[1]; dstp[2]=v[2]; dstp[3]=v[3];
        }
    }
}

// ---------------- MFMA GEMM: 16 rows x 64 cols per wave ----------------
// Hw pair-layout: row dword w = p*16+c holds fp16 cols (32p+c, 32p+16+c)
__global__ __launch_bounds__(256) void k_gemm(
    const float* __restrict__ IN, const float* __restrict__ addrow,
    const float* __restrict__ addtab, const int* __restrict__ hb,
    const uint4* __restrict__ Wf, const float* __restrict__ waf,
    uint_t* __restrict__ Hw, float* __restrict__ AS, float* __restrict__ AD,
    int n)
{
    __shared__ ushort_t sx[4][1024];   // per-wave 16x64 fp16 tile, XOR-swizzled
    int t = threadIdx.x, lane = t&63, wv = t>>6;
    int g = lane>>4, m = lane&15;
    ushort_t* sb = sx[wv];

    H8U B[8];
    #pragma unroll
    for(int f=0; f<8; f++){
        uint4 q = Wf[f*64 + lane];
        B[f].u[0]=q.x; B[f].u[1]=q.y; B[f].u[2]=q.z; B[f].u[3]=q.w;
    }
    vf4 wS[4], wD[4];
    #pragma unroll
    for(int j4=0;j4<4;j4++){
        const float* ps = waf + ((size_t)0*4 + j4)*256 + lane*4;
        const float* pd = waf + ((size_t)1*4 + j4)*256 + lane*4;
        wS[j4] = vf4{ps[0],ps[1],ps[2],ps[3]};
        wD[j4] = vf4{pd[0],pd[1],pd[2],pd[3]};
    }
    float ar0=0,ar1=0,ar2=0,ar3=0;
    if(addrow){
        const float* a = &addrow[m*4];
        ar0=a[0]; ar1=a[1]; ar2=a[2]; ar3=a[3];
    }

    int ntiles = (n + 15) >> 4;
    int wgid = (blockIdx.x*256 + t) >> 6;
    int nw = gridDim.x*4;
    for(int tile = wgid; tile < ntiles; tile += nw){
        int rb = tile*16;
        // ---- stage 16 rows (fp16, swizzled) ----
        #pragma unroll
        for(int p=0;p<4;p++){
            int row = p*4 + g;
            int rowc = min(rb + row, n-1);
            float4 x4 = *(const float4*)&IN[(size_t)rowc*HD + m*4];
            if(addrow){ x4.x+=ar0; x4.y+=ar1; x4.z+=ar2; x4.w+=ar3; }
            if(addtab){
                int b = hb[rowc];
                float4 a4 = *(const float4*)&addtab[b*HD + m*4];
                x4.x+=a4.x; x4.y+=a4.y; x4.z+=a4.z; x4.w+=a4.w;
            }
            uint2 pq; pq.x = pk2(x4.x, x4.y); pq.y = pk2(x4.z, x4.w);
            int idx = (row*64 + m*4) ^ ((row&7)<<3);
            *(uint2*)&sb[idx] = pq;
        }
        // ---- A fragments (row = m) ----
        int xr = (m&7)<<3;
        H8U A0, A1;
        {
            uint2 c0 = *(uint2*)&sb[(m*64 +  0 + g*4) ^ xr];
            uint2 c1 = *(uint2*)&sb[(m*64 + 16 + g*4) ^ xr];
            A0.u[0]=c0.x; A0.u[1]=c0.y; A0.u[2]=c1.x; A0.u[3]=c1.y;
            uint2 c2 = *(uint2*)&sb[(m*64 + 32 + g*4) ^ xr];
            uint2 c3 = *(uint2*)&sb[(m*64 + 48 + g*4) ^ xr];
            A1.u[0]=c2.x; A1.u[1]=c2.y; A1.u[2]=c3.x; A1.u[3]=c3.y;
        }
        // ---- attention scalars: AS = x . (W@a_src) ----
        float t1 = 0.f, t2 = 0.f;
        #pragma unroll
        for(int i=0;i<8;i++){
            float xv = (float)A0.v[i];
            t1 = fmaf(xv, wS[i>>2][i&3], t1);
            t2 = fmaf(xv, wD[i>>2][i&3], t2);
        }
        #pragma unroll
        for(int i=0;i<8;i++){
            float xv = (float)A1.v[i];
            t1 = fmaf(xv, wS[2+(i>>2)][i&3], t1);
            t2 = fmaf(xv, wD[2+(i>>2)][i&3], t2);
        }
        t1 += __shfl_xor(t1, 16, 64); t1 += __shfl_xor(t1, 32, 64);
        t2 += __shfl_xor(t2, 16, 64); t2 += __shfl_xor(t2, 32, 64);
        if(lane < 16 && rb + lane < n){ AS[rb+lane] = t1; AD[rb+lane] = t2; }
        // ---- MFMA: 4 col-tiles x 2 k-steps ----
        vf4 z = {0.f,0.f,0.f,0.f};
        vf4 a0 = __builtin_amdgcn_mfma_f32_16x16x32_f16(A0.v, B[0].v, z, 0,0,0);
        a0     = __builtin_amdgcn_mfma_f32_16x16x32_f16(A1.v, B[1].v, a0, 0,0,0);
        vf4 a1 = __builtin_amdgcn_mfma_f32_16x16x32_f16(A0.v, B[2].v, z, 0,0,0);
        a1     = __builtin_amdgcn_mfma_f32_16x16x32_f16(A1.v, B[3].v, a1, 0,0,0);
        vf4 a2 = __builtin_amdgcn_mfma_f32_16x16x32_f16(A0.v, B[4].v, z, 0,0,0);
        a2     = __builtin_amdgcn_mfma_f32_16x16x32_f16(A1.v, B[5].v, a2, 0,0,0);
        vf4 a3 = __builtin_amdgcn_mfma_f32_16x16x32_f16(A0.v, B[6].v, z, 0,0,0);
        a3     = __builtin_amdgcn_mfma_f32_16x16x32_f16(A1.v, B[7].v, a3, 0,0,0);
        // ---- epilogue: pack pairs, store Hw ----
        #pragma unroll
        for(int rr=0;rr<4;rr++){
            int row = rb + g*4 + rr;
            if(row < n){
                Hw[(size_t)row*32 + m]      = pk2(a0[rr], a1[rr]);   // cols m, m+16
                Hw[(size_t)row*32 + 16 + m] = pk2(a2[rr], a3[rr]);   // cols 32+m, 48+m
            }
        }
    }
}

// ---------------- wave-per-dst GAT aggregate; pair-layout H ----------------
__global__ __launch_bounds__(256) void k_agg(
    const uint_t* __restrict__ Hb, const float* __restrict__ AS, const float* __restrict__ AD,
    const int* __restrict__ rp, const int* __restrict__ col,
    const float* __restrict__ bias, float* __restrict__ OUT, int n)
{
    int t = threadIdx.x, lane = t & 63;
    int half = lane >> 5;
    int wl = lane & 31;
    int colA = 32*(wl>>4) + (wl&15);
    int colB = colA + 16;
    float bsx = bias[colA], bsy = bias[colB];
    int wv  = (blockIdx.x*256 + t) >> 6;
    int nwv = gridDim.x*4;
    for(int dst = wv; dst < n; dst += nwv){
        float ad = AD[dst];
        float wself = __expf(lrelu(AS[dst] + ad));
        float s = wself;
        uint_t hw = Hb[(size_t)dst*32 + wl];
        float2 acc;
        if(half == 0){ acc.x = cvt_h(hw,0)*wself; acc.y = cvt_h(hw,16)*wself; }
        else         { acc.x = 0.f;               acc.y = 0.f; }
        int beg = rp[dst], end = rp[dst+1];
        for(int base = beg; base < end; base += 64){
            int j = base + lane;
            int sj = 0; float wj = 0.f;
            if(j < end){ sj = col[j]; wj = __expf(lrelu(AS[sj] + ad)); }
            float sc = wj;
            #pragma unroll
            for(int o=32;o;o>>=1) sc += __shfl_xor(sc,o,64);
            s += sc;
            int cnt = min(64, end - base);
            int it = (cnt + 1) >> 1;
            int i = 0;
            for(; i + 4 <= it; i += 4){
                int q0 = 2*i + half, q1 = q0+2, q2 = q0+4, q3 = q0+6;
                float w0=__shfl(wj,q0,64), w1=__shfl(wj,q1,64), w2=__shfl(wj,q2,64), w3=__shfl(wj,q3,64);
                int   s0=__shfl(sj,q0,64), s1=__shfl(sj,q1,64), s2=__shfl(sj,q2,64), s3=__shfl(sj,q3,64);
                uint_t v0 = Hb[(size_t)s0*32 + wl];
                uint_t v1 = Hb[(size_t)s1*32 + wl];
                uint_t v2 = Hb[(size_t)s2*32 + wl];
                uint_t v3 = Hb[(size_t)s3*32 + wl];
                acc.x = fmaf(w0, cvt_h(v0,0),  acc.x);
                acc.y = fmaf(w0, cvt_h(v0,16), acc.y);
                acc.x = fmaf(w1, cvt_h(v1,0),  acc.x);
                acc.y = fmaf(w1, cvt_h(v1,16), acc.y);
                acc.x = fmaf(w2, cvt_h(v2,0),  acc.x);
                acc.y = fmaf(w2, cvt_h(v2,16), acc.y);
                acc.x = fmaf(w3, cvt_h(v3,0),  acc.x);
                acc.y = fmaf(w3, cvt_h(v3,16), acc.y);
            }
            for(; i < it; i++){
                int q = 2*i + half;
                float wq = __shfl(wj,q,64);
                int   sq = __shfl(sj,q,64);
                uint_t v = Hb[(size_t)sq*32 + wl];
                acc.x = fmaf(wq, cvt_h(v,0),  acc.x);
                acc.y = fmaf(wq, cvt_h(v,16), acc.y);
            }
        }
        acc.x += __shfl_xor(acc.x, 32, 64);
        acc.y += __shfl_xor(acc.y, 32, 64);
        if(half == 0){
            float inv = 1.f/(s + 1e-16f);
            OUT[(size_t)dst*HD + colA] = fmaf(acc.x, inv, bsx);
            OUT[(size_t)dst*HD + colB] = fmaf(acc.y, inv, bsy);
        }
    }
}

// ---------------- virtual-node segment sum: 1024-thread blocks, unroll-4 ----------------
__global__ __launch_bounds__(1024) void k_vnseg(const float* __restrict__ OUT, const int* __restrict__ hb,
                                                float* __restrict__ vnS, int n){
    __shared__ float acc[HNUM*HD];
    int t = threadIdx.x, lane = t & 63;
    for(int i=t;i<HNUM*HD;i+=1024) acc[i] = 0.f;
    __syncthreads();
    int wv  = (blockIdx.x*1024 + t) >> 6;
    int nwv = gridDim.x*16;
    for(int node = wv*4; node < n; node += nwv*4){
        bool o1 = node+1 < n, o2 = node+2 < n, o3 = node+3 < n;
        float v0 = OUT[(size_t)node*HD + lane];
        float v1 = o1 ? OUT[(size_t)(node+1)*HD + lane] : 0.f;
        float v2 = o2 ? OUT[(size_t)(node+2)*HD + lane] : 0.f;
        float v3 = o3 ? OUT[(size_t)(node+3)*HD + lane] : 0.f;
        int b0 = hb[node];
        int b1 = o1 ? hb[node+1] : 0;
        int b2 = o2 ? hb[node+2] : 0;
        int b3 = o3 ? hb[node+3] : 0;
        atomicAdd(&acc[b0*HD + lane], v0);
        if(o1) atomicAdd(&acc[b1*HD + lane], v1);
        if(o2) atomicAdd(&acc[b2*HD + lane], v2);
        if(o3) atomicAdd(&acc[b3*HD + lane], v3);
    }
    __syncthreads();
    for(int i=t;i<HNUM*HD;i+=1024) atomicAdd(&vnS[i], acc[i]);
}

// ---------------- vn update + both MLPs, fully in registers ----------------
__global__ __launch_bounds__(256) void k_vn(
    const float* __restrict__ vnS, const float* __restrict__ vne,
    const float* __restrict__ W1, const float* __restrict__ B1,
    const float* __restrict__ W2, const float* __restrict__ B2,
    float* __restrict__ vnD)
{
    int lane = threadIdx.x & 63;
    int w = (blockIdx.x*256 + threadIdx.x) >> 6;
    const int R = HNUM/32;
    float a[R], br[R];
    float ve = vne[lane];
    #pragma unroll
    for(int r=0;r<R;r++){
        int b = w*R + r;
        a[r] = vnS[b*HD + lane] + ve + ve;
    }
    for(int j=0;j<NMLP;j++){
        const float* w1 = W1 + j*HD*HD; const float* b1 = B1 + j*HD;
        const float* w2 = W2 + j*HD*HD; const float* b2 = B2 + j*HD;
        #pragma unroll
        for(int r=0;r<R;r++){
            float tacc = b1[lane];
            #pragma unroll
            for(int in=0;in<HD;in++) tacc = fmaf(__shfl(a[r], in, 64), w1[in*HD + lane], tacc);
            br[r] = fmaxf(tacc, 0.f);
        }
        #pragma unroll
        for(int r=0;r<R;r++){
            float tacc = b2[lane];
            #pragma unroll
            for(int in=0;in<HD;in++) tacc = fmaf(__shfl(br[r], in, 64), w2[in*HD + lane], tacc);
            a[r] = fmaxf(tacc, 0.f);
        }
    }
    #pragma unroll
    for(int r=0;r<R;r++){
        int b = w*R + r;
        vnD[b*HD + lane] = a[r];
    }
}

extern "C" void kernel_launch(void* const* d_in, const int* in_sizes, int n_in,
                              void* d_out, int out_size, void* d_ws, size_t ws_size,
                              hipStream_t stream)
{
    const float* x   = (const float*)d_in[0];
    const int*   ei  = (const int*)d_in[1];
    const int*   hb  = (const int*)d_in[2];
    const float* W0  = (const float*)d_in[5];
    const float* as0 = (const float*)d_in[6];
    const float* ad0 = (const float*)d_in[7];
    const float* b0  = (const float*)d_in[8];
    const float* Wl  = (const float*)d_in[9];
    const float* asl = (const float*)d_in[10];
    const float* adl = (const float*)d_in[11];
    const float* bl  = (const float*)d_in[12];
    const float* vne = (const float*)d_in[13];
    const float* mW1 = (const float*)d_in[14];
    const float* mb1 = (const float*)d_in[15];
    const float* mW2 = (const float*)d_in[16];
    const float* mb2 = (const float*)d_in[17];

    int N = in_sizes[0]/HD;
    int E = in_sizes[1]/2;
    const int* src = ei;
    const int* dst = ei + E;
    int NB = (N + (1<<BSH) - 1) >> BSH;

    char* p = (char*)d_ws;
    float* f_h   = (float*)p; p += (size_t)N*HD*4;   // fp16 H region + CSR alias
    float* f_as  = (float*)p; p += (size_t)N*4;
    float* f_ad  = (float*)p; p += (size_t)N*4;
    float* f_vnD = (float*)p; p += HNUM*HD*4;
    float* f_vnS = (float*)p; p += HNUM*HD*4;
    int*   i_rp  = (int*)p;   p += (size_t)(N+1)*4;
    int*   i_deg = (int*)p;   p += (size_t)N*4;
    int*   i_fill= (int*)p;   p += (size_t)N*4;
    int*   i_gb  = (int*)p;   p += MAXNB*4;
    int*   i_bb  = (int*)p;   p += MAXNB*4;
    int*   i_gc  = (int*)p;   p += MAXNB*4;
    int*   i_col = (int*)p;   p += (size_t)E*4;
    int*   i_bs  = (int*)p;   p += 4096;
    uint4* Wf3   = (uint4*)p; p += 3*512*16;         // packed W fragments
    float* waf3  = (float*)p; p += 3*8*64*4*4;       // W@a fragments (f32)
    int2*  bdata = (int2*)f_h;
    uint_t* Hw   = (uint_t*)f_h;

    float* outb = (float*)d_out;

    int nb = (N + 1023)/1024;
    // one-time weight pack (3 blocks = 3 layers)
    k_wcvt<<<3, 256, 0, stream>>>(W0, as0, ad0, Wl, asl, adl, Wf3, waf3);

    hipMemsetAsync(i_fill, 0, (size_t)N*4 + MAXNB*4, stream);
    k_bcnt <<<512, 256, 0, stream>>>(dst, i_gb, E, NB);
    k_bscan<<<1, 512, 0, stream>>>(i_gb, i_bb, i_gc, NB);
    k_bin  <<<(E+EPB-1)/EPB, 256, 0, stream>>>(src, dst, i_gc, bdata, E, NB);
    k_bhist<<<NB, 256, 0, stream>>>(bdata, i_bb, i_gb, i_deg, N);
    k_scan1<<<nb, 1024, 0, stream>>>(i_deg, i_rp + 1, i_bs, N);
    k_scan2<<<1, 1024, 0, stream>>>(i_bs, nb);
    k_scan3<<<nb, 1024, 0, stream>>>(i_rp, i_bs, N);
    k_bscat<<<NB, 256, 0, stream>>>(bdata, i_bb, i_gb, i_rp, i_fill, i_col);

    int ga = 4096;
    int gg = 768;    // MFMA gemm: 3072 waves x ~2 tiles
    // conv0: GAT(x, W0)
    k_gemm<<<gg, 256, 0, stream>>>(x, nullptr, nullptr, hb, Wf3, waf3, Hw, f_as, f_ad, N);
    k_agg <<<ga, 256, 0, stream>>>(Hw, f_as, f_ad, i_rp, i_col, b0, outb, N);
    // conv1: GAT(out0 + vn_emb, Wl[0])
    k_gemm<<<gg, 256, 0, stream>>>(outb, vne, nullptr, hb, Wf3 + 512, waf3 + 2048, Hw, f_as, f_ad, N);
    k_agg <<<ga, 256, 0, stream>>>(Hw, f_as, f_ad, i_rp, i_col, bl, outb, N);
    // vn update: vnD = MLPs(segsum(out1) + 2*vne)
    hipMemsetAsync(f_vnS, 0, HNUM*HD*4, stream);
    k_vnseg<<<256, 1024, 0, stream>>>(outb, hb, f_vnS, N);
    k_vn  <<<8, 256, 0, stream>>>(f_vnS, vne, mW1, mb1, mW2, mb2, f_vnD);
    // conv2: GAT(out1 + vnD[hb], Wl[1]) -> final output
    k_gemm<<<gg, 256, 0, stream>>>(outb, nullptr, f_vnD, hb, Wf3 + 1024, waf3 + 4096, Hw, f_as, f_ad, N);
    k_agg <<<ga, 256, 0, stream>>>(Hw, f_as, f_ad, i_rp, i_col, bl + HD, outb, N);
}

// Round 8
// 353.667 us; speedup vs baseline: 2.2819x; 1.1054x over previous
//
#include <hip/hip_runtime.h>
#include <hip/hip_fp16.h>
#include <math.h>

#define HD 64
#define HNUM 128
#define NMLP 2
#define BSH 8              // 256 dst-nodes per bucket
#define MAXNB 512
#define EPB 2048           // edges per k_bin block

typedef unsigned int uint_t;
typedef unsigned short ushort_t;
typedef _Float16 h8 __attribute__((ext_vector_type(8)));
typedef float vf4 __attribute__((ext_vector_type(4)));

union H8U { h8 v; uint_t u[4]; };

__device__ __forceinline__ float lrelu(float x){ return fmaxf(x, 0.2f*x); }

__device__ __forceinline__ float cvt_h(uint_t wv, uint_t sh){
    __half_raw hr; hr.x = (ushort_t)(wv >> sh);
    return __half2float((__half)hr);
}
__device__ __forceinline__ uint_t pk2(float a, float b){
    return (uint_t)__half_as_ushort(__float2half_rn(a)) |
           ((uint_t)__half_as_ushort(__float2half_rn(b)) << 16);
}

// ---------------- CSR build: bucketed counting sort ----------------
__global__ __launch_bounds__(256) void k_bcnt(const int* __restrict__ dst, int* __restrict__ gb,
                                              int E, int NB){
    __shared__ int h[MAXNB];
    int t = threadIdx.x;
    for(int i=t;i<NB;i+=256) h[i] = 0;
    __syncthreads();
    for(int e = blockIdx.x*256 + t; e < E; e += gridDim.x*256)
        atomicAdd(&h[dst[e]>>BSH], 1);
    __syncthreads();
    for(int i=t;i<NB;i+=256) if(h[i]) atomicAdd(&gb[i], h[i]);
}

__global__ __launch_bounds__(512) void k_bscan(const int* __restrict__ gb, int* __restrict__ bbase,
                                               int* __restrict__ gcur, int NB){
    __shared__ int s[512];
    int t = threadIdx.x;
    int v = (t < NB) ? gb[t] : 0;
    s[t] = v; __syncthreads();
    for(int o=1;o<512;o<<=1){
        int u = (t >= o) ? s[t-o] : 0;
        __syncthreads();
        s[t] += u;
        __syncthreads();
    }
    if(t < NB){ int ex = s[t] - v; bbase[t] = ex; gcur[t] = ex; }
}

__global__ __launch_bounds__(256) void k_bin(const int* __restrict__ src, const int* __restrict__ dst,
                                             int* __restrict__ gcur, int2* __restrict__ bdata,
                                             int E, int NB){
    __shared__ int cnt[MAXNB];
    __shared__ int base[MAXNB];
    int t = threadIdx.x;
    for(int i=t;i<NB;i+=256) cnt[i] = 0;
    __syncthreads();
    int s0 = blockIdx.x*EPB;
    int sv[8], dv[8], off[8];
    #pragma unroll
    for(int i=0;i<8;i++){
        int e = s0 + i*256 + t;
        if(e < E){
            sv[i] = src[e]; dv[i] = dst[e];
            off[i] = atomicAdd(&cnt[dv[i]>>BSH], 1);
        }
    }
    __syncthreads();
    for(int i=t;i<NB;i+=256) base[i] = cnt[i] ? atomicAdd(&gcur[i], cnt[i]) : 0;
    __syncthreads();
    #pragma unroll
    for(int i=0;i<8;i++){
        int e = s0 + i*256 + t;
        if(e < E) bdata[base[dv[i]>>BSH] + off[i]] = make_int2(sv[i], dv[i]);
    }
}

// fused per-bucket: LDS hist -> LDS scan -> rowptr slice -> LDS-cursor scatter
__global__ __launch_bounds__(256) void k_bfuse(const int2* __restrict__ bdata, const int* __restrict__ bbase,
                                               const int* __restrict__ gb, int* __restrict__ rp,
                                               int* __restrict__ col, int n, int NB, int E){
    __shared__ int h[256];
    __shared__ int sc[256];
    int b = blockIdx.x, t = threadIdx.x;
    int beg = bbase[b], cnt = gb[b];
    h[t] = 0; __syncthreads();
    for(int i=t;i<cnt;i+=256) atomicAdd(&h[bdata[beg+i].y & 255], 1);
    __syncthreads();
    int v = h[t];
    sc[t] = v; __syncthreads();
    for(int o=1;o<256;o<<=1){
        int u = (t >= o) ? sc[t-o] : 0;
        __syncthreads();
        sc[t] += u;
        __syncthreads();
    }
    int excl = sc[t] - v;
    int node = (b<<BSH) + t;
    if(node < n) rp[node] = beg + excl;
    if(b == NB-1 && t == 255) rp[n] = E;
    __syncthreads();
    sc[t] = excl;           // per-node local cursor
    __syncthreads();
    for(int i=t;i<cnt;i+=256){
        int2 e = bdata[beg+i];
        int pos = atomicAdd(&sc[e.y & 255], 1);
        col[beg + pos] = e.x;
    }
}

// ---------------- one-time weight fragment pack + W@a precompute ----------------
__global__ __launch_bounds__(256) void k_wcvt(
    const float* __restrict__ W0, const float* __restrict__ as0, const float* __restrict__ ad0,
    const float* __restrict__ Wl, const float* __restrict__ asl, const float* __restrict__ adl,
    uint4* __restrict__ Wf3, float* __restrict__ waf3)
{
    __shared__ float wa[2][64];
    int L = blockIdx.x, t = threadIdx.x;
    const float* W  = (L==0) ? W0  : Wl  + (L-1)*HD*HD;
    const float* as = (L==0) ? as0 : asl + (L-1)*HD;
    const float* ad = (L==0) ? ad0 : adl + (L-1)*HD;
    if(t < 128){
        int sd = t>>6, k = t&63;
        const float* av = sd ? ad : as;
        float acc = 0.f;
        for(int c=0;c<HD;c++) acc = fmaf(W[k*HD+c], av[c], acc);
        wa[sd][k] = acc;
    }
    __syncthreads();
    for(int it = t; it < 512; it += 256){
        int lane = it&63, s = (it>>6)&1, tile = it>>7;
        int g = lane>>4, m = lane&15, c = tile*16 + m;
        ushort_t h[8];
        #pragma unroll
        for(int i=0;i<8;i++){
            int k = s*32 + g*4 + (i&3) + 16*(i>>2);
            h[i] = __half_as_ushort(__float2half_rn(W[k*HD + c]));
        }
        uint4 q;
        q.x = (uint_t)h[0] | ((uint_t)h[1]<<16);
        q.y = (uint_t)h[2] | ((uint_t)h[3]<<16);
        q.z = (uint_t)h[4] | ((uint_t)h[5]<<16);
        q.w = (uint_t)h[6] | ((uint_t)h[7]<<16);
        Wf3[(size_t)L*512 + (tile*2+s)*64 + lane] = q;
    }
    if(t < 128){
        int lane = t&63, sd = t>>6, g = lane>>4;
        #pragma unroll
        for(int j4=0;j4<4;j4++){
            float v[4];
            #pragma unroll
            for(int e=0;e<4;e++){
                int j = j4*4 + e;
                int k = (j>>3)*32 + g*4 + (j&3) + 16*((j>>2)&1);
                v[e] = wa[sd][k];
            }
            float* dstp = waf3 + ((size_t)L*8 + sd*4 + j4)*64*4 + lane*4;
            dstp[0]=v[0]; dstp[1]=v[1]; dstp[2]=v[2]; dstp[3]=v[3];
        }
    }
}

// ---------------- MFMA GEMM: 16 rows x 64 cols per wave ----------------
// Hw pair-layout: row dword w holds fp16 cols (32*(w>>4)+(w&15), same+16)
__global__ __launch_bounds__(256) void k_gemm(
    const float* __restrict__ IN, const float* __restrict__ addrow,
    const float* __restrict__ addtab, const int* __restrict__ hb,
    const uint4* __restrict__ Wf, const float* __restrict__ waf,
    uint_t* __restrict__ Hw, float* __restrict__ AS, float* __restrict__ AD,
    int n)
{
    __shared__ ushort_t sx[4][1024];
    int t = threadIdx.x, lane = t&63, wv = t>>6;
    int g = lane>>4, m = lane&15;
    ushort_t* sb = sx[wv];

    H8U B[8];
    #pragma unroll
    for(int f=0; f<8; f++){
        uint4 q = Wf[f*64 + lane];
        B[f].u[0]=q.x; B[f].u[1]=q.y; B[f].u[2]=q.z; B[f].u[3]=q.w;
    }
    vf4 wS[4], wD[4];
    #pragma unroll
    for(int j4=0;j4<4;j4++){
        const float* ps = waf + ((size_t)0*4 + j4)*256 + lane*4;
        const float* pd = waf + ((size_t)1*4 + j4)*256 + lane*4;
        wS[j4] = vf4{ps[0],ps[1],ps[2],ps[3]};
        wD[j4] = vf4{pd[0],pd[1],pd[2],pd[3]};
    }
    float ar0=0,ar1=0,ar2=0,ar3=0;
    if(addrow){
        const float* a = &addrow[m*4];
        ar0=a[0]; ar1=a[1]; ar2=a[2]; ar3=a[3];
    }

    int ntiles = (n + 15) >> 4;
    int wgid = (blockIdx.x*256 + t) >> 6;
    int nw = gridDim.x*4;
    for(int tile = wgid; tile < ntiles; tile += nw){
        int rb = tile*16;
        #pragma unroll
        for(int p=0;p<4;p++){
            int row = p*4 + g;
            int rowc = min(rb + row, n-1);
            float4 x4 = *(const float4*)&IN[(size_t)rowc*HD + m*4];
            if(addrow){ x4.x+=ar0; x4.y+=ar1; x4.z+=ar2; x4.w+=ar3; }
            if(addtab){
                int b = hb[rowc];
                float4 a4 = *(const float4*)&addtab[b*HD + m*4];
                x4.x+=a4.x; x4.y+=a4.y; x4.z+=a4.z; x4.w+=a4.w;
            }
            uint2 pq; pq.x = pk2(x4.x, x4.y); pq.y = pk2(x4.z, x4.w);
            int idx = (row*64 + m*4) ^ ((row&7)<<3);
            *(uint2*)&sb[idx] = pq;
        }
        int xr = (m&7)<<3;
        H8U A0, A1;
        {
            uint2 c0 = *(uint2*)&sb[(m*64 +  0 + g*4) ^ xr];
            uint2 c1 = *(uint2*)&sb[(m*64 + 16 + g*4) ^ xr];
            A0.u[0]=c0.x; A0.u[1]=c0.y; A0.u[2]=c1.x; A0.u[3]=c1.y;
            uint2 c2 = *(uint2*)&sb[(m*64 + 32 + g*4) ^ xr];
            uint2 c3 = *(uint2*)&sb[(m*64 + 48 + g*4) ^ xr];
            A1.u[0]=c2.x; A1.u[1]=c2.y; A1.u[2]=c3.x; A1.u[3]=c3.y;
        }
        float t1 = 0.f, t2 = 0.f;
        #pragma unroll
        for(int i=0;i<8;i++){
            float xv = (float)A0.v[i];
            t1 = fmaf(xv, wS[i>>2][i&3], t1);
            t2 = fmaf(xv, wD[i>>2][i&3], t2);
        }
        #pragma unroll
        for(int i=0;i<8;i++){
            float xv = (float)A1.v[i];
            t1 = fmaf(xv, wS[2+(i>>2)][i&3], t1);
            t2 = fmaf(xv, wD[2+(i>>2)][i&3], t2);
        }
        t1 += __shfl_xor(t1, 16, 64); t1 += __shfl_xor(t1, 32, 64);
        t2 += __shfl_xor(t2, 16, 64); t2 += __shfl_xor(t2, 32, 64);
        if(lane < 16 && rb + lane < n){ AS[rb+lane] = t1; AD[rb+lane] = t2; }
        vf4 z = {0.f,0.f,0.f,0.f};
        vf4 a0 = __builtin_amdgcn_mfma_f32_16x16x32_f16(A0.v, B[0].v, z, 0,0,0);
        a0     = __builtin_amdgcn_mfma_f32_16x16x32_f16(A1.v, B[1].v, a0, 0,0,0);
        vf4 a1 = __builtin_amdgcn_mfma_f32_16x16x32_f16(A0.v, B[2].v, z, 0,0,0);
        a1     = __builtin_amdgcn_mfma_f32_16x16x32_f16(A1.v, B[3].v, a1, 0,0,0);
        vf4 a2 = __builtin_amdgcn_mfma_f32_16x16x32_f16(A0.v, B[4].v, z, 0,0,0);
        a2     = __builtin_amdgcn_mfma_f32_16x16x32_f16(A1.v, B[5].v, a2, 0,0,0);
        vf4 a3 = __builtin_amdgcn_mfma_f32_16x16x32_f16(A0.v, B[6].v, z, 0,0,0);
        a3     = __builtin_amdgcn_mfma_f32_16x16x32_f16(A1.v, B[7].v, a3, 0,0,0);
        #pragma unroll
        for(int rr=0;rr<4;rr++){
            int row = rb + g*4 + rr;
            if(row < n){
                Hw[(size_t)row*32 + m]      = pk2(a0[rr], a1[rr]);
                Hw[(size_t)row*32 + 16 + m] = pk2(a2[rr], a3[rr]);
            }
        }
    }
}

// ---------------- GAT aggregate: edge-quad layout (4 edges/iter, uint2/lane) ----------------
__global__ __launch_bounds__(256) void k_agg(
    const uint_t* __restrict__ Hb, const float* __restrict__ AS, const float* __restrict__ AD,
    const int* __restrict__ rp, const int* __restrict__ col,
    const float* __restrict__ bias, float* __restrict__ OUT, int n)
{
    int t = threadIdx.x, lane = t & 63;
    int g = lane >> 4;          // edge slot 0..3
    int p = lane & 15;          // dword-pair position: dwords 2p, 2p+1
    int w0 = 2*p, w1 = 2*p+1;
    int c00 = 32*(w0>>4)+(w0&15), c01 = c00+16;
    int c10 = 32*(w1>>4)+(w1&15), c11 = c10+16;
    float b00 = bias[c00], b01 = bias[c01], b10 = bias[c10], b11 = bias[c11];
    int wv  = (blockIdx.x*256 + t) >> 6;
    int nwv = gridDim.x*4;
    for(int dst = wv; dst < n; dst += nwv){
        float ad = AD[dst];
        float wself = __expf(lrelu(AS[dst] + ad));
        float s = wself;
        float4 acc = {0.f,0.f,0.f,0.f};
        {
            uint2 hd = *(const uint2*)&Hb[(size_t)dst*32 + w0];
            if(g == 0){
                acc.x = cvt_h(hd.x,0)*wself; acc.y = cvt_h(hd.x,16)*wself;
                acc.z = cvt_h(hd.y,0)*wself; acc.w = cvt_h(hd.y,16)*wself;
            }
        }
        int beg = rp[dst], end = rp[dst+1];
        for(int base = beg; base < end; base += 64){
            int j = base + lane;
            int sj = 0; float wj = 0.f;
            if(j < end){ sj = col[j]; wj = __expf(lrelu(AS[sj] + ad)); }
            float sc = wj;
            #pragma unroll
            for(int o=32;o;o>>=1) sc += __shfl_xor(sc,o,64);
            s += sc;
            int cnt = min(64, end - base);
            int it = (cnt + 3) >> 2;      // quads of edges; lanes with q>=cnt have wj=0
            int i = 0;
            for(; i + 2 <= it; i += 2){
                int qa = 4*i + g, qb = qa + 4;
                float wa = __shfl(wj, qa, 64), wb = __shfl(wj, qb, 64);
                int   sa = __shfl(sj, qa, 64), sb_ = __shfl(sj, qb, 64);
                uint2 va = *(const uint2*)&Hb[(size_t)sa*32 + w0];
                uint2 vb = *(const uint2*)&Hb[(size_t)sb_*32 + w0];
                acc.x = fmaf(wa, cvt_h(va.x,0),  acc.x);
                acc.y = fmaf(wa, cvt_h(va.x,16), acc.y);
                acc.z = fmaf(wa, cvt_h(va.y,0),  acc.z);
                acc.w = fmaf(wa, cvt_h(va.y,16), acc.w);
                acc.x = fmaf(wb, cvt_h(vb.x,0),  acc.x);
                acc.y = fmaf(wb, cvt_h(vb.x,16), acc.y);
                acc.z = fmaf(wb, cvt_h(vb.y,0),  acc.z);
                acc.w = fmaf(wb, cvt_h(vb.y,16), acc.w);
            }
            for(; i < it; i++){
                int q = 4*i + g;
                float wq = __shfl(wj, q, 64);
                int   sq = __shfl(sj, q, 64);
                uint2 v = *(const uint2*)&Hb[(size_t)sq*32 + w0];
                acc.x = fmaf(wq, cvt_h(v.x,0),  acc.x);
                acc.y = fmaf(wq, cvt_h(v.x,16), acc.y);
                acc.z = fmaf(wq, cvt_h(v.y,0),  acc.z);
                acc.w = fmaf(wq, cvt_h(v.y,16), acc.w);
            }
        }
        acc.x += __shfl_xor(acc.x,16,64); acc.x += __shfl_xor(acc.x,32,64);
        acc.y += __shfl_xor(acc.y,16,64); acc.y += __shfl_xor(acc.y,32,64);
        acc.z += __shfl_xor(acc.z,16,64); acc.z += __shfl_xor(acc.z,32,64);
        acc.w += __shfl_xor(acc.w,16,64); acc.w += __shfl_xor(acc.w,32,64);
        if(g == 0){
            float inv = 1.f/(s + 1e-16f);
            OUT[(size_t)dst*HD + c00] = fmaf(acc.x, inv, b00);
            OUT[(size_t)dst*HD + c01] = fmaf(acc.y, inv, b01);
            OUT[(size_t)dst*HD + c10] = fmaf(acc.z, inv, b10);
            OUT[(size_t)dst*HD + c11] = fmaf(acc.w, inv, b11);
        }
    }
}

// ---------------- virtual-node segment sum: 1024-thread blocks, unroll-4 ----------------
__global__ __launch_bounds__(1024) void k_vnseg(const float* __restrict__ OUT, const int* __restrict__ hb,
                                                float* __restrict__ vnS, int n){
    __shared__ float acc[HNUM*HD];
    int t = threadIdx.x, lane = t & 63;
    for(int i=t;i<HNUM*HD;i+=1024) acc[i] = 0.f;
    __syncthreads();
    int wv  = (blockIdx.x*1024 + t) >> 6;
    int nwv = gridDim.x*16;
    for(int node = wv*4; node < n; node += nwv*4){
        bool o1 = node+1 < n, o2 = node+2 < n, o3 = node+3 < n;
        float v0 = OUT[(size_t)node*HD + lane];
        float v1 = o1 ? OUT[(size_t)(node+1)*HD + lane] : 0.f;
        float v2 = o2 ? OUT[(size_t)(node+2)*HD + lane] : 0.f;
        float v3 = o3 ? OUT[(size_t)(node+3)*HD + lane] : 0.f;
        int b0 = hb[node];
        int b1 = o1 ? hb[node+1] : 0;
        int b2 = o2 ? hb[node+2] : 0;
        int b3 = o3 ? hb[node+3] : 0;
        atomicAdd(&acc[b0*HD + lane], v0);
        if(o1) atomicAdd(&acc[b1*HD + lane], v1);
        if(o2) atomicAdd(&acc[b2*HD + lane], v2);
        if(o3) atomicAdd(&acc[b3*HD + lane], v3);
    }
    __syncthreads();
    for(int i=t;i<HNUM*HD;i+=1024) atomicAdd(&vnS[i], acc[i]);
}

// ---------------- vn update + both MLPs, fully in registers ----------------
__global__ __launch_bounds__(256) void k_vn(
    const float* __restrict__ vnS, const float* __restrict__ vne,
    const float* __restrict__ W1, const float* __restrict__ B1,
    const float* __restrict__ W2, const float* __restrict__ B2,
    float* __restrict__ vnD)
{
    int lane = threadIdx.x & 63;
    int w = (blockIdx.x*256 + threadIdx.x) >> 6;
    const int R = HNUM/32;
    float a[R], br[R];
    float ve = vne[lane];
    #pragma unroll
    for(int r=0;r<R;r++){
        int b = w*R + r;
        a[r] = vnS[b*HD + lane] + ve + ve;
    }
    for(int j=0;j<NMLP;j++){
        const float* w1 = W1 + j*HD*HD; const float* b1 = B1 + j*HD;
        const float* w2 = W2 + j*HD*HD; const float* b2 = B2 + j*HD;
        #pragma unroll
        for(int r=0;r<R;r++){
            float tacc = b1[lane];
            #pragma unroll
            for(int in=0;in<HD;in++) tacc = fmaf(__shfl(a[r], in, 64), w1[in*HD + lane], tacc);
            br[r] = fmaxf(tacc, 0.f);
        }
        #pragma unroll
        for(int r=0;r<R;r++){
            float tacc = b2[lane];
            #pragma unroll
            for(int in=0;in<HD;in++) tacc = fmaf(__shfl(br[r], in, 64), w2[in*HD + lane], tacc);
            a[r] = fmaxf(tacc, 0.f);
        }
    }
    #pragma unroll
    for(int r=0;r<R;r++){
        int b = w*R + r;
        vnD[b*HD + lane] = a[r];
    }
}

extern "C" void kernel_launch(void* const* d_in, const int* in_sizes, int n_in,
                              void* d_out, int out_size, void* d_ws, size_t ws_size,
                              hipStream_t stream)
{
    const float* x   = (const float*)d_in[0];
    const int*   ei  = (const int*)d_in[1];
    const int*   hb  = (const int*)d_in[2];
    const float* W0  = (const float*)d_in[5];
    const float* as0 = (const float*)d_in[6];
    const float* ad0 = (const float*)d_in[7];
    const float* b0  = (const float*)d_in[8];
    const float* Wl  = (const float*)d_in[9];
    const float* asl = (const float*)d_in[10];
    const float* adl = (const float*)d_in[11];
    const float* bl  = (const float*)d_in[12];
    const float* vne = (const float*)d_in[13];
    const float* mW1 = (const float*)d_in[14];
    const float* mb1 = (const float*)d_in[15];
    const float* mW2 = (const float*)d_in[16];
    const float* mb2 = (const float*)d_in[17];

    int N = in_sizes[0]/HD;
    int E = in_sizes[1]/2;
    const int* src = ei;
    const int* dst = ei + E;
    int NB = (N + (1<<BSH) - 1) >> BSH;

    char* p = (char*)d_ws;
    float* f_h   = (float*)p; p += (size_t)N*HD*4;   // fp16 H region + CSR alias
    float* f_as  = (float*)p; p += (size_t)N*4;
    float* f_ad  = (float*)p; p += (size_t)N*4;
    float* f_vnD = (float*)p; p += HNUM*HD*4;
    float* f_vnS = (float*)p; p += HNUM*HD*4;
    int*   i_rp  = (int*)p;   p += (size_t)(N+1)*4;
    int*   i_gb  = (int*)p;   p += MAXNB*4;
    int*   i_bb  = (int*)p;   p += MAXNB*4;
    int*   i_gc  = (int*)p;   p += MAXNB*4;
    int*   i_col = (int*)p;   p += (size_t)E*4;
    uint4* Wf3   = (uint4*)p; p += 3*512*16;
    float* waf3  = (float*)p; p += 3*8*64*4*4;
    int2*  bdata = (int2*)f_h;
    uint_t* Hw   = (uint_t*)f_h;

    float* outb = (float*)d_out;

    // one-time weight pack (3 blocks = 3 layers)
    k_wcvt<<<3, 256, 0, stream>>>(W0, as0, ad0, Wl, asl, adl, Wf3, waf3);

    hipMemsetAsync(i_gb, 0, MAXNB*4, stream);
    k_bcnt <<<512, 256, 0, stream>>>(dst, i_gb, E, NB);
    k_bscan<<<1, 512, 0, stream>>>(i_gb, i_bb, i_gc, NB);
    k_bin  <<<(E+EPB-1)/EPB, 256, 0, stream>>>(src, dst, i_gc, bdata, E, NB);
    k_bfuse<<<NB, 256, 0, stream>>>(bdata, i_bb, i_gb, i_rp, i_col, N, NB, E);

    int ga = 4096;
    int gg = 768;
    // conv0: GAT(x, W0)
    k_gemm<<<gg, 256, 0, stream>>>(x, nullptr, nullptr, hb, Wf3, waf3, Hw, f_as, f_ad, N);
    k_agg <<<ga, 256, 0, stream>>>(Hw, f_as, f_ad, i_rp, i_col, b0, outb, N);
    // conv1: GAT(out0 + vn_emb, Wl[0])
    k_gemm<<<gg, 256, 0, stream>>>(outb, vne, nullptr, hb, Wf3 + 512, waf3 + 2048, Hw, f_as, f_ad, N);
    k_agg <<<ga, 256, 0, stream>>>(Hw, f_as, f_ad, i_rp, i_col, bl, outb, N);
    // vn update: vnD = MLPs(segsum(out1) + 2*vne)
    hipMemsetAsync(f_vnS, 0, HNUM*HD*4, stream);
    k_vnseg<<<256, 1024, 0, stream>>>(outb, hb, f_vnS, N);
    k_vn  <<<8, 256, 0, stream>>>(f_vnS, vne, mW1, mb1, mW2, mb2, f_vnD);
    // conv2: GAT(out1 + vnD[hb], Wl[1]) -> final output
    k_gemm<<<gg, 256, 0, stream>>>(outb, nullptr, f_vnD, hb, Wf3 + 1024, waf3 + 4096, Hw, f_as, f_ad, N);
    k_agg <<<ga, 256, 0, stream>>>(Hw, f_as, f_ad, i_rp, i_col, bl + HD, outb, N);
}

// Round 9
// 314.767 us; speedup vs baseline: 2.5639x; 1.1236x over previous
//
#include <hip/hip_runtime.h>
#include <hip/hip_fp16.h>
#include <math.h>

#define HD 64
#define HNUM 128
#define NMLP 2
#define BSH 8              // 256 dst-nodes per bucket
#define MAXNB 512
#define EPB 2048           // edges per k_bin block

typedef unsigned int uint_t;
typedef unsigned short ushort_t;
typedef _Float16 h8 __attribute__((ext_vector_type(8)));
typedef float vf4 __attribute__((ext_vector_type(4)));

union H8U { h8 v; uint_t u[4]; };

__device__ __forceinline__ float lrelu(float x){ return fmaxf(x, 0.2f*x); }

__device__ __forceinline__ float cvt_h(uint_t wv, uint_t sh){
    __half_raw hr; hr.x = (ushort_t)(wv >> sh);
    return __half2float((__half)hr);
}
__device__ __forceinline__ uint_t pk2(float a, float b){
    return (uint_t)__half_as_ushort(__float2half_rn(a)) |
           ((uint_t)__half_as_ushort(__float2half_rn(b)) << 16);
}

// ---------------- CSR build: bucketed counting sort ----------------
__global__ __launch_bounds__(256) void k_bcnt(const int* __restrict__ dst, int* __restrict__ gb,
                                              int E, int NB){
    __shared__ int h[MAXNB];
    int t = threadIdx.x;
    for(int i=t;i<NB;i+=256) h[i] = 0;
    __syncthreads();
    for(int e = blockIdx.x*256 + t; e < E; e += gridDim.x*256)
        atomicAdd(&h[dst[e]>>BSH], 1);
    __syncthreads();
    for(int i=t;i<NB;i+=256) if(h[i]) atomicAdd(&gb[i], h[i]);
}

__global__ __launch_bounds__(512) void k_bscan(const int* __restrict__ gb, int* __restrict__ bbase,
                                               int* __restrict__ gcur, int NB){
    __shared__ int s[512];
    int t = threadIdx.x;
    int v = (t < NB) ? gb[t] : 0;
    s[t] = v; __syncthreads();
    for(int o=1;o<512;o<<=1){
        int u = (t >= o) ? s[t-o] : 0;
        __syncthreads();
        s[t] += u;
        __syncthreads();
    }
    if(t < NB){ int ex = s[t] - v; bbase[t] = ex; gcur[t] = ex; }
}

__global__ __launch_bounds__(256) void k_bin(const int* __restrict__ src, const int* __restrict__ dst,
                                             int* __restrict__ gcur, int2* __restrict__ bdata,
                                             int E, int NB){
    __shared__ int cnt[MAXNB];
    __shared__ int base[MAXNB];
    int t = threadIdx.x;
    for(int i=t;i<NB;i+=256) cnt[i] = 0;
    __syncthreads();
    int s0 = blockIdx.x*EPB;
    int sv[8], dv[8], off[8];
    #pragma unroll
    for(int i=0;i<8;i++){
        int e = s0 + i*256 + t;
        if(e < E){
            sv[i] = src[e]; dv[i] = dst[e];
            off[i] = atomicAdd(&cnt[dv[i]>>BSH], 1);
        }
    }
    __syncthreads();
    for(int i=t;i<NB;i+=256) base[i] = cnt[i] ? atomicAdd(&gcur[i], cnt[i]) : 0;
    __syncthreads();
    #pragma unroll
    for(int i=0;i<8;i++){
        int e = s0 + i*256 + t;
        if(e < E) bdata[base[dv[i]>>BSH] + off[i]] = make_int2(sv[i], dv[i]);
    }
}

// fused per-bucket: LDS hist -> LDS scan -> rowptr slice -> LDS-cursor scatter
__global__ __launch_bounds__(256) void k_bfuse(const int2* __restrict__ bdata, const int* __restrict__ bbase,
                                               const int* __restrict__ gb, int* __restrict__ rp,
                                               int* __restrict__ col, int n, int NB, int E){
    __shared__ int h[256];
    __shared__ int sc[256];
    int b = blockIdx.x, t = threadIdx.x;
    int beg = bbase[b], cnt = gb[b];
    h[t] = 0; __syncthreads();
    for(int i=t;i<cnt;i+=256) atomicAdd(&h[bdata[beg+i].y & 255], 1);
    __syncthreads();
    int v = h[t];
    sc[t] = v; __syncthreads();
    for(int o=1;o<256;o<<=1){
        int u = (t >= o) ? sc[t-o] : 0;
        __syncthreads();
        sc[t] += u;
        __syncthreads();
    }
    int excl = sc[t] - v;
    int node = (b<<BSH) + t;
    if(node < n) rp[node] = beg + excl;
    if(b == NB-1 && t == 255) rp[n] = E;
    __syncthreads();
    sc[t] = excl;           // per-node local cursor
    __syncthreads();
    for(int i=t;i<cnt;i+=256){
        int2 e = bdata[beg+i];
        int pos = atomicAdd(&sc[e.y & 255], 1);
        col[beg + pos] = e.x;
    }
}

// ---------------- one-time weight fragment pack + W@a precompute ----------------
__global__ __launch_bounds__(256) void k_wcvt(
    const float* __restrict__ W0, const float* __restrict__ as0, const float* __restrict__ ad0,
    const float* __restrict__ Wl, const float* __restrict__ asl, const float* __restrict__ adl,
    uint4* __restrict__ Wf3, float* __restrict__ waf3)
{
    __shared__ float wa[2][64];
    int L = blockIdx.x, t = threadIdx.x;
    const float* W  = (L==0) ? W0  : Wl  + (L-1)*HD*HD;
    const float* as = (L==0) ? as0 : asl + (L-1)*HD;
    const float* ad = (L==0) ? ad0 : adl + (L-1)*HD;
    if(t < 128){
        int sd = t>>6, k = t&63;
        const float* av = sd ? ad : as;
        float acc = 0.f;
        for(int c=0;c<HD;c++) acc = fmaf(W[k*HD+c], av[c], acc);
        wa[sd][k] = acc;
    }
    __syncthreads();
    for(int it = t; it < 512; it += 256){
        int lane = it&63, s = (it>>6)&1, tile = it>>7;
        int g = lane>>4, m = lane&15, c = tile*16 + m;
        ushort_t h[8];
        #pragma unroll
        for(int i=0;i<8;i++){
            int k = s*32 + g*4 + (i&3) + 16*(i>>2);
            h[i] = __half_as_ushort(__float2half_rn(W[k*HD + c]));
        }
        uint4 q;
        q.x = (uint_t)h[0] | ((uint_t)h[1]<<16);
        q.y = (uint_t)h[2] | ((uint_t)h[3]<<16);
        q.z = (uint_t)h[4] | ((uint_t)h[5]<<16);
        q.w = (uint_t)h[6] | ((uint_t)h[7]<<16);
        Wf3[(size_t)L*512 + (tile*2+s)*64 + lane] = q;
    }
    if(t < 128){
        int lane = t&63, sd = t>>6, g = lane>>4;
        #pragma unroll
        for(int j4=0;j4<4;j4++){
            float v[4];
            #pragma unroll
            for(int e=0;e<4;e++){
                int j = j4*4 + e;
                int k = (j>>3)*32 + g*4 + (j&3) + 16*((j>>2)&1);
                v[e] = wa[sd][k];
            }
            float* dstp = waf3 + ((size_t)L*8 + sd*4 + j4)*64*4 + lane*4;
            dstp[0]=v[0]; dstp[1]=v[1]; dstp[2]=v[2]; dstp[3]=v[3];
        }
    }
}

// ---------------- MFMA GEMM: 16 rows x 64 cols per wave ----------------
// Hw pair-layout: row dword w holds fp16 cols (32*(w>>4)+(w&15), same+16)
__global__ __launch_bounds__(256) void k_gemm(
    const float* __restrict__ IN, const float* __restrict__ addrow,
    const float* __restrict__ addtab, const int* __restrict__ hb,
    const uint4* __restrict__ Wf, const float* __restrict__ waf,
    uint_t* __restrict__ Hw, float* __restrict__ AS, float* __restrict__ AD,
    int n)
{
    __shared__ ushort_t sx[4][1024];
    int t = threadIdx.x, lane = t&63, wv = t>>6;
    int g = lane>>4, m = lane&15;
    ushort_t* sb = sx[wv];

    H8U B[8];
    #pragma unroll
    for(int f=0; f<8; f++){
        uint4 q = Wf[f*64 + lane];
        B[f].u[0]=q.x; B[f].u[1]=q.y; B[f].u[2]=q.z; B[f].u[3]=q.w;
    }
    vf4 wS[4], wD[4];
    #pragma unroll
    for(int j4=0;j4<4;j4++){
        const float* ps = waf + ((size_t)0*4 + j4)*256 + lane*4;
        const float* pd = waf + ((size_t)1*4 + j4)*256 + lane*4;
        wS[j4] = vf4{ps[0],ps[1],ps[2],ps[3]};
        wD[j4] = vf4{pd[0],pd[1],pd[2],pd[3]};
    }
    float ar0=0,ar1=0,ar2=0,ar3=0;
    if(addrow){
        const float* a = &addrow[m*4];
        ar0=a[0]; ar1=a[1]; ar2=a[2]; ar3=a[3];
    }

    int ntiles = (n + 15) >> 4;
    int wgid = (blockIdx.x*256 + t) >> 6;
    int nw = gridDim.x*4;
    for(int tile = wgid; tile < ntiles; tile += nw){
        int rb = tile*16;
        #pragma unroll
        for(int p=0;p<4;p++){
            int row = p*4 + g;
            int rowc = min(rb + row, n-1);
            float4 x4 = *(const float4*)&IN[(size_t)rowc*HD + m*4];
            if(addrow){ x4.x+=ar0; x4.y+=ar1; x4.z+=ar2; x4.w+=ar3; }
            if(addtab){
                int b = hb[rowc];
                float4 a4 = *(const float4*)&addtab[b*HD + m*4];
                x4.x+=a4.x; x4.y+=a4.y; x4.z+=a4.z; x4.w+=a4.w;
            }
            uint2 pq; pq.x = pk2(x4.x, x4.y); pq.y = pk2(x4.z, x4.w);
            int idx = (row*64 + m*4) ^ ((row&7)<<3);
            *(uint2*)&sb[idx] = pq;
        }
        int xr = (m&7)<<3;
        H8U A0, A1;
        {
            uint2 c0 = *(uint2*)&sb[(m*64 +  0 + g*4) ^ xr];
            uint2 c1 = *(uint2*)&sb[(m*64 + 16 + g*4) ^ xr];
            A0.u[0]=c0.x; A0.u[1]=c0.y; A0.u[2]=c1.x; A0.u[3]=c1.y;
            uint2 c2 = *(uint2*)&sb[(m*64 + 32 + g*4) ^ xr];
            uint2 c3 = *(uint2*)&sb[(m*64 + 48 + g*4) ^ xr];
            A1.u[0]=c2.x; A1.u[1]=c2.y; A1.u[2]=c3.x; A1.u[3]=c3.y;
        }
        float t1 = 0.f, t2 = 0.f;
        #pragma unroll
        for(int i=0;i<8;i++){
            float xv = (float)A0.v[i];
            t1 = fmaf(xv, wS[i>>2][i&3], t1);
            t2 = fmaf(xv, wD[i>>2][i&3], t2);
        }
        #pragma unroll
        for(int i=0;i<8;i++){
            float xv = (float)A1.v[i];
            t1 = fmaf(xv, wS[2+(i>>2)][i&3], t1);
            t2 = fmaf(xv, wD[2+(i>>2)][i&3], t2);
        }
        t1 += __shfl_xor(t1, 16, 64); t1 += __shfl_xor(t1, 32, 64);
        t2 += __shfl_xor(t2, 16, 64); t2 += __shfl_xor(t2, 32, 64);
        if(lane < 16 && rb + lane < n){ AS[rb+lane] = t1; AD[rb+lane] = t2; }
        vf4 z = {0.f,0.f,0.f,0.f};
        vf4 a0 = __builtin_amdgcn_mfma_f32_16x16x32_f16(A0.v, B[0].v, z, 0,0,0);
        a0     = __builtin_amdgcn_mfma_f32_16x16x32_f16(A1.v, B[1].v, a0, 0,0,0);
        vf4 a1 = __builtin_amdgcn_mfma_f32_16x16x32_f16(A0.v, B[2].v, z, 0,0,0);
        a1     = __builtin_amdgcn_mfma_f32_16x16x32_f16(A1.v, B[3].v, a1, 0,0,0);
        vf4 a2 = __builtin_amdgcn_mfma_f32_16x16x32_f16(A0.v, B[4].v, z, 0,0,0);
        a2     = __builtin_amdgcn_mfma_f32_16x16x32_f16(A1.v, B[5].v, a2, 0,0,0);
        vf4 a3 = __builtin_amdgcn_mfma_f32_16x16x32_f16(A0.v, B[6].v, z, 0,0,0);
        a3     = __builtin_amdgcn_mfma_f32_16x16x32_f16(A1.v, B[7].v, a3, 0,0,0);
        #pragma unroll
        for(int rr=0;rr<4;rr++){
            int row = rb + g*4 + rr;
            if(row < n){
                Hw[(size_t)row*32 + m]      = pk2(a0[rr], a1[rr]);
                Hw[(size_t)row*32 + 16 + m] = pk2(a2[rr], a3[rr]);
            }
        }
    }
}

// ---------------- GAT aggregate: quarter-wave per dst (4 dsts/wave) ----------------
// Lane (q,p): quarter q owns dst base+q; lane p holds row dwords 2p,2p+1 (4 cols).
__global__ __launch_bounds__(256) void k_agg(
    const uint_t* __restrict__ Hb, const float* __restrict__ AS, const float* __restrict__ AD,
    const int* __restrict__ rp, const int* __restrict__ col,
    const float* __restrict__ bias, float* __restrict__ OUT, int n)
{
    int t = threadIdx.x, lane = t & 63;
    int p = lane & 15;          // position within quarter
    int qb = lane & 48;         // quarter base lane (0,16,32,48)
    int w0 = 2*p;
    int c00 = 32*(w0>>4)+(w0&15), c01 = c00+16;
    int c10 = c00+1, c11 = c00+17;        // w1=w0+1 shares the >>4 group
    float b00 = bias[c00], b01 = bias[c01], b10 = bias[c10], b11 = bias[c11];
    int wv  = (blockIdx.x*256 + t) >> 6;
    int nwv = gridDim.x*4;
    for(int base = wv*4; base < n; base += nwv*4){
        int dq = min(base + (qb>>4), n-1);
        float ad = AD[dq];
        float wself = __expf(lrelu(AS[dq] + ad));
        uint2 hd = *(const uint2*)&Hb[(size_t)dq*32 + w0];
        float4 acc;
        acc.x = cvt_h(hd.x,0)*wself; acc.y = cvt_h(hd.x,16)*wself;
        acc.z = cvt_h(hd.y,0)*wself; acc.w = cvt_h(hd.y,16)*wself;
        float sacc = 0.f;
        int beg = rp[dq], end = rp[dq+1];
        int cnt = end - beg;
        int nit = (cnt + 15) >> 4;
        nit = max(nit, __shfl_xor(nit, 16, 64));
        nit = max(nit, __shfl_xor(nit, 32, 64));
        for(int it = 0; it < nit; it++){
            int j = beg + it*16 + p;
            bool valid = j < end;
            int sj = dq;
            if(cnt > 0) sj = col[valid ? j : end - 1];
            float wj = 0.f;
            if(valid) wj = __expf(lrelu(AS[sj] + ad));
            sacc += wj;
            int ccnt = cnt - it*16;
            ccnt = ccnt < 0 ? 0 : (ccnt > 16 ? 16 : ccnt);
            int emax = ccnt;
            emax = max(emax, __shfl_xor(emax, 16, 64));
            emax = max(emax, __shfl_xor(emax, 32, 64));
            int e = 0;
            for(; e + 4 <= emax; e += 4){
                float wq0 = __shfl(wj, qb+e,   64);
                float wq1 = __shfl(wj, qb+e+1, 64);
                float wq2 = __shfl(wj, qb+e+2, 64);
                float wq3 = __shfl(wj, qb+e+3, 64);
                int   sq0 = __shfl(sj, qb+e,   64);
                int   sq1 = __shfl(sj, qb+e+1, 64);
                int   sq2 = __shfl(sj, qb+e+2, 64);
                int   sq3 = __shfl(sj, qb+e+3, 64);
                uint2 v0 = *(const uint2*)&Hb[(size_t)sq0*32 + w0];
                uint2 v1 = *(const uint2*)&Hb[(size_t)sq1*32 + w0];
                uint2 v2 = *(const uint2*)&Hb[(size_t)sq2*32 + w0];
                uint2 v3 = *(const uint2*)&Hb[(size_t)sq3*32 + w0];
                acc.x = fmaf(wq0, cvt_h(v0.x,0),  acc.x);
                acc.y = fmaf(wq0, cvt_h(v0.x,16), acc.y);
                acc.z = fmaf(wq0, cvt_h(v0.y,0),  acc.z);
                acc.w = fmaf(wq0, cvt_h(v0.y,16), acc.w);
                acc.x = fmaf(wq1, cvt_h(v1.x,0),  acc.x);
                acc.y = fmaf(wq1, cvt_h(v1.x,16), acc.y);
                acc.z = fmaf(wq1, cvt_h(v1.y,0),  acc.z);
                acc.w = fmaf(wq1, cvt_h(v1.y,16), acc.w);
                acc.x = fmaf(wq2, cvt_h(v2.x,0),  acc.x);
                acc.y = fmaf(wq2, cvt_h(v2.x,16), acc.y);
                acc.z = fmaf(wq2, cvt_h(v2.y,0),  acc.z);
                acc.w = fmaf(wq2, cvt_h(v2.y,16), acc.w);
                acc.x = fmaf(wq3, cvt_h(v3.x,0),  acc.x);
                acc.y = fmaf(wq3, cvt_h(v3.x,16), acc.y);
                acc.z = fmaf(wq3, cvt_h(v3.y,0),  acc.z);
                acc.w = fmaf(wq3, cvt_h(v3.y,16), acc.w);
            }
            for(; e < emax; e++){
                float wq = __shfl(wj, qb+e, 64);
                int   sq = __shfl(sj, qb+e, 64);
                uint2 v = *(const uint2*)&Hb[(size_t)sq*32 + w0];
                acc.x = fmaf(wq, cvt_h(v.x,0),  acc.x);
                acc.y = fmaf(wq, cvt_h(v.x,16), acc.y);
                acc.z = fmaf(wq, cvt_h(v.y,0),  acc.z);
                acc.w = fmaf(wq, cvt_h(v.y,16), acc.w);
            }
        }
        sacc += __shfl_xor(sacc, 1, 64);
        sacc += __shfl_xor(sacc, 2, 64);
        sacc += __shfl_xor(sacc, 4, 64);
        sacc += __shfl_xor(sacc, 8, 64);
        float s = wself + sacc;
        float inv = 1.f/(s + 1e-16f);
        if(base + (qb>>4) < n){
            OUT[(size_t)dq*HD + c00] = fmaf(acc.x, inv, b00);
            OUT[(size_t)dq*HD + c01] = fmaf(acc.y, inv, b01);
            OUT[(size_t)dq*HD + c10] = fmaf(acc.z, inv, b10);
            OUT[(size_t)dq*HD + c11] = fmaf(acc.w, inv, b11);
        }
    }
}

// ---------------- virtual-node segment sum: 1024-thread blocks, unroll-4 ----------------
__global__ __launch_bounds__(1024) void k_vnseg(const float* __restrict__ OUT, const int* __restrict__ hb,
                                                float* __restrict__ vnS, int n){
    __shared__ float acc[HNUM*HD];
    int t = threadIdx.x, lane = t & 63;
    for(int i=t;i<HNUM*HD;i+=1024) acc[i] = 0.f;
    __syncthreads();
    int wv  = (blockIdx.x*1024 + t) >> 6;
    int nwv = gridDim.x*16;
    for(int node = wv*4; node < n; node += nwv*4){
        bool o1 = node+1 < n, o2 = node+2 < n, o3 = node+3 < n;
        float v0 = OUT[(size_t)node*HD + lane];
        float v1 = o1 ? OUT[(size_t)(node+1)*HD + lane] : 0.f;
        float v2 = o2 ? OUT[(size_t)(node+2)*HD + lane] : 0.f;
        float v3 = o3 ? OUT[(size_t)(node+3)*HD + lane] : 0.f;
        int b0 = hb[node];
        int b1 = o1 ? hb[node+1] : 0;
        int b2 = o2 ? hb[node+2] : 0;
        int b3 = o3 ? hb[node+3] : 0;
        atomicAdd(&acc[b0*HD + lane], v0);
        if(o1) atomicAdd(&acc[b1*HD + lane], v1);
        if(o2) atomicAdd(&acc[b2*HD + lane], v2);
        if(o3) atomicAdd(&acc[b3*HD + lane], v3);
    }
    __syncthreads();
    for(int i=t;i<HNUM*HD;i+=1024) atomicAdd(&vnS[i], acc[i]);
}

// ---------------- vn update + both MLPs, fully in registers ----------------
__global__ __launch_bounds__(256) void k_vn(
    const float* __restrict__ vnS, const float* __restrict__ vne,
    const float* __restrict__ W1, const float* __restrict__ B1,
    const float* __restrict__ W2, const float* __restrict__ B2,
    float* __restrict__ vnD)
{
    int lane = threadIdx.x & 63;
    int w = (blockIdx.x*256 + threadIdx.x) >> 6;
    const int R = HNUM/32;
    float a[R], br[R];
    float ve = vne[lane];
    #pragma unroll
    for(int r=0;r<R;r++){
        int b = w*R + r;
        a[r] = vnS[b*HD + lane] + ve + ve;
    }
    for(int j=0;j<NMLP;j++){
        const float* w1 = W1 + j*HD*HD; const float* b1 = B1 + j*HD;
        const float* w2 = W2 + j*HD*HD; const float* b2 = B2 + j*HD;
        #pragma unroll
        for(int r=0;r<R;r++){
            float tacc = b1[lane];
            #pragma unroll
            for(int in=0;in<HD;in++) tacc = fmaf(__shfl(a[r], in, 64), w1[in*HD + lane], tacc);
            br[r] = fmaxf(tacc, 0.f);
        }
        #pragma unroll
        for(int r=0;r<R;r++){
            float tacc = b2[lane];
            #pragma unroll
            for(int in=0;in<HD;in++) tacc = fmaf(__shfl(br[r], in, 64), w2[in*HD + lane], tacc);
            a[r] = fmaxf(tacc, 0.f);
        }
    }
    #pragma unroll
    for(int r=0;r<R;r++){
        int b = w*R + r;
        vnD[b*HD + lane] = a[r];
    }
}

extern "C" void kernel_launch(void* const* d_in, const int* in_sizes, int n_in,
                              void* d_out, int out_size, void* d_ws, size_t ws_size,
                              hipStream_t stream)
{
    const float* x   = (const float*)d_in[0];
    const int*   ei  = (const int*)d_in[1];
    const int*   hb  = (const int*)d_in[2];
    const float* W0  = (const float*)d_in[5];
    const float* as0 = (const float*)d_in[6];
    const float* ad0 = (const float*)d_in[7];
    const float* b0  = (const float*)d_in[8];
    const float* Wl  = (const float*)d_in[9];
    const float* asl = (const float*)d_in[10];
    const float* adl = (const float*)d_in[11];
    const float* bl  = (const float*)d_in[12];
    const float* vne = (const float*)d_in[13];
    const float* mW1 = (const float*)d_in[14];
    const float* mb1 = (const float*)d_in[15];
    const float* mW2 = (const float*)d_in[16];
    const float* mb2 = (const float*)d_in[17];

    int N = in_sizes[0]/HD;
    int E = in_sizes[1]/2;
    const int* src = ei;
    const int* dst = ei + E;
    int NB = (N + (1<<BSH) - 1) >> BSH;

    char* p = (char*)d_ws;
    float* f_h   = (float*)p; p += (size_t)N*HD*4;   // fp16 H region + CSR alias
    float* f_as  = (float*)p; p += (size_t)N*4;
    float* f_ad  = (float*)p; p += (size_t)N*4;
    float* f_vnD = (float*)p; p += HNUM*HD*4;
    float* f_vnS = (float*)p; p += HNUM*HD*4;
    int*   i_rp  = (int*)p;   p += (size_t)(N+1)*4;
    int*   i_gb  = (int*)p;   p += MAXNB*4;
    int*   i_bb  = (int*)p;   p += MAXNB*4;
    int*   i_gc  = (int*)p;   p += MAXNB*4;
    int*   i_col = (int*)p;   p += (size_t)E*4;
    uint4* Wf3   = (uint4*)p; p += 3*512*16;
    float* waf3  = (float*)p; p += 3*8*64*4*4;
    int2*  bdata = (int2*)f_h;
    uint_t* Hw   = (uint_t*)f_h;

    float* outb = (float*)d_out;

    // one-time weight pack (3 blocks = 3 layers)
    k_wcvt<<<3, 256, 0, stream>>>(W0, as0, ad0, Wl, asl, adl, Wf3, waf3);

    hipMemsetAsync(i_gb, 0, MAXNB*4, stream);
    k_bcnt <<<512, 256, 0, stream>>>(dst, i_gb, E, NB);
    k_bscan<<<1, 512, 0, stream>>>(i_gb, i_bb, i_gc, NB);
    k_bin  <<<(E+EPB-1)/EPB, 256, 0, stream>>>(src, dst, i_gc, bdata, E, NB);
    k_bfuse<<<NB, 256, 0, stream>>>(bdata, i_bb, i_gb, i_rp, i_col, N, NB, E);

    int ga = 4096;
    int gg = 768;
    // conv0: GAT(x, W0)
    k_gemm<<<gg, 256, 0, stream>>>(x, nullptr, nullptr, hb, Wf3, waf3, Hw, f_as, f_ad, N);
    k_agg <<<ga, 256, 0, stream>>>(Hw, f_as, f_ad, i_rp, i_col, b0, outb, N);
    // conv1: GAT(out0 + vn_emb, Wl[0])
    k_gemm<<<gg, 256, 0, stream>>>(outb, vne, nullptr, hb, Wf3 + 512, waf3 + 2048, Hw, f_as, f_ad, N);
    k_agg <<<ga, 256, 0, stream>>>(Hw, f_as, f_ad, i_rp, i_col, bl, outb, N);
    // vn update: vnD = MLPs(segsum(out1) + 2*vne)
    hipMemsetAsync(f_vnS, 0, HNUM*HD*4, stream);
    k_vnseg<<<256, 1024, 0, stream>>>(outb, hb, f_vnS, N);
    k_vn  <<<8, 256, 0, stream>>>(f_vnS, vne, mW1, mb1, mW2, mb2, f_vnD);
    // conv2: GAT(out1 + vnD[hb], Wl[1]) -> final output
    k_gemm<<<gg, 256, 0, stream>>>(outb, nullptr, f_vnD, hb, Wf3 + 1024, waf3 + 4096, Hw, f_as, f_ad, N);
    k_agg <<<ga, 256, 0, stream>>>(Hw, f_as, f_ad, i_rp, i_col, bl + HD, outb, N);
}

// Round 10
// 305.844 us; speedup vs baseline: 2.6387x; 1.0292x over previous
//
#include <hip/hip_runtime.h>
#include <hip/hip_fp16.h>
#include <math.h>

#define HD 64
#define HNUM 128
#define NMLP 2
#define BSH 8              // 256 dst-nodes per bucket
#define MAXNB 512
#define EPB 2048           // edges per k_bin block
#define NPART 256          // k_vnseg partial blocks

typedef unsigned int uint_t;
typedef unsigned short ushort_t;
typedef _Float16 h8 __attribute__((ext_vector_type(8)));
typedef float vf4 __attribute__((ext_vector_type(4)));

union H8U { h8 v; uint_t u[4]; };

__device__ __forceinline__ float lrelu(float x){ return fmaxf(x, 0.2f*x); }

__device__ __forceinline__ float cvt_h(uint_t wv, uint_t sh){
    __half_raw hr; hr.x = (ushort_t)(wv >> sh);
    return __half2float((__half)hr);
}
__device__ __forceinline__ uint_t pk2(float a, float b){
    return (uint_t)__half_as_ushort(__float2half_rn(a)) |
           ((uint_t)__half_as_ushort(__float2half_rn(b)) << 16);
}

// ---------------- CSR build: bucketed counting sort ----------------
__global__ __launch_bounds__(256) void k_bcnt(const int* __restrict__ dst, int* __restrict__ gb,
                                              int E, int NB){
    __shared__ int h[MAXNB];
    int t = threadIdx.x;
    for(int i=t;i<NB;i+=256) h[i] = 0;
    __syncthreads();
    for(int e = blockIdx.x*256 + t; e < E; e += gridDim.x*256)
        atomicAdd(&h[dst[e]>>BSH], 1);
    __syncthreads();
    for(int i=t;i<NB;i+=256) if(h[i]) atomicAdd(&gb[i], h[i]);
}

__global__ __launch_bounds__(512) void k_bscan(const int* __restrict__ gb, int* __restrict__ bbase,
                                               int* __restrict__ gcur, int NB){
    __shared__ int s[512];
    int t = threadIdx.x;
    int v = (t < NB) ? gb[t] : 0;
    s[t] = v; __syncthreads();
    for(int o=1;o<512;o<<=1){
        int u = (t >= o) ? s[t-o] : 0;
        __syncthreads();
        s[t] += u;
        __syncthreads();
    }
    if(t < NB){ int ex = s[t] - v; bbase[t] = ex; gcur[t] = ex; }
}

__global__ __launch_bounds__(256) void k_bin(const int* __restrict__ src, const int* __restrict__ dst,
                                             int* __restrict__ gcur, int2* __restrict__ bdata,
                                             int E, int NB){
    __shared__ int cnt[MAXNB];
    __shared__ int base[MAXNB];
    int t = threadIdx.x;
    for(int i=t;i<NB;i+=256) cnt[i] = 0;
    __syncthreads();
    int s0 = blockIdx.x*EPB;
    int sv[8], dv[8], off[8];
    #pragma unroll
    for(int i=0;i<8;i++){
        int e = s0 + i*256 + t;
        if(e < E){
            sv[i] = src[e]; dv[i] = dst[e];
            off[i] = atomicAdd(&cnt[dv[i]>>BSH], 1);
        }
    }
    __syncthreads();
    for(int i=t;i<NB;i+=256) base[i] = cnt[i] ? atomicAdd(&gcur[i], cnt[i]) : 0;
    __syncthreads();
    #pragma unroll
    for(int i=0;i<8;i++){
        int e = s0 + i*256 + t;
        if(e < E) bdata[base[dv[i]>>BSH] + off[i]] = make_int2(sv[i], dv[i]);
    }
}

// fused per-bucket: LDS hist -> LDS scan -> rowptr slice -> LDS-cursor scatter
__global__ __launch_bounds__(256) void k_bfuse(const int2* __restrict__ bdata, const int* __restrict__ bbase,
                                               const int* __restrict__ gb, int* __restrict__ rp,
                                               int* __restrict__ col, int n, int NB, int E){
    __shared__ int h[256];
    __shared__ int sc[256];
    int b = blockIdx.x, t = threadIdx.x;
    int beg = bbase[b], cnt = gb[b];
    h[t] = 0; __syncthreads();
    for(int i=t;i<cnt;i+=256) atomicAdd(&h[bdata[beg+i].y & 255], 1);
    __syncthreads();
    int v = h[t];
    sc[t] = v; __syncthreads();
    for(int o=1;o<256;o<<=1){
        int u = (t >= o) ? sc[t-o] : 0;
        __syncthreads();
        sc[t] += u;
        __syncthreads();
    }
    int excl = sc[t] - v;
    int node = (b<<BSH) + t;
    if(node < n) rp[node] = beg + excl;
    if(b == NB-1 && t == 255) rp[n] = E;
    __syncthreads();
    sc[t] = excl;           // per-node local cursor
    __syncthreads();
    for(int i=t;i<cnt;i+=256){
        int2 e = bdata[beg+i];
        int pos = atomicAdd(&sc[e.y & 255], 1);
        col[beg + pos] = e.x;
    }
}

// ---------------- one-time weight fragment pack + W@a precompute ----------------
__global__ __launch_bounds__(256) void k_wcvt(
    const float* __restrict__ W0, const float* __restrict__ as0, const float* __restrict__ ad0,
    const float* __restrict__ Wl, const float* __restrict__ asl, const float* __restrict__ adl,
    uint4* __restrict__ Wf3, float* __restrict__ waf3)
{
    __shared__ float wa[2][64];
    int L = blockIdx.x, t = threadIdx.x;
    const float* W  = (L==0) ? W0  : Wl  + (L-1)*HD*HD;
    const float* as = (L==0) ? as0 : asl + (L-1)*HD;
    const float* ad = (L==0) ? ad0 : adl + (L-1)*HD;
    if(t < 128){
        int sd = t>>6, k = t&63;
        const float* av = sd ? ad : as;
        float acc = 0.f;
        for(int c=0;c<HD;c++) acc = fmaf(W[k*HD+c], av[c], acc);
        wa[sd][k] = acc;
    }
    __syncthreads();
    for(int it = t; it < 512; it += 256){
        int lane = it&63, s = (it>>6)&1, tile = it>>7;
        int g = lane>>4, m = lane&15, c = tile*16 + m;
        ushort_t h[8];
        #pragma unroll
        for(int i=0;i<8;i++){
            int k = s*32 + g*4 + (i&3) + 16*(i>>2);
            h[i] = __half_as_ushort(__float2half_rn(W[k*HD + c]));
        }
        uint4 q;
        q.x = (uint_t)h[0] | ((uint_t)h[1]<<16);
        q.y = (uint_t)h[2] | ((uint_t)h[3]<<16);
        q.z = (uint_t)h[4] | ((uint_t)h[5]<<16);
        q.w = (uint_t)h[6] | ((uint_t)h[7]<<16);
        Wf3[(size_t)L*512 + (tile*2+s)*64 + lane] = q;
    }
    if(t < 128){
        int lane = t&63, sd = t>>6, g = lane>>4;
        #pragma unroll
        for(int j4=0;j4<4;j4++){
            float v[4];
            #pragma unroll
            for(int e=0;e<4;e++){
                int j = j4*4 + e;
                int k = (j>>3)*32 + g*4 + (j&3) + 16*((j>>2)&1);
                v[e] = wa[sd][k];
            }
            float* dstp = waf3 + ((size_t)L*8 + sd*4 + j4)*64*4 + lane*4;
            dstp[0]=v[0]; dstp[1]=v[1]; dstp[2]=v[2]; dstp[3]=v[3];
        }
    }
}

// ---------------- MFMA GEMM: 16 rows x 64 cols per wave ----------------
// Hw pair-layout: row dword w holds fp16 cols (32*(w>>4)+(w&15), same+16)
__global__ __launch_bounds__(256) void k_gemm(
    const float* __restrict__ IN, const float* __restrict__ addrow,
    const float* __restrict__ addtab, const int* __restrict__ hb,
    const uint4* __restrict__ Wf, const float* __restrict__ waf,
    uint_t* __restrict__ Hw, float* __restrict__ AS, float* __restrict__ AD,
    int n)
{
    __shared__ ushort_t sx[4][1024];
    int t = threadIdx.x, lane = t&63, wv = t>>6;
    int g = lane>>4, m = lane&15;
    ushort_t* sb = sx[wv];

    H8U B[8];
    #pragma unroll
    for(int f=0; f<8; f++){
        uint4 q = Wf[f*64 + lane];
        B[f].u[0]=q.x; B[f].u[1]=q.y; B[f].u[2]=q.z; B[f].u[3]=q.w;
    }
    vf4 wS[4], wD[4];
    #pragma unroll
    for(int j4=0;j4<4;j4++){
        const float* ps = waf + ((size_t)0*4 + j4)*256 + lane*4;
        const float* pd = waf + ((size_t)1*4 + j4)*256 + lane*4;
        wS[j4] = vf4{ps[0],ps[1],ps[2],ps[3]};
        wD[j4] = vf4{pd[0],pd[1],pd[2],pd[3]};
    }
    float ar0=0,ar1=0,ar2=0,ar3=0;
    if(addrow){
        const float* a = &addrow[m*4];
        ar0=a[0]; ar1=a[1]; ar2=a[2]; ar3=a[3];
    }

    int ntiles = (n + 15) >> 4;
    int wgid = (blockIdx.x*256 + t) >> 6;
    int nw = gridDim.x*4;
    for(int tile = wgid; tile < ntiles; tile += nw){
        int rb = tile*16;
        #pragma unroll
        for(int p=0;p<4;p++){
            int row = p*4 + g;
            int rowc = min(rb + row, n-1);
            float4 x4 = *(const float4*)&IN[(size_t)rowc*HD + m*4];
            if(addrow){ x4.x+=ar0; x4.y+=ar1; x4.z+=ar2; x4.w+=ar3; }
            if(addtab){
                int b = hb[rowc];
                float4 a4 = *(const float4*)&addtab[b*HD + m*4];
                x4.x+=a4.x; x4.y+=a4.y; x4.z+=a4.z; x4.w+=a4.w;
            }
            uint2 pq; pq.x = pk2(x4.x, x4.y); pq.y = pk2(x4.z, x4.w);
            int idx = (row*64 + m*4) ^ ((row&7)<<3);
            *(uint2*)&sb[idx] = pq;
        }
        int xr = (m&7)<<3;
        H8U A0, A1;
        {
            uint2 c0 = *(uint2*)&sb[(m*64 +  0 + g*4) ^ xr];
            uint2 c1 = *(uint2*)&sb[(m*64 + 16 + g*4) ^ xr];
            A0.u[0]=c0.x; A0.u[1]=c0.y; A0.u[2]=c1.x; A0.u[3]=c1.y;
            uint2 c2 = *(uint2*)&sb[(m*64 + 32 + g*4) ^ xr];
            uint2 c3 = *(uint2*)&sb[(m*64 + 48 + g*4) ^ xr];
            A1.u[0]=c2.x; A1.u[1]=c2.y; A1.u[2]=c3.x; A1.u[3]=c3.y;
        }
        float t1 = 0.f, t2 = 0.f;
        #pragma unroll
        for(int i=0;i<8;i++){
            float xv = (float)A0.v[i];
            t1 = fmaf(xv, wS[i>>2][i&3], t1);
            t2 = fmaf(xv, wD[i>>2][i&3], t2);
        }
        #pragma unroll
        for(int i=0;i<8;i++){
            float xv = (float)A1.v[i];
            t1 = fmaf(xv, wS[2+(i>>2)][i&3], t1);
            t2 = fmaf(xv, wD[2+(i>>2)][i&3], t2);
        }
        t1 += __shfl_xor(t1, 16, 64); t1 += __shfl_xor(t1, 32, 64);
        t2 += __shfl_xor(t2, 16, 64); t2 += __shfl_xor(t2, 32, 64);
        if(lane < 16 && rb + lane < n){ AS[rb+lane] = t1; AD[rb+lane] = t2; }
        vf4 z = {0.f,0.f,0.f,0.f};
        vf4 a0 = __builtin_amdgcn_mfma_f32_16x16x32_f16(A0.v, B[0].v, z, 0,0,0);
        a0     = __builtin_amdgcn_mfma_f32_16x16x32_f16(A1.v, B[1].v, a0, 0,0,0);
        vf4 a1 = __builtin_amdgcn_mfma_f32_16x16x32_f16(A0.v, B[2].v, z, 0,0,0);
        a1     = __builtin_amdgcn_mfma_f32_16x16x32_f16(A1.v, B[3].v, a1, 0,0,0);
        vf4 a2 = __builtin_amdgcn_mfma_f32_16x16x32_f16(A0.v, B[4].v, z, 0,0,0);
        a2     = __builtin_amdgcn_mfma_f32_16x16x32_f16(A1.v, B[5].v, a2, 0,0,0);
        vf4 a3 = __builtin_amdgcn_mfma_f32_16x16x32_f16(A0.v, B[6].v, z, 0,0,0);
        a3     = __builtin_amdgcn_mfma_f32_16x16x32_f16(A1.v, B[7].v, a3, 0,0,0);
        #pragma unroll
        for(int rr=0;rr<4;rr++){
            int row = rb + g*4 + rr;
            if(row < n){
                Hw[(size_t)row*32 + m]      = pk2(a0[rr], a1[rr]);
                Hw[(size_t)row*32 + 16 + m] = pk2(a2[rr], a3[rr]);
            }
        }
    }
}

// ---------------- GAT aggregate: quarter-wave per dst (4 dsts/wave) ----------------
__global__ __launch_bounds__(256) void k_agg(
    const uint_t* __restrict__ Hb, const float* __restrict__ AS, const float* __restrict__ AD,
    const int* __restrict__ rp, const int* __restrict__ col,
    const float* __restrict__ bias, float* __restrict__ OUT, int n)
{
    int t = threadIdx.x, lane = t & 63;
    int p = lane & 15;          // position within quarter
    int qb = lane & 48;         // quarter base lane (0,16,32,48)
    int w0 = 2*p;
    int c00 = 32*(w0>>4)+(w0&15), c01 = c00+16;
    int c10 = c00+1, c11 = c00+17;
    float b00 = bias[c00], b01 = bias[c01], b10 = bias[c10], b11 = bias[c11];
    int wv  = (blockIdx.x*256 + t) >> 6;
    int nwv = gridDim.x*4;
    for(int base = wv*4; base < n; base += nwv*4){
        int dq = min(base + (qb>>4), n-1);
        float ad = AD[dq];
        float wself = __expf(lrelu(AS[dq] + ad));
        uint2 hd = *(const uint2*)&Hb[(size_t)dq*32 + w0];
        float4 acc;
        acc.x = cvt_h(hd.x,0)*wself; acc.y = cvt_h(hd.x,16)*wself;
        acc.z = cvt_h(hd.y,0)*wself; acc.w = cvt_h(hd.y,16)*wself;
        float sacc = 0.f;
        int beg = rp[dq], end = rp[dq+1];
        int cnt = end - beg;
        int nit = (cnt + 15) >> 4;
        nit = max(nit, __shfl_xor(nit, 16, 64));
        nit = max(nit, __shfl_xor(nit, 32, 64));
        for(int it = 0; it < nit; it++){
            int j = beg + it*16 + p;
            bool valid = j < end;
            int sj = dq;
            if(cnt > 0) sj = col[valid ? j : end - 1];
            float wj = 0.f;
            if(valid) wj = __expf(lrelu(AS[sj] + ad));
            sacc += wj;
            int ccnt = cnt - it*16;
            ccnt = ccnt < 0 ? 0 : (ccnt > 16 ? 16 : ccnt);
            int emax = ccnt;
            emax = max(emax, __shfl_xor(emax, 16, 64));
            emax = max(emax, __shfl_xor(emax, 32, 64));
            int e = 0;
            for(; e + 4 <= emax; e += 4){
                float wq0 = __shfl(wj, qb+e,   64);
                float wq1 = __shfl(wj, qb+e+1, 64);
                float wq2 = __shfl(wj, qb+e+2, 64);
                float wq3 = __shfl(wj, qb+e+3, 64);
                int   sq0 = __shfl(sj, qb+e,   64);
                int   sq1 = __shfl(sj, qb+e+1, 64);
                int   sq2 = __shfl(sj, qb+e+2, 64);
                int   sq3 = __shfl(sj, qb+e+3, 64);
                uint2 v0 = *(const uint2*)&Hb[(size_t)sq0*32 + w0];
                uint2 v1 = *(const uint2*)&Hb[(size_t)sq1*32 + w0];
                uint2 v2 = *(const uint2*)&Hb[(size_t)sq2*32 + w0];
                uint2 v3 = *(const uint2*)&Hb[(size_t)sq3*32 + w0];
                acc.x = fmaf(wq0, cvt_h(v0.x,0),  acc.x);
                acc.y = fmaf(wq0, cvt_h(v0.x,16), acc.y);
                acc.z = fmaf(wq0, cvt_h(v0.y,0),  acc.z);
                acc.w = fmaf(wq0, cvt_h(v0.y,16), acc.w);
                acc.x = fmaf(wq1, cvt_h(v1.x,0),  acc.x);
                acc.y = fmaf(wq1, cvt_h(v1.x,16), acc.y);
                acc.z = fmaf(wq1, cvt_h(v1.y,0),  acc.z);
                acc.w = fmaf(wq1, cvt_h(v1.y,16), acc.w);
                acc.x = fmaf(wq2, cvt_h(v2.x,0),  acc.x);
                acc.y = fmaf(wq2, cvt_h(v2.x,16), acc.y);
                acc.z = fmaf(wq2, cvt_h(v2.y,0),  acc.z);
                acc.w = fmaf(wq2, cvt_h(v2.y,16), acc.w);
                acc.x = fmaf(wq3, cvt_h(v3.x,0),  acc.x);
                acc.y = fmaf(wq3, cvt_h(v3.x,16), acc.y);
                acc.z = fmaf(wq3, cvt_h(v3.y,0),  acc.z);
                acc.w = fmaf(wq3, cvt_h(v3.y,16), acc.w);
            }
            for(; e < emax; e++){
                float wq = __shfl(wj, qb+e, 64);
                int   sq = __shfl(sj, qb+e, 64);
                uint2 v = *(const uint2*)&Hb[(size_t)sq*32 + w0];
                acc.x = fmaf(wq, cvt_h(v.x,0),  acc.x);
                acc.y = fmaf(wq, cvt_h(v.x,16), acc.y);
                acc.z = fmaf(wq, cvt_h(v.y,0),  acc.z);
                acc.w = fmaf(wq, cvt_h(v.y,16), acc.w);
            }
        }
        sacc += __shfl_xor(sacc, 1, 64);
        sacc += __shfl_xor(sacc, 2, 64);
        sacc += __shfl_xor(sacc, 4, 64);
        sacc += __shfl_xor(sacc, 8, 64);
        float s = wself + sacc;
        float inv = 1.f/(s + 1e-16f);
        if(base + (qb>>4) < n){
            OUT[(size_t)dq*HD + c00] = fmaf(acc.x, inv, b00);
            OUT[(size_t)dq*HD + c01] = fmaf(acc.y, inv, b01);
            OUT[(size_t)dq*HD + c10] = fmaf(acc.z, inv, b10);
            OUT[(size_t)dq*HD + c11] = fmaf(acc.w, inv, b11);
        }
    }
}

// ---------------- virtual-node segment sum: LDS accumulate -> per-block PARTIAL store ----------------
__global__ __launch_bounds__(1024) void k_vnseg(const float* __restrict__ OUT, const int* __restrict__ hb,
                                                float* __restrict__ part, int n){
    __shared__ float acc[HNUM*HD];
    int t = threadIdx.x, lane = t & 63;
    for(int i=t;i<HNUM*HD;i+=1024) acc[i] = 0.f;
    __syncthreads();
    int wv  = (blockIdx.x*1024 + t) >> 6;
    int nwv = gridDim.x*16;
    for(int base = wv*8; base < n; base += nwv*8){
        float v[8]; int b[8];
        #pragma unroll
        for(int i=0;i<8;i++){
            int node = base + i;
            bool ok = node < n;
            v[i] = ok ? OUT[(size_t)node*HD + lane] : 0.f;
            b[i] = ok ? hb[node] : 0;
        }
        #pragma unroll
        for(int i=0;i<8;i++)
            if(v[i] != 0.f || (base + i < n)) atomicAdd(&acc[b[i]*HD + lane], v[i]);
    }
    __syncthreads();
    float* pp = part + (size_t)blockIdx.x*HNUM*HD;
    for(int i=t;i<HNUM*HD;i+=1024) pp[i] = acc[i];
}

// ---------------- vn update: one wave per vn row; partial reduce + LDS-broadcast MLPs ----------------
__global__ __launch_bounds__(64) void k_vn(
    const float* __restrict__ part, int nparts, const float* __restrict__ vne,
    const float* __restrict__ W1, const float* __restrict__ B1,
    const float* __restrict__ W2, const float* __restrict__ B2,
    float* __restrict__ vnD)
{
    __shared__ float sx[HD];
    int lane = threadIdx.x;
    int r = blockIdx.x;                 // vn row 0..HNUM-1
    const float* pr = part + (size_t)r*HD + lane;
    float a0=0.f, a1=0.f, a2=0.f, a3=0.f;
    int pb = 0;
    for(; pb + 4 <= nparts; pb += 4){
        a0 += pr[(size_t)(pb  )*HNUM*HD];
        a1 += pr[(size_t)(pb+1)*HNUM*HD];
        a2 += pr[(size_t)(pb+2)*HNUM*HD];
        a3 += pr[(size_t)(pb+3)*HNUM*HD];
    }
    for(; pb < nparts; pb++) a0 += pr[(size_t)pb*HNUM*HD];
    float ve = vne[lane];
    float a = ((a0+a1)+(a2+a3)) + ve + ve;   // segsum + vn_direct0 + vn_root0
    for(int j=0;j<NMLP;j++){
        const float* w1 = W1 + j*HD*HD; const float* b1 = B1 + j*HD;
        const float* w2 = W2 + j*HD*HD; const float* b2 = B2 + j*HD;
        __syncthreads();
        sx[lane] = a;
        __syncthreads();
        float t = b1[lane];
        #pragma unroll
        for(int in=0;in<HD;in++) t = fmaf(sx[in], w1[in*HD + lane], t);
        t = fmaxf(t, 0.f);
        __syncthreads();
        sx[lane] = t;
        __syncthreads();
        float u = b2[lane];
        #pragma unroll
        for(int in=0;in<HD;in++) u = fmaf(sx[in], w2[in*HD + lane], u);
        a = fmaxf(u, 0.f);
    }
    vnD[r*HD + lane] = a;
}

extern "C" void kernel_launch(void* const* d_in, const int* in_sizes, int n_in,
                              void* d_out, int out_size, void* d_ws, size_t ws_size,
                              hipStream_t stream)
{
    const float* x   = (const float*)d_in[0];
    const int*   ei  = (const int*)d_in[1];
    const int*   hb  = (const int*)d_in[2];
    const float* W0  = (const float*)d_in[5];
    const float* as0 = (const float*)d_in[6];
    const float* ad0 = (const float*)d_in[7];
    const float* b0  = (const float*)d_in[8];
    const float* Wl  = (const float*)d_in[9];
    const float* asl = (const float*)d_in[10];
    const float* adl = (const float*)d_in[11];
    const float* bl  = (const float*)d_in[12];
    const float* vne = (const float*)d_in[13];
    const float* mW1 = (const float*)d_in[14];
    const float* mb1 = (const float*)d_in[15];
    const float* mW2 = (const float*)d_in[16];
    const float* mb2 = (const float*)d_in[17];

    int N = in_sizes[0]/HD;
    int E = in_sizes[1]/2;
    const int* src = ei;
    const int* dst = ei + E;
    int NB = (N + (1<<BSH) - 1) >> BSH;

    char* p = (char*)d_ws;
    float* f_h   = (float*)p; p += (size_t)N*HD*4;   // fp16 H (lower half) + partials (upper half) + CSR alias
    float* f_as  = (float*)p; p += (size_t)N*4;
    float* f_ad  = (float*)p; p += (size_t)N*4;
    float* f_vnD = (float*)p; p += HNUM*HD*4;
    int*   i_rp  = (int*)p;   p += (size_t)(N+1)*4;
    int*   i_gb  = (int*)p;   p += MAXNB*4;
    int*   i_bb  = (int*)p;   p += MAXNB*4;
    int*   i_gc  = (int*)p;   p += MAXNB*4;
    int*   i_col = (int*)p;   p += (size_t)E*4;
    uint4* Wf3   = (uint4*)p; p += 3*512*16;
    float* waf3  = (float*)p; p += 3*8*64*4*4;
    int2*  bdata = (int2*)f_h;
    uint_t* Hw   = (uint_t*)f_h;                      // N*32 dwords = lower 12.8 MB
    float* f_part = (float*)((char*)f_h + (size_t)N*128);  // upper half: NPART*8192*4 = 8 MB

    float* outb = (float*)d_out;

    // one-time weight pack (3 blocks = 3 layers)
    k_wcvt<<<3, 256, 0, stream>>>(W0, as0, ad0, Wl, asl, adl, Wf3, waf3);

    hipMemsetAsync(i_gb, 0, MAXNB*4, stream);
    k_bcnt <<<512, 256, 0, stream>>>(dst, i_gb, E, NB);
    k_bscan<<<1, 512, 0, stream>>>(i_gb, i_bb, i_gc, NB);
    k_bin  <<<(E+EPB-1)/EPB, 256, 0, stream>>>(src, dst, i_gc, bdata, E, NB);
    k_bfuse<<<NB, 256, 0, stream>>>(bdata, i_bb, i_gb, i_rp, i_col, N, NB, E);

    int ga = 4096;
    int gg = 768;
    // conv0: GAT(x, W0)
    k_gemm<<<gg, 256, 0, stream>>>(x, nullptr, nullptr, hb, Wf3, waf3, Hw, f_as, f_ad, N);
    k_agg <<<ga, 256, 0, stream>>>(Hw, f_as, f_ad, i_rp, i_col, b0, outb, N);
    // conv1: GAT(out0 + vn_emb, Wl[0])
    k_gemm<<<gg, 256, 0, stream>>>(outb, vne, nullptr, hb, Wf3 + 512, waf3 + 2048, Hw, f_as, f_ad, N);
    k_agg <<<ga, 256, 0, stream>>>(Hw, f_as, f_ad, i_rp, i_col, bl, outb, N);
    // vn update: vnD = MLPs(segsum(out1) + 2*vne)  -- partials, no global atomics
    k_vnseg<<<NPART, 1024, 0, stream>>>(outb, hb, f_part, N);
    k_vn  <<<HNUM, 64, 0, stream>>>(f_part, NPART, vne, mW1, mb1, mW2, mb2, f_vnD);
    // conv2: GAT(out1 + vnD[hb], Wl[1]) -> final output
    k_gemm<<<gg, 256, 0, stream>>>(outb, nullptr, f_vnD, hb, Wf3 + 1024, waf3 + 4096, Hw, f_as, f_ad, N);
    k_agg <<<ga, 256, 0, stream>>>(Hw, f_as, f_ad, i_rp, i_col, bl + HD, outb, N);
}

// Round 11
// 301.092 us; speedup vs baseline: 2.6804x; 1.0158x over previous
//
#include <hip/hip_runtime.h>
#include <hip/hip_fp16.h>
#include <math.h>

#define HD 64
#define HNUM 128
#define NMLP 2
#define BSH 8              // 256 dst-nodes per bucket
#define MAXNB 512
#define EPB 2048           // edges per k_bin block
#define NPART 256          // k_vnseg partial blocks

typedef unsigned int uint_t;
typedef unsigned short ushort_t;
typedef _Float16 h8 __attribute__((ext_vector_type(8)));
typedef float vf4 __attribute__((ext_vector_type(4)));

union H8U { h8 v; uint_t u[4]; };

__device__ __forceinline__ float lrelu(float x){ return fmaxf(x, 0.2f*x); }

__device__ __forceinline__ float cvt_h(uint_t wv, uint_t sh){
    __half_raw hr; hr.x = (ushort_t)(wv >> sh);
    return __half2float((__half)hr);
}
__device__ __forceinline__ uint_t pk2(float a, float b){
    return (uint_t)__half_as_ushort(__float2half_rn(a)) |
           ((uint_t)__half_as_ushort(__float2half_rn(b)) << 16);
}

// ---------------- CSR build: bucketed counting sort ----------------
__global__ __launch_bounds__(256) void k_bcnt(const int* __restrict__ dst, int* __restrict__ gb,
                                              int E, int NB){
    __shared__ int h[MAXNB];
    int t = threadIdx.x;
    for(int i=t;i<NB;i+=256) h[i] = 0;
    __syncthreads();
    for(int e = blockIdx.x*256 + t; e < E; e += gridDim.x*256)
        atomicAdd(&h[dst[e]>>BSH], 1);
    __syncthreads();
    for(int i=t;i<NB;i+=256) if(h[i]) atomicAdd(&gb[i], h[i]);
}

__global__ __launch_bounds__(512) void k_bscan(const int* __restrict__ gb, int* __restrict__ bbase,
                                               int* __restrict__ gcur, int NB){
    __shared__ int s[512];
    int t = threadIdx.x;
    int v = (t < NB) ? gb[t] : 0;
    s[t] = v; __syncthreads();
    for(int o=1;o<512;o<<=1){
        int u = (t >= o) ? s[t-o] : 0;
        __syncthreads();
        s[t] += u;
        __syncthreads();
    }
    if(t < NB){ int ex = s[t] - v; bbase[t] = ex; gcur[t] = ex; }
}

__global__ __launch_bounds__(256) void k_bin(const int* __restrict__ src, const int* __restrict__ dst,
                                             int* __restrict__ gcur, int2* __restrict__ bdata,
                                             int E, int NB){
    __shared__ int cnt[MAXNB];
    __shared__ int base[MAXNB];
    int t = threadIdx.x;
    for(int i=t;i<NB;i+=256) cnt[i] = 0;
    __syncthreads();
    int s0 = blockIdx.x*EPB;
    int sv[8], dv[8], off[8];
    #pragma unroll
    for(int i=0;i<8;i++){
        int e = s0 + i*256 + t;
        if(e < E){
            sv[i] = src[e]; dv[i] = dst[e];
            off[i] = atomicAdd(&cnt[dv[i]>>BSH], 1);
        }
    }
    __syncthreads();
    for(int i=t;i<NB;i+=256) base[i] = cnt[i] ? atomicAdd(&gcur[i], cnt[i]) : 0;
    __syncthreads();
    #pragma unroll
    for(int i=0;i<8;i++){
        int e = s0 + i*256 + t;
        if(e < E) bdata[base[dv[i]>>BSH] + off[i]] = make_int2(sv[i], dv[i]);
    }
}

// fused per-bucket: LDS hist -> LDS scan -> rowptr slice -> LDS-cursor scatter
__global__ __launch_bounds__(256) void k_bfuse(const int2* __restrict__ bdata, const int* __restrict__ bbase,
                                               const int* __restrict__ gb, int* __restrict__ rp,
                                               int* __restrict__ col, int n, int NB, int E){
    __shared__ int h[256];
    __shared__ int sc[256];
    int b = blockIdx.x, t = threadIdx.x;
    int beg = bbase[b], cnt = gb[b];
    h[t] = 0; __syncthreads();
    for(int i=t;i<cnt;i+=256) atomicAdd(&h[bdata[beg+i].y & 255], 1);
    __syncthreads();
    int v = h[t];
    sc[t] = v; __syncthreads();
    for(int o=1;o<256;o<<=1){
        int u = (t >= o) ? sc[t-o] : 0;
        __syncthreads();
        sc[t] += u;
        __syncthreads();
    }
    int excl = sc[t] - v;
    int node = (b<<BSH) + t;
    if(node < n) rp[node] = beg + excl;
    if(b == NB-1 && t == 255) rp[n] = E;
    __syncthreads();
    sc[t] = excl;           // per-node local cursor
    __syncthreads();
    for(int i=t;i<cnt;i+=256){
        int2 e = bdata[beg+i];
        int pos = atomicAdd(&sc[e.y & 255], 1);
        col[beg + pos] = e.x;
    }
}

// ---------------- one-time weight fragment pack + W@a precompute ----------------
__global__ __launch_bounds__(256) void k_wcvt(
    const float* __restrict__ W0, const float* __restrict__ as0, const float* __restrict__ ad0,
    const float* __restrict__ Wl, const float* __restrict__ asl, const float* __restrict__ adl,
    uint4* __restrict__ Wf3, float* __restrict__ waf3)
{
    __shared__ float wa[2][64];
    int L = blockIdx.x, t = threadIdx.x;
    const float* W  = (L==0) ? W0  : Wl  + (L-1)*HD*HD;
    const float* as = (L==0) ? as0 : asl + (L-1)*HD;
    const float* ad = (L==0) ? ad0 : adl + (L-1)*HD;
    if(t < 128){
        int sd = t>>6, k = t&63;
        const float* av = sd ? ad : as;
        float acc = 0.f;
        for(int c=0;c<HD;c++) acc = fmaf(W[k*HD+c], av[c], acc);
        wa[sd][k] = acc;
    }
    __syncthreads();
    for(int it = t; it < 512; it += 256){
        int lane = it&63, s = (it>>6)&1, tile = it>>7;
        int g = lane>>4, m = lane&15, c = tile*16 + m;
        ushort_t h[8];
        #pragma unroll
        for(int i=0;i<8;i++){
            int k = s*32 + g*4 + (i&3) + 16*(i>>2);
            h[i] = __half_as_ushort(__float2half_rn(W[k*HD + c]));
        }
        uint4 q;
        q.x = (uint_t)h[0] | ((uint_t)h[1]<<16);
        q.y = (uint_t)h[2] | ((uint_t)h[3]<<16);
        q.z = (uint_t)h[4] | ((uint_t)h[5]<<16);
        q.w = (uint_t)h[6] | ((uint_t)h[7]<<16);
        Wf3[(size_t)L*512 + (tile*2+s)*64 + lane] = q;
    }
    if(t < 128){
        int lane = t&63, sd = t>>6, g = lane>>4;
        #pragma unroll
        for(int j4=0;j4<4;j4++){
            float v[4];
            #pragma unroll
            for(int e=0;e<4;e++){
                int j = j4*4 + e;
                int k = (j>>3)*32 + g*4 + (j&3) + 16*((j>>2)&1);
                v[e] = wa[sd][k];
            }
            float* dstp = waf3 + ((size_t)L*8 + sd*4 + j4)*64*4 + lane*4;
            dstp[0]=v[0]; dstp[1]=v[1]; dstp[2]=v[2]; dstp[3]=v[3];
        }
    }
}

// ---------------- MFMA GEMM: 16 rows x 64 cols per wave ----------------
// Hw pair-layout: row dword w holds fp16 cols (32*(w>>4)+(w&15), same+16)
__global__ __launch_bounds__(256) void k_gemm(
    const float* __restrict__ IN, const float* __restrict__ addrow,
    const float* __restrict__ addtab, const int* __restrict__ hb,
    const uint4* __restrict__ Wf, const float* __restrict__ waf,
    uint_t* __restrict__ Hw, float* __restrict__ AS, float* __restrict__ AD,
    int n)
{
    __shared__ ushort_t sx[4][1024];
    int t = threadIdx.x, lane = t&63, wv = t>>6;
    int g = lane>>4, m = lane&15;
    ushort_t* sb = sx[wv];

    H8U B[8];
    #pragma unroll
    for(int f=0; f<8; f++){
        uint4 q = Wf[f*64 + lane];
        B[f].u[0]=q.x; B[f].u[1]=q.y; B[f].u[2]=q.z; B[f].u[3]=q.w;
    }
    vf4 wS[4], wD[4];
    #pragma unroll
    for(int j4=0;j4<4;j4++){
        const float* ps = waf + ((size_t)0*4 + j4)*256 + lane*4;
        const float* pd = waf + ((size_t)1*4 + j4)*256 + lane*4;
        wS[j4] = vf4{ps[0],ps[1],ps[2],ps[3]};
        wD[j4] = vf4{pd[0],pd[1],pd[2],pd[3]};
    }
    float ar0=0,ar1=0,ar2=0,ar3=0;
    if(addrow){
        const float* a = &addrow[m*4];
        ar0=a[0]; ar1=a[1]; ar2=a[2]; ar3=a[3];
    }

    int ntiles = (n + 15) >> 4;
    int wgid = (blockIdx.x*256 + t) >> 6;
    int nw = gridDim.x*4;
    for(int tile = wgid; tile < ntiles; tile += nw){
        int rb = tile*16;
        #pragma unroll
        for(int p=0;p<4;p++){
            int row = p*4 + g;
            int rowc = min(rb + row, n-1);
            float4 x4 = *(const float4*)&IN[(size_t)rowc*HD + m*4];
            if(addrow){ x4.x+=ar0; x4.y+=ar1; x4.z+=ar2; x4.w+=ar3; }
            if(addtab){
                int b = hb[rowc];
                float4 a4 = *(const float4*)&addtab[b*HD + m*4];
                x4.x+=a4.x; x4.y+=a4.y; x4.z+=a4.z; x4.w+=a4.w;
            }
            uint2 pq; pq.x = pk2(x4.x, x4.y); pq.y = pk2(x4.z, x4.w);
            int idx = (row*64 + m*4) ^ ((row&7)<<3);
            *(uint2*)&sb[idx] = pq;
        }
        int xr = (m&7)<<3;
        H8U A0, A1;
        {
            uint2 c0 = *(uint2*)&sb[(m*64 +  0 + g*4) ^ xr];
            uint2 c1 = *(uint2*)&sb[(m*64 + 16 + g*4) ^ xr];
            A0.u[0]=c0.x; A0.u[1]=c0.y; A0.u[2]=c1.x; A0.u[3]=c1.y;
            uint2 c2 = *(uint2*)&sb[(m*64 + 32 + g*4) ^ xr];
            uint2 c3 = *(uint2*)&sb[(m*64 + 48 + g*4) ^ xr];
            A1.u[0]=c2.x; A1.u[1]=c2.y; A1.u[2]=c3.x; A1.u[3]=c3.y;
        }
        float t1 = 0.f, t2 = 0.f;
        #pragma unroll
        for(int i=0;i<8;i++){
            float xv = (float)A0.v[i];
            t1 = fmaf(xv, wS[i>>2][i&3], t1);
            t2 = fmaf(xv, wD[i>>2][i&3], t2);
        }
        #pragma unroll
        for(int i=0;i<8;i++){
            float xv = (float)A1.v[i];
            t1 = fmaf(xv, wS[2+(i>>2)][i&3], t1);
            t2 = fmaf(xv, wD[2+(i>>2)][i&3], t2);
        }
        t1 += __shfl_xor(t1, 16, 64); t1 += __shfl_xor(t1, 32, 64);
        t2 += __shfl_xor(t2, 16, 64); t2 += __shfl_xor(t2, 32, 64);
        if(lane < 16 && rb + lane < n){ AS[rb+lane] = t1; AD[rb+lane] = t2; }
        vf4 z = {0.f,0.f,0.f,0.f};
        vf4 a0 = __builtin_amdgcn_mfma_f32_16x16x32_f16(A0.v, B[0].v, z, 0,0,0);
        a0     = __builtin_amdgcn_mfma_f32_16x16x32_f16(A1.v, B[1].v, a0, 0,0,0);
        vf4 a1 = __builtin_amdgcn_mfma_f32_16x16x32_f16(A0.v, B[2].v, z, 0,0,0);
        a1     = __builtin_amdgcn_mfma_f32_16x16x32_f16(A1.v, B[3].v, a1, 0,0,0);
        vf4 a2 = __builtin_amdgcn_mfma_f32_16x16x32_f16(A0.v, B[4].v, z, 0,0,0);
        a2     = __builtin_amdgcn_mfma_f32_16x16x32_f16(A1.v, B[5].v, a2, 0,0,0);
        vf4 a3 = __builtin_amdgcn_mfma_f32_16x16x32_f16(A0.v, B[6].v, z, 0,0,0);
        a3     = __builtin_amdgcn_mfma_f32_16x16x32_f16(A1.v, B[7].v, a3, 0,0,0);
        #pragma unroll
        for(int rr=0;rr<4;rr++){
            int row = rb + g*4 + rr;
            if(row < n){
                Hw[(size_t)row*32 + m]      = pk2(a0[rr], a1[rr]);
                Hw[(size_t)row*32 + 16 + m] = pk2(a2[rr], a3[rr]);
            }
        }
    }
}

// ---------------- GAT aggregate: quarter-wave per dst (4 dsts/wave) ----------------
__global__ __launch_bounds__(256) void k_agg(
    const uint_t* __restrict__ Hb, const float* __restrict__ AS, const float* __restrict__ AD,
    const int* __restrict__ rp, const int* __restrict__ col,
    const float* __restrict__ bias, float* __restrict__ OUT, int n)
{
    int t = threadIdx.x, lane = t & 63;
    int p = lane & 15;          // position within quarter
    int qb = lane & 48;         // quarter base lane (0,16,32,48)
    int w0 = 2*p;
    int c00 = 32*(w0>>4)+(w0&15), c01 = c00+16;
    int c10 = c00+1, c11 = c00+17;
    float b00 = bias[c00], b01 = bias[c01], b10 = bias[c10], b11 = bias[c11];
    int wv  = (blockIdx.x*256 + t) >> 6;
    int nwv = gridDim.x*4;
    for(int base = wv*4; base < n; base += nwv*4){
        int dq = min(base + (qb>>4), n-1);
        float ad = AD[dq];
        float wself = __expf(lrelu(AS[dq] + ad));
        uint2 hd = *(const uint2*)&Hb[(size_t)dq*32 + w0];
        float4 acc;
        acc.x = cvt_h(hd.x,0)*wself; acc.y = cvt_h(hd.x,16)*wself;
        acc.z = cvt_h(hd.y,0)*wself; acc.w = cvt_h(hd.y,16)*wself;
        float sacc = 0.f;
        int beg = rp[dq], end = rp[dq+1];
        int cnt = end - beg;
        int nit = (cnt + 15) >> 4;
        nit = max(nit, __shfl_xor(nit, 16, 64));
        nit = max(nit, __shfl_xor(nit, 32, 64));
        for(int it = 0; it < nit; it++){
            int j = beg + it*16 + p;
            bool valid = j < end;
            int sj = dq;
            if(cnt > 0) sj = col[valid ? j : end - 1];
            float wj = 0.f;
            if(valid) wj = __expf(lrelu(AS[sj] + ad));
            sacc += wj;
            int ccnt = cnt - it*16;
            ccnt = ccnt < 0 ? 0 : (ccnt > 16 ? 16 : ccnt);
            int emax = ccnt;
            emax = max(emax, __shfl_xor(emax, 16, 64));
            emax = max(emax, __shfl_xor(emax, 32, 64));
            int e = 0;
            for(; e + 4 <= emax; e += 4){
                float wq0 = __shfl(wj, qb+e,   64);
                float wq1 = __shfl(wj, qb+e+1, 64);
                float wq2 = __shfl(wj, qb+e+2, 64);
                float wq3 = __shfl(wj, qb+e+3, 64);
                int   sq0 = __shfl(sj, qb+e,   64);
                int   sq1 = __shfl(sj, qb+e+1, 64);
                int   sq2 = __shfl(sj, qb+e+2, 64);
                int   sq3 = __shfl(sj, qb+e+3, 64);
                uint2 v0 = *(const uint2*)&Hb[(size_t)sq0*32 + w0];
                uint2 v1 = *(const uint2*)&Hb[(size_t)sq1*32 + w0];
                uint2 v2 = *(const uint2*)&Hb[(size_t)sq2*32 + w0];
                uint2 v3 = *(const uint2*)&Hb[(size_t)sq3*32 + w0];
                acc.x = fmaf(wq0, cvt_h(v0.x,0),  acc.x);
                acc.y = fmaf(wq0, cvt_h(v0.x,16), acc.y);
                acc.z = fmaf(wq0, cvt_h(v0.y,0),  acc.z);
                acc.w = fmaf(wq0, cvt_h(v0.y,16), acc.w);
                acc.x = fmaf(wq1, cvt_h(v1.x,0),  acc.x);
                acc.y = fmaf(wq1, cvt_h(v1.x,16), acc.y);
                acc.z = fmaf(wq1, cvt_h(v1.y,0),  acc.z);
                acc.w = fmaf(wq1, cvt_h(v1.y,16), acc.w);
                acc.x = fmaf(wq2, cvt_h(v2.x,0),  acc.x);
                acc.y = fmaf(wq2, cvt_h(v2.x,16), acc.y);
                acc.z = fmaf(wq2, cvt_h(v2.y,0),  acc.z);
                acc.w = fmaf(wq2, cvt_h(v2.y,16), acc.w);
                acc.x = fmaf(wq3, cvt_h(v3.x,0),  acc.x);
                acc.y = fmaf(wq3, cvt_h(v3.x,16), acc.y);
                acc.z = fmaf(wq3, cvt_h(v3.y,0),  acc.z);
                acc.w = fmaf(wq3, cvt_h(v3.y,16), acc.w);
            }
            for(; e < emax; e++){
                float wq = __shfl(wj, qb+e, 64);
                int   sq = __shfl(sj, qb+e, 64);
                uint2 v = *(const uint2*)&Hb[(size_t)sq*32 + w0];
                acc.x = fmaf(wq, cvt_h(v.x,0),  acc.x);
                acc.y = fmaf(wq, cvt_h(v.x,16), acc.y);
                acc.z = fmaf(wq, cvt_h(v.y,0),  acc.z);
                acc.w = fmaf(wq, cvt_h(v.y,16), acc.w);
            }
        }
        sacc += __shfl_xor(sacc, 1, 64);
        sacc += __shfl_xor(sacc, 2, 64);
        sacc += __shfl_xor(sacc, 4, 64);
        sacc += __shfl_xor(sacc, 8, 64);
        float s = wself + sacc;
        float inv = 1.f/(s + 1e-16f);
        if(base + (qb>>4) < n){
            OUT[(size_t)dq*HD + c00] = fmaf(acc.x, inv, b00);
            OUT[(size_t)dq*HD + c01] = fmaf(acc.y, inv, b01);
            OUT[(size_t)dq*HD + c10] = fmaf(acc.z, inv, b10);
            OUT[(size_t)dq*HD + c11] = fmaf(acc.w, inv, b11);
        }
    }
}

// ---------------- virtual-node segment sum: native ds_add_f32 via unsafeAtomicAdd ----------------
__global__ __launch_bounds__(1024) void k_vnseg(const float* __restrict__ OUT, const int* __restrict__ hb,
                                                float* __restrict__ part, int n){
    __shared__ float acc[HNUM*HD];
    int t = threadIdx.x, lane = t & 63;
    for(int i=t;i<HNUM*HD;i+=1024) acc[i] = 0.f;
    __syncthreads();
    int wv  = (blockIdx.x*1024 + t) >> 6;
    int nwv = gridDim.x*16;
    for(int base = wv*8; base < n; base += nwv*8){
        float v[8]; int b[8];
        #pragma unroll
        for(int i=0;i<8;i++){
            int node = base + i;
            bool ok = node < n;
            v[i] = ok ? OUT[(size_t)node*HD + lane] : 0.f;
            b[i] = ok ? hb[node] : 0;
        }
        #pragma unroll
        for(int i=0;i<8;i++)
            unsafeAtomicAdd(&acc[b[i]*HD + lane], v[i]);   // native ds_add_f32, no CAS loop
    }
    __syncthreads();
    float* pp = part + (size_t)blockIdx.x*HNUM*HD;
    for(int i=t;i<HNUM*HD;i+=1024) pp[i] = acc[i];
}

// ---------------- vn update: one wave per vn row; partial reduce + LDS-broadcast MLPs ----------------
__global__ __launch_bounds__(64) void k_vn(
    const float* __restrict__ part, int nparts, const float* __restrict__ vne,
    const float* __restrict__ W1, const float* __restrict__ B1,
    const float* __restrict__ W2, const float* __restrict__ B2,
    float* __restrict__ vnD)
{
    __shared__ float sx[HD];
    int lane = threadIdx.x;
    int r = blockIdx.x;                 // vn row 0..HNUM-1
    const float* pr = part + (size_t)r*HD + lane;
    float a0=0.f, a1=0.f, a2=0.f, a3=0.f;
    int pb = 0;
    for(; pb + 4 <= nparts; pb += 4){
        a0 += pr[(size_t)(pb  )*HNUM*HD];
        a1 += pr[(size_t)(pb+1)*HNUM*HD];
        a2 += pr[(size_t)(pb+2)*HNUM*HD];
        a3 += pr[(size_t)(pb+3)*HNUM*HD];
    }
    for(; pb < nparts; pb++) a0 += pr[(size_t)pb*HNUM*HD];
    float ve = vne[lane];
    float a = ((a0+a1)+(a2+a3)) + ve + ve;   // segsum + vn_direct0 + vn_root0
    for(int j=0;j<NMLP;j++){
        const float* w1 = W1 + j*HD*HD; const float* b1 = B1 + j*HD;
        const float* w2 = W2 + j*HD*HD; const float* b2 = B2 + j*HD;
        __syncthreads();
        sx[lane] = a;
        __syncthreads();
        float t = b1[lane];
        #pragma unroll
        for(int in=0;in<HD;in++) t = fmaf(sx[in], w1[in*HD + lane], t);
        t = fmaxf(t, 0.f);
        __syncthreads();
        sx[lane] = t;
        __syncthreads();
        float u = b2[lane];
        #pragma unroll
        for(int in=0;in<HD;in++) u = fmaf(sx[in], w2[in*HD + lane], u);
        a = fmaxf(u, 0.f);
    }
    vnD[r*HD + lane] = a;
}

extern "C" void kernel_launch(void* const* d_in, const int* in_sizes, int n_in,
                              void* d_out, int out_size, void* d_ws, size_t ws_size,
                              hipStream_t stream)
{
    const float* x   = (const float*)d_in[0];
    const int*   ei  = (const int*)d_in[1];
    const int*   hb  = (const int*)d_in[2];
    const float* W0  = (const float*)d_in[5];
    const float* as0 = (const float*)d_in[6];
    const float* ad0 = (const float*)d_in[7];
    const float* b0  = (const float*)d_in[8];
    const float* Wl  = (const float*)d_in[9];
    const float* asl = (const float*)d_in[10];
    const float* adl = (const float*)d_in[11];
    const float* bl  = (const float*)d_in[12];
    const float* vne = (const float*)d_in[13];
    const float* mW1 = (const float*)d_in[14];
    const float* mb1 = (const float*)d_in[15];
    const float* mW2 = (const float*)d_in[16];
    const float* mb2 = (const float*)d_in[17];

    int N = in_sizes[0]/HD;
    int E = in_sizes[1]/2;
    const int* src = ei;
    const int* dst = ei + E;
    int NB = (N + (1<<BSH) - 1) >> BSH;

    char* p = (char*)d_ws;
    float* f_h   = (float*)p; p += (size_t)N*HD*4;   // fp16 H (lower half) + partials (upper half) + CSR alias
    float* f_as  = (float*)p; p += (size_t)N*4;
    float* f_ad  = (float*)p; p += (size_t)N*4;
    float* f_vnD = (float*)p; p += HNUM*HD*4;
    int*   i_rp  = (int*)p;   p += (size_t)(N+1)*4;
    int*   i_gb  = (int*)p;   p += MAXNB*4;
    int*   i_bb  = (int*)p;   p += MAXNB*4;
    int*   i_gc  = (int*)p;   p += MAXNB*4;
    int*   i_col = (int*)p;   p += (size_t)E*4;
    uint4* Wf3   = (uint4*)p; p += 3*512*16;
    float* waf3  = (float*)p; p += 3*8*64*4*4;
    int2*  bdata = (int2*)f_h;
    uint_t* Hw   = (uint_t*)f_h;                      // N*32 dwords = lower 12.8 MB
    float* f_part = (float*)((char*)f_h + (size_t)N*128);  // upper half: NPART*8192*4 = 8 MB

    float* outb = (float*)d_out;

    // one-time weight pack (3 blocks = 3 layers)
    k_wcvt<<<3, 256, 0, stream>>>(W0, as0, ad0, Wl, asl, adl, Wf3, waf3);

    hipMemsetAsync(i_gb, 0, MAXNB*4, stream);
    k_bcnt <<<512, 256, 0, stream>>>(dst, i_gb, E, NB);
    k_bscan<<<1, 512, 0, stream>>>(i_gb, i_bb, i_gc, NB);
    k_bin  <<<(E+EPB-1)/EPB, 256, 0, stream>>>(src, dst, i_gc, bdata, E, NB);
    k_bfuse<<<NB, 256, 0, stream>>>(bdata, i_bb, i_gb, i_rp, i_col, N, NB, E);

    int ga = 4096;
    int gg = 768;
    // conv0: GAT(x, W0)
    k_gemm<<<gg, 256, 0, stream>>>(x, nullptr, nullptr, hb, Wf3, waf3, Hw, f_as, f_ad, N);
    k_agg <<<ga, 256, 0, stream>>>(Hw, f_as, f_ad, i_rp, i_col, b0, outb, N);
    // conv1: GAT(out0 + vn_emb, Wl[0])
    k_gemm<<<gg, 256, 0, stream>>>(outb, vne, nullptr, hb, Wf3 + 512, waf3 + 2048, Hw, f_as, f_ad, N);
    k_agg <<<ga, 256, 0, stream>>>(Hw, f_as, f_ad, i_rp, i_col, bl, outb, N);
    // vn update: vnD = MLPs(segsum(out1) + 2*vne)  -- partials, native LDS fadd
    k_vnseg<<<NPART, 1024, 0, stream>>>(outb, hb, f_part, N);
    k_vn  <<<HNUM, 64, 0, stream>>>(f_part, NPART, vne, mW1, mb1, mW2, mb2, f_vnD);
    // conv2: GAT(out1 + vnD[hb], Wl[1]) -> final output
    k_gemm<<<gg, 256, 0, stream>>>(outb, nullptr, f_vnD, hb, Wf3 + 1024, waf3 + 4096, Hw, f_as, f_ad, N);
    k_agg <<<ga, 256, 0, stream>>>(Hw, f_as, f_ad, i_rp, i_col, bl + HD, outb, N);
}

// Round 12
// 262.028 us; speedup vs baseline: 3.0800x; 1.1491x over previous
//
#include <hip/hip_runtime.h>
#include <hip/hip_fp16.h>
#include <math.h>

#define HD 64
#define HNUM 128
#define NMLP 2
#define BSH 8              // 256 dst-nodes per bucket
#define MAXNB 512
#define EPB 2048           // edges per k_bin block

typedef unsigned int uint_t;
typedef unsigned short ushort_t;
typedef _Float16 h8 __attribute__((ext_vector_type(8)));
typedef float vf4 __attribute__((ext_vector_type(4)));

union H8U { h8 v; uint_t u[4]; };

__device__ __forceinline__ float lrelu(float x){ return fmaxf(x, 0.2f*x); }

__device__ __forceinline__ float cvt_h(uint_t wv, uint_t sh){
    __half_raw hr; hr.x = (ushort_t)(wv >> sh);
    return __half2float((__half)hr);
}
__device__ __forceinline__ uint_t pk2(float a, float b){
    return (uint_t)__half_as_ushort(__float2half_rn(a)) |
           ((uint_t)__half_as_ushort(__float2half_rn(b)) << 16);
}

// ---------------- CSR build: bucketed counting sort ----------------
__global__ __launch_bounds__(256) void k_bcnt(const int* __restrict__ dst, int* __restrict__ gb,
                                              int E, int NB){
    __shared__ int h[MAXNB];
    int t = threadIdx.x;
    for(int i=t;i<NB;i+=256) h[i] = 0;
    __syncthreads();
    for(int e = blockIdx.x*256 + t; e < E; e += gridDim.x*256)
        atomicAdd(&h[dst[e]>>BSH], 1);
    __syncthreads();
    for(int i=t;i<NB;i+=256) if(h[i]) atomicAdd(&gb[i], h[i]);
}

__global__ __launch_bounds__(512) void k_bscan(const int* __restrict__ gb, int* __restrict__ bbase,
                                               int* __restrict__ gcur, int NB){
    __shared__ int s[512];
    int t = threadIdx.x;
    int v = (t < NB) ? gb[t] : 0;
    s[t] = v; __syncthreads();
    for(int o=1;o<512;o<<=1){
        int u = (t >= o) ? s[t-o] : 0;
        __syncthreads();
        s[t] += u;
        __syncthreads();
    }
    if(t < NB){ int ex = s[t] - v; bbase[t] = ex; gcur[t] = ex; }
}

__global__ __launch_bounds__(256) void k_bin(const int* __restrict__ src, const int* __restrict__ dst,
                                             int* __restrict__ gcur, int2* __restrict__ bdata,
                                             int E, int NB){
    __shared__ int cnt[MAXNB];
    __shared__ int base[MAXNB];
    int t = threadIdx.x;
    for(int i=t;i<NB;i+=256) cnt[i] = 0;
    __syncthreads();
    int s0 = blockIdx.x*EPB;
    int sv[8], dv[8], off[8];
    #pragma unroll
    for(int i=0;i<8;i++){
        int e = s0 + i*256 + t;
        if(e < E){
            sv[i] = src[e]; dv[i] = dst[e];
            off[i] = atomicAdd(&cnt[dv[i]>>BSH], 1);
        }
    }
    __syncthreads();
    for(int i=t;i<NB;i+=256) base[i] = cnt[i] ? atomicAdd(&gcur[i], cnt[i]) : 0;
    __syncthreads();
    #pragma unroll
    for(int i=0;i<8;i++){
        int e = s0 + i*256 + t;
        if(e < E) bdata[base[dv[i]>>BSH] + off[i]] = make_int2(sv[i], dv[i]);
    }
}

// fused per-bucket: LDS hist -> LDS scan -> rowptr slice -> LDS-cursor scatter
__global__ __launch_bounds__(256) void k_bfuse(const int2* __restrict__ bdata, const int* __restrict__ bbase,
                                               const int* __restrict__ gb, int* __restrict__ rp,
                                               int* __restrict__ col, int n, int NB, int E){
    __shared__ int h[256];
    __shared__ int sc[256];
    int b = blockIdx.x, t = threadIdx.x;
    int beg = bbase[b], cnt = gb[b];
    h[t] = 0; __syncthreads();
    for(int i=t;i<cnt;i+=256) atomicAdd(&h[bdata[beg+i].y & 255], 1);
    __syncthreads();
    int v = h[t];
    sc[t] = v; __syncthreads();
    for(int o=1;o<256;o<<=1){
        int u = (t >= o) ? sc[t-o] : 0;
        __syncthreads();
        sc[t] += u;
        __syncthreads();
    }
    int excl = sc[t] - v;
    int node = (b<<BSH) + t;
    if(node < n) rp[node] = beg + excl;
    if(b == NB-1 && t == 255) rp[n] = E;
    __syncthreads();
    sc[t] = excl;           // per-node local cursor
    __syncthreads();
    for(int i=t;i<cnt;i+=256){
        int2 e = bdata[beg+i];
        int pos = atomicAdd(&sc[e.y & 255], 1);
        col[beg + pos] = e.x;
    }
}

// ---------------- vn-group build: counting sort of nodes by hb ----------------
__global__ __launch_bounds__(256) void k_vcnt(const int* __restrict__ hb, int* __restrict__ vcnt, int n){
    __shared__ int h[HNUM];
    int t = threadIdx.x;
    if(t < HNUM) h[t] = 0;
    __syncthreads();
    for(int i = blockIdx.x*256 + t; i < n; i += gridDim.x*256) atomicAdd(&h[hb[i]], 1);
    __syncthreads();
    if(t < HNUM && h[t]) atomicAdd(&vcnt[t], h[t]);
}

__global__ __launch_bounds__(128) void k_vscan(const int* __restrict__ vcnt, int* __restrict__ vrp,
                                               int* __restrict__ vcur, int n){
    __shared__ int s[HNUM];
    int t = threadIdx.x;
    int v = vcnt[t];
    s[t] = v; __syncthreads();
    for(int o=1;o<HNUM;o<<=1){
        int u = (t >= o) ? s[t-o] : 0;
        __syncthreads();
        s[t] += u;
        __syncthreads();
    }
    int ex = s[t] - v;
    vrp[t] = ex; vcur[t] = ex;
    if(t == HNUM-1) vrp[HNUM] = n;
}

__global__ __launch_bounds__(256) void k_vbin(const int* __restrict__ hb, int* __restrict__ vcur,
                                              int* __restrict__ perm, int n){
    __shared__ int cnt[HNUM];
    __shared__ int base[HNUM];
    int t = threadIdx.x;
    if(t < HNUM) cnt[t] = 0;
    __syncthreads();
    int s0 = blockIdx.x*2048;
    int hv[8], off[8];
    #pragma unroll
    for(int i=0;i<8;i++){
        int nd = s0 + i*256 + t;
        if(nd < n){ hv[i] = hb[nd]; off[i] = atomicAdd(&cnt[hv[i]], 1); }
    }
    __syncthreads();
    if(t < HNUM) base[t] = cnt[t] ? atomicAdd(&vcur[t], cnt[t]) : 0;
    __syncthreads();
    #pragma unroll
    for(int i=0;i<8;i++){
        int nd = s0 + i*256 + t;
        if(nd < n) perm[base[hv[i]] + off[i]] = nd;
    }
}

// ---------------- one-time weight fragment pack + W@a precompute ----------------
__global__ __launch_bounds__(256) void k_wcvt(
    const float* __restrict__ W0, const float* __restrict__ as0, const float* __restrict__ ad0,
    const float* __restrict__ Wl, const float* __restrict__ asl, const float* __restrict__ adl,
    uint4* __restrict__ Wf3, float* __restrict__ waf3)
{
    __shared__ float wa[2][64];
    int L = blockIdx.x, t = threadIdx.x;
    const float* W  = (L==0) ? W0  : Wl  + (L-1)*HD*HD;
    const float* as = (L==0) ? as0 : asl + (L-1)*HD;
    const float* ad = (L==0) ? ad0 : adl + (L-1)*HD;
    if(t < 128){
        int sd = t>>6, k = t&63;
        const float* av = sd ? ad : as;
        float acc = 0.f;
        for(int c=0;c<HD;c++) acc = fmaf(W[k*HD+c], av[c], acc);
        wa[sd][k] = acc;
    }
    __syncthreads();
    for(int it = t; it < 512; it += 256){
        int lane = it&63, s = (it>>6)&1, tile = it>>7;
        int g = lane>>4, m = lane&15, c = tile*16 + m;
        ushort_t h[8];
        #pragma unroll
        for(int i=0;i<8;i++){
            int k = s*32 + g*4 + (i&3) + 16*(i>>2);
            h[i] = __half_as_ushort(__float2half_rn(W[k*HD + c]));
        }
        uint4 q;
        q.x = (uint_t)h[0] | ((uint_t)h[1]<<16);
        q.y = (uint_t)h[2] | ((uint_t)h[3]<<16);
        q.z = (uint_t)h[4] | ((uint_t)h[5]<<16);
        q.w = (uint_t)h[6] | ((uint_t)h[7]<<16);
        Wf3[(size_t)L*512 + (tile*2+s)*64 + lane] = q;
    }
    if(t < 128){
        int lane = t&63, sd = t>>6, g = lane>>4;
        #pragma unroll
        for(int j4=0;j4<4;j4++){
            float v[4];
            #pragma unroll
            for(int e=0;e<4;e++){
                int j = j4*4 + e;
                int k = (j>>3)*32 + g*4 + (j&3) + 16*((j>>2)&1);
                v[e] = wa[sd][k];
            }
            float* dstp = waf3 + ((size_t)L*8 + sd*4 + j4)*64*4 + lane*4;
            dstp[0]=v[0]; dstp[1]=v[1]; dstp[2]=v[2]; dstp[3]=v[3];
        }
    }
}

// ---------------- MFMA GEMM: 16 rows x 64 cols per wave ----------------
// Hw pair-layout: row dword w holds fp16 cols (32*(w>>4)+(w&15), same+16)
__global__ __launch_bounds__(256) void k_gemm(
    const float* __restrict__ IN, const float* __restrict__ addrow,
    const float* __restrict__ addtab, const int* __restrict__ hb,
    const uint4* __restrict__ Wf, const float* __restrict__ waf,
    uint_t* __restrict__ Hw, float* __restrict__ AS, float* __restrict__ AD,
    int n)
{
    __shared__ ushort_t sx[4][1024];
    int t = threadIdx.x, lane = t&63, wv = t>>6;
    int g = lane>>4, m = lane&15;
    ushort_t* sb = sx[wv];

    H8U B[8];
    #pragma unroll
    for(int f=0; f<8; f++){
        uint4 q = Wf[f*64 + lane];
        B[f].u[0]=q.x; B[f].u[1]=q.y; B[f].u[2]=q.z; B[f].u[3]=q.w;
    }
    vf4 wS[4], wD[4];
    #pragma unroll
    for(int j4=0;j4<4;j4++){
        const float* ps = waf + ((size_t)0*4 + j4)*256 + lane*4;
        const float* pd = waf + ((size_t)1*4 + j4)*256 + lane*4;
        wS[j4] = vf4{ps[0],ps[1],ps[2],ps[3]};
        wD[j4] = vf4{pd[0],pd[1],pd[2],pd[3]};
    }
    float ar0=0,ar1=0,ar2=0,ar3=0;
    if(addrow){
        const float* a = &addrow[m*4];
        ar0=a[0]; ar1=a[1]; ar2=a[2]; ar3=a[3];
    }

    int ntiles = (n + 15) >> 4;
    int wgid = (blockIdx.x*256 + t) >> 6;
    int nw = gridDim.x*4;
    for(int tile = wgid; tile < ntiles; tile += nw){
        int rb = tile*16;
        #pragma unroll
        for(int p=0;p<4;p++){
            int row = p*4 + g;
            int rowc = min(rb + row, n-1);
            float4 x4 = *(const float4*)&IN[(size_t)rowc*HD + m*4];
            if(addrow){ x4.x+=ar0; x4.y+=ar1; x4.z+=ar2; x4.w+=ar3; }
            if(addtab){
                int b = hb[rowc];
                float4 a4 = *(const float4*)&addtab[b*HD + m*4];
                x4.x+=a4.x; x4.y+=a4.y; x4.z+=a4.z; x4.w+=a4.w;
            }
            uint2 pq; pq.x = pk2(x4.x, x4.y); pq.y = pk2(x4.z, x4.w);
            int idx = (row*64 + m*4) ^ ((row&7)<<3);
            *(uint2*)&sb[idx] = pq;
        }
        int xr = (m&7)<<3;
        H8U A0, A1;
        {
            uint2 c0 = *(uint2*)&sb[(m*64 +  0 + g*4) ^ xr];
            uint2 c1 = *(uint2*)&sb[(m*64 + 16 + g*4) ^ xr];
            A0.u[0]=c0.x; A0.u[1]=c0.y; A0.u[2]=c1.x; A0.u[3]=c1.y;
            uint2 c2 = *(uint2*)&sb[(m*64 + 32 + g*4) ^ xr];
            uint2 c3 = *(uint2*)&sb[(m*64 + 48 + g*4) ^ xr];
            A1.u[0]=c2.x; A1.u[1]=c2.y; A1.u[2]=c3.x; A1.u[3]=c3.y;
        }
        float t1 = 0.f, t2 = 0.f;
        #pragma unroll
        for(int i=0;i<8;i++){
            float xv = (float)A0.v[i];
            t1 = fmaf(xv, wS[i>>2][i&3], t1);
            t2 = fmaf(xv, wD[i>>2][i&3], t2);
        }
        #pragma unroll
        for(int i=0;i<8;i++){
            float xv = (float)A1.v[i];
            t1 = fmaf(xv, wS[2+(i>>2)][i&3], t1);
            t2 = fmaf(xv, wD[2+(i>>2)][i&3], t2);
        }
        t1 += __shfl_xor(t1, 16, 64); t1 += __shfl_xor(t1, 32, 64);
        t2 += __shfl_xor(t2, 16, 64); t2 += __shfl_xor(t2, 32, 64);
        if(lane < 16 && rb + lane < n){ AS[rb+lane] = t1; AD[rb+lane] = t2; }
        vf4 z = {0.f,0.f,0.f,0.f};
        vf4 a0 = __builtin_amdgcn_mfma_f32_16x16x32_f16(A0.v, B[0].v, z, 0,0,0);
        a0     = __builtin_amdgcn_mfma_f32_16x16x32_f16(A1.v, B[1].v, a0, 0,0,0);
        vf4 a1 = __builtin_amdgcn_mfma_f32_16x16x32_f16(A0.v, B[2].v, z, 0,0,0);
        a1     = __builtin_amdgcn_mfma_f32_16x16x32_f16(A1.v, B[3].v, a1, 0,0,0);
        vf4 a2 = __builtin_amdgcn_mfma_f32_16x16x32_f16(A0.v, B[4].v, z, 0,0,0);
        a2     = __builtin_amdgcn_mfma_f32_16x16x32_f16(A1.v, B[5].v, a2, 0,0,0);
        vf4 a3 = __builtin_amdgcn_mfma_f32_16x16x32_f16(A0.v, B[6].v, z, 0,0,0);
        a3     = __builtin_amdgcn_mfma_f32_16x16x32_f16(A1.v, B[7].v, a3, 0,0,0);
        #pragma unroll
        for(int rr=0;rr<4;rr++){
            int row = rb + g*4 + rr;
            if(row < n){
                Hw[(size_t)row*32 + m]      = pk2(a0[rr], a1[rr]);
                Hw[(size_t)row*32 + 16 + m] = pk2(a2[rr], a3[rr]);
            }
        }
    }
}

// ---------------- GAT aggregate: quarter-wave per dst (4 dsts/wave) ----------------
__global__ __launch_bounds__(256) void k_agg(
    const uint_t* __restrict__ Hb, const float* __restrict__ AS, const float* __restrict__ AD,
    const int* __restrict__ rp, const int* __restrict__ col,
    const float* __restrict__ bias, float* __restrict__ OUT, int n)
{
    int t = threadIdx.x, lane = t & 63;
    int p = lane & 15;          // position within quarter
    int qb = lane & 48;         // quarter base lane (0,16,32,48)
    int w0 = 2*p;
    int c00 = 32*(w0>>4)+(w0&15), c01 = c00+16;
    int c10 = c00+1, c11 = c00+17;
    float b00 = bias[c00], b01 = bias[c01], b10 = bias[c10], b11 = bias[c11];
    int wv  = (blockIdx.x*256 + t) >> 6;
    int nwv = gridDim.x*4;
    for(int base = wv*4; base < n; base += nwv*4){
        int dq = min(base + (qb>>4), n-1);
        float ad = AD[dq];
        float wself = __expf(lrelu(AS[dq] + ad));
        uint2 hd = *(const uint2*)&Hb[(size_t)dq*32 + w0];
        float4 acc;
        acc.x = cvt_h(hd.x,0)*wself; acc.y = cvt_h(hd.x,16)*wself;
        acc.z = cvt_h(hd.y,0)*wself; acc.w = cvt_h(hd.y,16)*wself;
        float sacc = 0.f;
        int beg = rp[dq], end = rp[dq+1];
        int cnt = end - beg;
        int nit = (cnt + 15) >> 4;
        nit = max(nit, __shfl_xor(nit, 16, 64));
        nit = max(nit, __shfl_xor(nit, 32, 64));
        for(int it = 0; it < nit; it++){
            int j = beg + it*16 + p;
            bool valid = j < end;
            int sj = dq;
            if(cnt > 0) sj = col[valid ? j : end - 1];
            float wj = 0.f;
            if(valid) wj = __expf(lrelu(AS[sj] + ad));
            sacc += wj;
            int ccnt = cnt - it*16;
            ccnt = ccnt < 0 ? 0 : (ccnt > 16 ? 16 : ccnt);
            int emax = ccnt;
            emax = max(emax, __shfl_xor(emax, 16, 64));
            emax = max(emax, __shfl_xor(emax, 32, 64));
            int e = 0;
            for(; e + 4 <= emax; e += 4){
                float wq0 = __shfl(wj, qb+e,   64);
                float wq1 = __shfl(wj, qb+e+1, 64);
                float wq2 = __shfl(wj, qb+e+2, 64);
                float wq3 = __shfl(wj, qb+e+3, 64);
                int   sq0 = __shfl(sj, qb+e,   64);
                int   sq1 = __shfl(sj, qb+e+1, 64);
                int   sq2 = __shfl(sj, qb+e+2, 64);
                int   sq3 = __shfl(sj, qb+e+3, 64);
                uint2 v0 = *(const uint2*)&Hb[(size_t)sq0*32 + w0];
                uint2 v1 = *(const uint2*)&Hb[(size_t)sq1*32 + w0];
                uint2 v2 = *(const uint2*)&Hb[(size_t)sq2*32 + w0];
                uint2 v3 = *(const uint2*)&Hb[(size_t)sq3*32 + w0];
                acc.x = fmaf(wq0, cvt_h(v0.x,0),  acc.x);
                acc.y = fmaf(wq0, cvt_h(v0.x,16), acc.y);
                acc.z = fmaf(wq0, cvt_h(v0.y,0),  acc.z);
                acc.w = fmaf(wq0, cvt_h(v0.y,16), acc.w);
                acc.x = fmaf(wq1, cvt_h(v1.x,0),  acc.x);
                acc.y = fmaf(wq1, cvt_h(v1.x,16), acc.y);
                acc.z = fmaf(wq1, cvt_h(v1.y,0),  acc.z);
                acc.w = fmaf(wq1, cvt_h(v1.y,16), acc.w);
                acc.x = fmaf(wq2, cvt_h(v2.x,0),  acc.x);
                acc.y = fmaf(wq2, cvt_h(v2.x,16), acc.y);
                acc.z = fmaf(wq2, cvt_h(v2.y,0),  acc.z);
                acc.w = fmaf(wq2, cvt_h(v2.y,16), acc.w);
                acc.x = fmaf(wq3, cvt_h(v3.x,0),  acc.x);
                acc.y = fmaf(wq3, cvt_h(v3.x,16), acc.y);
                acc.z = fmaf(wq3, cvt_h(v3.y,0),  acc.z);
                acc.w = fmaf(wq3, cvt_h(v3.y,16), acc.w);
            }
            for(; e < emax; e++){
                float wq = __shfl(wj, qb+e, 64);
                int   sq = __shfl(sj, qb+e, 64);
                uint2 v = *(const uint2*)&Hb[(size_t)sq*32 + w0];
                acc.x = fmaf(wq, cvt_h(v.x,0),  acc.x);
                acc.y = fmaf(wq, cvt_h(v.x,16), acc.y);
                acc.z = fmaf(wq, cvt_h(v.y,0),  acc.z);
                acc.w = fmaf(wq, cvt_h(v.y,16), acc.w);
            }
        }
        sacc += __shfl_xor(sacc, 1, 64);
        sacc += __shfl_xor(sacc, 2, 64);
        sacc += __shfl_xor(sacc, 4, 64);
        sacc += __shfl_xor(sacc, 8, 64);
        float s = wself + sacc;
        float inv = 1.f/(s + 1e-16f);
        if(base + (qb>>4) < n){
            OUT[(size_t)dq*HD + c00] = fmaf(acc.x, inv, b00);
            OUT[(size_t)dq*HD + c01] = fmaf(acc.y, inv, b01);
            OUT[(size_t)dq*HD + c10] = fmaf(acc.z, inv, b10);
            OUT[(size_t)dq*HD + c11] = fmaf(acc.w, inv, b11);
        }
    }
}

// ---------------- vn segment sum: hb-grouped, pure register accumulation ----------------
// 8 blocks x 4 waves per vn-group; wave accumulates strided rows, one global fadd at end.
__global__ __launch_bounds__(256) void k_vsum(const float* __restrict__ OUT, const int* __restrict__ perm,
                                              const int* __restrict__ vrp, float* __restrict__ vnS){
    int t = threadIdx.x, lane = t & 63, w = t >> 6;
    int g = blockIdx.x >> 3, sub = blockIdx.x & 7;
    int wig = sub*4 + w;                  // wave index in group: 0..31
    int beg = vrp[g], end = vrp[g+1];
    float a0=0.f, a1=0.f, a2=0.f, a3=0.f;
    int i = beg + wig;
    for(; i + 96 < end; i += 128){
        int p0 = perm[i], p1 = perm[i+32], p2 = perm[i+64], p3 = perm[i+96];
        a0 += OUT[(size_t)p0*HD + lane];
        a1 += OUT[(size_t)p1*HD + lane];
        a2 += OUT[(size_t)p2*HD + lane];
        a3 += OUT[(size_t)p3*HD + lane];
    }
    for(; i < end; i += 32) a0 += OUT[(size_t)perm[i]*HD + lane];
    float a = (a0+a1)+(a2+a3);
    unsafeAtomicAdd(&vnS[g*HD + lane], a);   // 32 contenders per address
}

// ---------------- vn update: one wave per vn row; LDS-broadcast MLPs ----------------
__global__ __launch_bounds__(64) void k_vn(
    const float* __restrict__ vnS, const float* __restrict__ vne,
    const float* __restrict__ W1, const float* __restrict__ B1,
    const float* __restrict__ W2, const float* __restrict__ B2,
    float* __restrict__ vnD)
{
    __shared__ float sx[HD];
    int lane = threadIdx.x;
    int r = blockIdx.x;                 // vn row 0..HNUM-1
    float ve = vne[lane];
    float a = vnS[r*HD + lane] + ve + ve;   // segsum + vn_direct0 + vn_root0
    for(int j=0;j<NMLP;j++){
        const float* w1 = W1 + j*HD*HD; const float* b1 = B1 + j*HD;
        const float* w2 = W2 + j*HD*HD; const float* b2 = B2 + j*HD;
        __syncthreads();
        sx[lane] = a;
        __syncthreads();
        float t = b1[lane];
        #pragma unroll
        for(int in=0;in<HD;in++) t = fmaf(sx[in], w1[in*HD + lane], t);
        t = fmaxf(t, 0.f);
        __syncthreads();
        sx[lane] = t;
        __syncthreads();
        float u = b2[lane];
        #pragma unroll
        for(int in=0;in<HD;in++) u = fmaf(sx[in], w2[in*HD + lane], u);
        a = fmaxf(u, 0.f);
    }
    vnD[r*HD + lane] = a;
}

extern "C" void kernel_launch(void* const* d_in, const int* in_sizes, int n_in,
                              void* d_out, int out_size, void* d_ws, size_t ws_size,
                              hipStream_t stream)
{
    const float* x   = (const float*)d_in[0];
    const int*   ei  = (const int*)d_in[1];
    const int*   hb  = (const int*)d_in[2];
    const float* W0  = (const float*)d_in[5];
    const float* as0 = (const float*)d_in[6];
    const float* ad0 = (const float*)d_in[7];
    const float* b0  = (const float*)d_in[8];
    const float* Wl  = (const float*)d_in[9];
    const float* asl = (const float*)d_in[10];
    const float* adl = (const float*)d_in[11];
    const float* bl  = (const float*)d_in[12];
    const float* vne = (const float*)d_in[13];
    const float* mW1 = (const float*)d_in[14];
    const float* mb1 = (const float*)d_in[15];
    const float* mW2 = (const float*)d_in[16];
    const float* mb2 = (const float*)d_in[17];

    int N = in_sizes[0]/HD;
    int E = in_sizes[1]/2;
    const int* src = ei;
    const int* dst = ei + E;
    int NB = (N + (1<<BSH) - 1) >> BSH;

    char* p = (char*)d_ws;
    float* f_h   = (float*)p; p += (size_t)N*HD*4;   // fp16 H (lower half) + CSR alias
    float* f_as  = (float*)p; p += (size_t)N*4;
    float* f_ad  = (float*)p; p += (size_t)N*4;
    float* f_vnD = (float*)p; p += HNUM*HD*4;
    float* f_vnS = (float*)p; p += HNUM*HD*4;        // zeroed with i_vcnt below
    int*   i_vcnt= (int*)p;   p += HNUM*4;
    int*   i_vrp = (int*)p;   p += (HNUM+1)*4;
    int*   i_vcur= (int*)p;   p += HNUM*4;
    int*   i_perm= (int*)p;   p += (size_t)N*4;
    int*   i_rp  = (int*)p;   p += (size_t)(N+1)*4;
    int*   i_gb  = (int*)p;   p += MAXNB*4;
    int*   i_bb  = (int*)p;   p += MAXNB*4;
    int*   i_gc  = (int*)p;   p += MAXNB*4;
    int*   i_col = (int*)p;   p += (size_t)E*4;
    uint4* Wf3   = (uint4*)p; p += 3*512*16;
    float* waf3  = (float*)p; p += 3*8*64*4*4;
    int2*  bdata = (int2*)f_h;
    uint_t* Hw   = (uint_t*)f_h;                      // N*32 dwords = lower 12.8 MB

    float* outb = (float*)d_out;

    // one-time weight pack (3 blocks = 3 layers)
    k_wcvt<<<3, 256, 0, stream>>>(W0, as0, ad0, Wl, asl, adl, Wf3, waf3);

    hipMemsetAsync(i_gb, 0, MAXNB*4, stream);
    hipMemsetAsync(f_vnS, 0, HNUM*HD*4 + HNUM*4, stream);   // vnS + vcnt
    // edge CSR
    k_bcnt <<<512, 256, 0, stream>>>(dst, i_gb, E, NB);
    k_bscan<<<1, 512, 0, stream>>>(i_gb, i_bb, i_gc, NB);
    k_bin  <<<(E+EPB-1)/EPB, 256, 0, stream>>>(src, dst, i_gc, bdata, E, NB);
    k_bfuse<<<NB, 256, 0, stream>>>(bdata, i_bb, i_gb, i_rp, i_col, N, NB, E);
    // vn-group permutation (counting sort of nodes by hb)
    k_vcnt <<<128, 256, 0, stream>>>(hb, i_vcnt, N);
    k_vscan<<<1, 128, 0, stream>>>(i_vcnt, i_vrp, i_vcur, N);
    k_vbin <<<(N+2047)/2048, 256, 0, stream>>>(hb, i_vcur, i_perm, N);

    int ga = 4096;
    int gg = 768;
    // conv0: GAT(x, W0)
    k_gemm<<<gg, 256, 0, stream>>>(x, nullptr, nullptr, hb, Wf3, waf3, Hw, f_as, f_ad, N);
    k_agg <<<ga, 256, 0, stream>>>(Hw, f_as, f_ad, i_rp, i_col, b0, outb, N);
    // conv1: GAT(out0 + vn_emb, Wl[0])
    k_gemm<<<gg, 256, 0, stream>>>(outb, vne, nullptr, hb, Wf3 + 512, waf3 + 2048, Hw, f_as, f_ad, N);
    k_agg <<<ga, 256, 0, stream>>>(Hw, f_as, f_ad, i_rp, i_col, bl, outb, N);
    // vn update: vnD = MLPs(segsum(out1) + 2*vne)  -- grouped register sum
    k_vsum<<<HNUM*8, 256, 0, stream>>>(outb, i_perm, i_vrp, f_vnS);
    k_vn  <<<HNUM, 64, 0, stream>>>(f_vnS, vne, mW1, mb1, mW2, mb2, f_vnD);
    // conv2: GAT(out1 + vnD[hb], Wl[1]) -> final output
    k_gemm<<<gg, 256, 0, stream>>>(outb, nullptr, f_vnD, hb, Wf3 + 1024, waf3 + 4096, Hw, f_as, f_ad, N);
    k_agg <<<ga, 256, 0, stream>>>(Hw, f_as, f_ad, i_rp, i_col, bl + HD, outb, N);
}

// Round 13
// 246.698 us; speedup vs baseline: 3.2714x; 1.0621x over previous
//
#include <hip/hip_runtime.h>
#include <hip/hip_fp16.h>
#include <math.h>

#define HD 64
#define HNUM 128
#define NMLP 2
#define BSH 8              // 256 dst-nodes per bucket
#define MAXNB 512
#define EPB 4096           // edges per k_bin block (16/thread)

typedef unsigned int uint_t;
typedef unsigned short ushort_t;
typedef _Float16 h8 __attribute__((ext_vector_type(8)));
typedef float vf4 __attribute__((ext_vector_type(4)));

union H8U { h8 v; uint_t u[4]; };

__device__ __forceinline__ float lrelu(float x){ return fmaxf(x, 0.2f*x); }

__device__ __forceinline__ float cvt_h(uint_t wv, uint_t sh){
    __half_raw hr; hr.x = (ushort_t)(wv >> sh);
    return __half2float((__half)hr);
}
__device__ __forceinline__ uint_t pk2(float a, float b){
    return (uint_t)__half_as_ushort(__float2half_rn(a)) |
           ((uint_t)__half_as_ushort(__float2half_rn(b)) << 16);
}

// ---------------- CSR build: bucketed counting sort (packed 4B records) ----------------
__global__ __launch_bounds__(256) void k_bcnt(const int* __restrict__ dst, int* __restrict__ gb,
                                              int E, int NB){
    __shared__ int h[MAXNB];
    int t = threadIdx.x;
    for(int i=t;i<NB;i+=256) h[i] = 0;
    __syncthreads();
    for(int e = blockIdx.x*256 + t; e < E; e += gridDim.x*256)
        atomicAdd(&h[dst[e]>>BSH], 1);
    __syncthreads();
    for(int i=t;i<NB;i+=256) if(h[i]) atomicAdd(&gb[i], h[i]);
}

__global__ __launch_bounds__(512) void k_bscan(const int* __restrict__ gb, int* __restrict__ bbase,
                                               int* __restrict__ gcur, int NB){
    __shared__ int s[512];
    int t = threadIdx.x;
    int v = (t < NB) ? gb[t] : 0;
    s[t] = v; __syncthreads();
    for(int o=1;o<512;o<<=1){
        int u = (t >= o) ? s[t-o] : 0;
        __syncthreads();
        s[t] += u;
        __syncthreads();
    }
    if(t < NB){ int ex = s[t] - v; bbase[t] = ex; gcur[t] = ex; }
}

// bin edges as packed (src<<8)|(dst&255); 16 edges/thread to coarsen bucket claims
__global__ __launch_bounds__(256) void k_bin(const int* __restrict__ src, const int* __restrict__ dst,
                                             int* __restrict__ gcur, uint_t* __restrict__ bdata,
                                             int E, int NB){
    __shared__ int cnt[MAXNB];
    __shared__ int base[MAXNB];
    int t = threadIdx.x;
    for(int i=t;i<NB;i+=256) cnt[i] = 0;
    __syncthreads();
    int s0 = blockIdx.x*EPB;
    uint_t pk[16]; int bk[16], off[16];
    #pragma unroll
    for(int i=0;i<16;i++){
        int e = s0 + i*256 + t;
        if(e < E){
            int sv = src[e], dv = dst[e];
            pk[i]  = ((uint_t)sv << 8) | (uint_t)(dv & 255);
            bk[i]  = dv >> BSH;
            off[i] = atomicAdd(&cnt[bk[i]], 1);
        }
    }
    __syncthreads();
    for(int i=t;i<NB;i+=256) base[i] = cnt[i] ? atomicAdd(&gcur[i], cnt[i]) : 0;
    __syncthreads();
    #pragma unroll
    for(int i=0;i<16;i++){
        int e = s0 + i*256 + t;
        if(e < E) bdata[base[bk[i]] + off[i]] = pk[i];
    }
}

// fused per-bucket: LDS hist -> LDS scan -> rowptr slice -> LDS-cursor scatter
__global__ __launch_bounds__(256) void k_bfuse(const uint_t* __restrict__ bdata, const int* __restrict__ bbase,
                                               const int* __restrict__ gb, int* __restrict__ rp,
                                               int* __restrict__ col, int n, int NB, int E){
    __shared__ int h[256];
    __shared__ int sc[256];
    int b = blockIdx.x, t = threadIdx.x;
    int beg = bbase[b], cnt = gb[b];
    h[t] = 0; __syncthreads();
    for(int i=t;i<cnt;i+=256) atomicAdd(&h[bdata[beg+i] & 255], 1);
    __syncthreads();
    int v = h[t];
    sc[t] = v; __syncthreads();
    for(int o=1;o<256;o<<=1){
        int u = (t >= o) ? sc[t-o] : 0;
        __syncthreads();
        sc[t] += u;
        __syncthreads();
    }
    int excl = sc[t] - v;
    int node = (b<<BSH) + t;
    if(node < n) rp[node] = beg + excl;
    if(b == NB-1 && t == 255) rp[n] = E;
    __syncthreads();
    sc[t] = excl;           // per-node local cursor
    __syncthreads();
    for(int i=t;i<cnt;i+=256){
        uint_t e = bdata[beg+i];
        int pos = atomicAdd(&sc[e & 255], 1);
        col[beg + pos] = (int)(e >> 8);
    }
}

// ---------------- vn-group build: counting sort of nodes by hb ----------------
__global__ __launch_bounds__(256) void k_vcnt(const int* __restrict__ hb, int* __restrict__ vcnt, int n){
    __shared__ int h[HNUM];
    int t = threadIdx.x;
    if(t < HNUM) h[t] = 0;
    __syncthreads();
    for(int i = blockIdx.x*256 + t; i < n; i += gridDim.x*256) atomicAdd(&h[hb[i]], 1);
    __syncthreads();
    if(t < HNUM && h[t]) atomicAdd(&vcnt[t], h[t]);
}

__global__ __launch_bounds__(128) void k_vscan(const int* __restrict__ vcnt, int* __restrict__ vrp,
                                               int* __restrict__ vcur, int n){
    __shared__ int s[HNUM];
    int t = threadIdx.x;
    int v = vcnt[t];
    s[t] = v; __syncthreads();
    for(int o=1;o<HNUM;o<<=1){
        int u = (t >= o) ? s[t-o] : 0;
        __syncthreads();
        s[t] += u;
        __syncthreads();
    }
    int ex = s[t] - v;
    vrp[t] = ex; vcur[t] = ex;
    if(t == HNUM-1) vrp[HNUM] = n;
}

__global__ __launch_bounds__(256) void k_vbin(const int* __restrict__ hb, int* __restrict__ vcur,
                                              int* __restrict__ perm, int n){
    __shared__ int cnt[HNUM];
    __shared__ int base[HNUM];
    int t = threadIdx.x;
    if(t < HNUM) cnt[t] = 0;
    __syncthreads();
    int s0 = blockIdx.x*2048;
    int hv[8], off[8];
    #pragma unroll
    for(int i=0;i<8;i++){
        int nd = s0 + i*256 + t;
        if(nd < n){ hv[i] = hb[nd]; off[i] = atomicAdd(&cnt[hv[i]], 1); }
    }
    __syncthreads();
    if(t < HNUM) base[t] = cnt[t] ? atomicAdd(&vcur[t], cnt[t]) : 0;
    __syncthreads();
    #pragma unroll
    for(int i=0;i<8;i++){
        int nd = s0 + i*256 + t;
        if(nd < n) perm[base[hv[i]] + off[i]] = nd;
    }
}

// ---------------- one-time weight fragment pack + W@a precompute ----------------
__global__ __launch_bounds__(256) void k_wcvt(
    const float* __restrict__ W0, const float* __restrict__ as0, const float* __restrict__ ad0,
    const float* __restrict__ Wl, const float* __restrict__ asl, const float* __restrict__ adl,
    uint4* __restrict__ Wf3, float* __restrict__ waf3)
{
    __shared__ float wa[2][64];
    int L = blockIdx.x, t = threadIdx.x;
    const float* W  = (L==0) ? W0  : Wl  + (L-1)*HD*HD;
    const float* as = (L==0) ? as0 : asl + (L-1)*HD;
    const float* ad = (L==0) ? ad0 : adl + (L-1)*HD;
    if(t < 128){
        int sd = t>>6, k = t&63;
        const float* av = sd ? ad : as;
        float acc = 0.f;
        for(int c=0;c<HD;c++) acc = fmaf(W[k*HD+c], av[c], acc);
        wa[sd][k] = acc;
    }
    __syncthreads();
    for(int it = t; it < 512; it += 256){
        int lane = it&63, s = (it>>6)&1, tile = it>>7;
        int g = lane>>4, m = lane&15, c = tile*16 + m;
        ushort_t h[8];
        #pragma unroll
        for(int i=0;i<8;i++){
            int k = s*32 + g*4 + (i&3) + 16*(i>>2);
            h[i] = __half_as_ushort(__float2half_rn(W[k*HD + c]));
        }
        uint4 q;
        q.x = (uint_t)h[0] | ((uint_t)h[1]<<16);
        q.y = (uint_t)h[2] | ((uint_t)h[3]<<16);
        q.z = (uint_t)h[4] | ((uint_t)h[5]<<16);
        q.w = (uint_t)h[6] | ((uint_t)h[7]<<16);
        Wf3[(size_t)L*512 + (tile*2+s)*64 + lane] = q;
    }
    if(t < 128){
        int lane = t&63, sd = t>>6, g = lane>>4;
        #pragma unroll
        for(int j4=0;j4<4;j4++){
            float v[4];
            #pragma unroll
            for(int e=0;e<4;e++){
                int j = j4*4 + e;
                int k = (j>>3)*32 + g*4 + (j&3) + 16*((j>>2)&1);
                v[e] = wa[sd][k];
            }
            float* dstp = waf3 + ((size_t)L*8 + sd*4 + j4)*64*4 + lane*4;
            dstp[0]=v[0]; dstp[1]=v[1]; dstp[2]=v[2]; dstp[3]=v[3];
        }
    }
}

// ---------------- MFMA GEMM: 16 rows x 64 cols per wave ----------------
// Hw pair-layout: row dword w holds fp16 cols (32*(w>>4)+(w&15), same+16)
__global__ __launch_bounds__(256) void k_gemm(
    const float* __restrict__ IN, const float* __restrict__ addrow,
    const float* __restrict__ addtab, const int* __restrict__ hb,
    const uint4* __restrict__ Wf, const float* __restrict__ waf,
    uint_t* __restrict__ Hw, float* __restrict__ AS, float* __restrict__ AD,
    int n)
{
    __shared__ ushort_t sx[4][1024];
    int t = threadIdx.x, lane = t&63, wv = t>>6;
    int g = lane>>4, m = lane&15;
    ushort_t* sb = sx[wv];

    H8U B[8];
    #pragma unroll
    for(int f=0; f<8; f++){
        uint4 q = Wf[f*64 + lane];
        B[f].u[0]=q.x; B[f].u[1]=q.y; B[f].u[2]=q.z; B[f].u[3]=q.w;
    }
    vf4 wS[4], wD[4];
    #pragma unroll
    for(int j4=0;j4<4;j4++){
        const float* ps = waf + ((size_t)0*4 + j4)*256 + lane*4;
        const float* pd = waf + ((size_t)1*4 + j4)*256 + lane*4;
        wS[j4] = vf4{ps[0],ps[1],ps[2],ps[3]};
        wD[j4] = vf4{pd[0],pd[1],pd[2],pd[3]};
    }
    float ar0=0,ar1=0,ar2=0,ar3=0;
    if(addrow){
        const float* a = &addrow[m*4];
        ar0=a[0]; ar1=a[1]; ar2=a[2]; ar3=a[3];
    }

    int ntiles = (n + 15) >> 4;
    int wgid = (blockIdx.x*256 + t) >> 6;
    int nw = gridDim.x*4;
    for(int tile = wgid; tile < ntiles; tile += nw){
        int rb = tile*16;
        #pragma unroll
        for(int p=0;p<4;p++){
            int row = p*4 + g;
            int rowc = min(rb + row, n-1);
            float4 x4 = *(const float4*)&IN[(size_t)rowc*HD + m*4];
            if(addrow){ x4.x+=ar0; x4.y+=ar1; x4.z+=ar2; x4.w+=ar3; }
            if(addtab){
                int b = hb[rowc];
                float4 a4 = *(const float4*)&addtab[b*HD + m*4];
                x4.x+=a4.x; x4.y+=a4.y; x4.z+=a4.z; x4.w+=a4.w;
            }
            uint2 pq; pq.x = pk2(x4.x, x4.y); pq.y = pk2(x4.z, x4.w);
            int idx = (row*64 + m*4) ^ ((row&7)<<3);
            *(uint2*)&sb[idx] = pq;
        }
        int xr = (m&7)<<3;
        H8U A0, A1;
        {
            uint2 c0 = *(uint2*)&sb[(m*64 +  0 + g*4) ^ xr];
            uint2 c1 = *(uint2*)&sb[(m*64 + 16 + g*4) ^ xr];
            A0.u[0]=c0.x; A0.u[1]=c0.y; A0.u[2]=c1.x; A0.u[3]=c1.y;
            uint2 c2 = *(uint2*)&sb[(m*64 + 32 + g*4) ^ xr];
            uint2 c3 = *(uint2*)&sb[(m*64 + 48 + g*4) ^ xr];
            A1.u[0]=c2.x; A1.u[1]=c2.y; A1.u[2]=c3.x; A1.u[3]=c3.y;
        }
        float t1 = 0.f, t2 = 0.f;
        #pragma unroll
        for(int i=0;i<8;i++){
            float xv = (float)A0.v[i];
            t1 = fmaf(xv, wS[i>>2][i&3], t1);
            t2 = fmaf(xv, wD[i>>2][i&3], t2);
        }
        #pragma unroll
        for(int i=0;i<8;i++){
            float xv = (float)A1.v[i];
            t1 = fmaf(xv, wS[2+(i>>2)][i&3], t1);
            t2 = fmaf(xv, wD[2+(i>>2)][i&3], t2);
        }
        t1 += __shfl_xor(t1, 16, 64); t1 += __shfl_xor(t1, 32, 64);
        t2 += __shfl_xor(t2, 16, 64); t2 += __shfl_xor(t2, 32, 64);
        if(lane < 16 && rb + lane < n){ AS[rb+lane] = t1; AD[rb+lane] = t2; }
        vf4 z = {0.f,0.f,0.f,0.f};
        vf4 a0 = __builtin_amdgcn_mfma_f32_16x16x32_f16(A0.v, B[0].v, z, 0,0,0);
        a0     = __builtin_amdgcn_mfma_f32_16x16x32_f16(A1.v, B[1].v, a0, 0,0,0);
        vf4 a1 = __builtin_amdgcn_mfma_f32_16x16x32_f16(A0.v, B[2].v, z, 0,0,0);
        a1     = __builtin_amdgcn_mfma_f32_16x16x32_f16(A1.v, B[3].v, a1, 0,0,0);
        vf4 a2 = __builtin_amdgcn_mfma_f32_16x16x32_f16(A0.v, B[4].v, z, 0,0,0);
        a2     = __builtin_amdgcn_mfma_f32_16x16x32_f16(A1.v, B[5].v, a2, 0,0,0);
        vf4 a3 = __builtin_amdgcn_mfma_f32_16x16x32_f16(A0.v, B[6].v, z, 0,0,0);
        a3     = __builtin_amdgcn_mfma_f32_16x16x32_f16(A1.v, B[7].v, a3, 0,0,0);
        #pragma unroll
        for(int rr=0;rr<4;rr++){
            int row = rb + g*4 + rr;
            if(row < n){
                Hw[(size_t)row*32 + m]      = pk2(a0[rr], a1[rr]);
                Hw[(size_t)row*32 + 16 + m] = pk2(a2[rr], a3[rr]);
            }
        }
    }
}

// ---------------- GAT aggregate: quarter-wave per dst (4 dsts/wave) ----------------
__global__ __launch_bounds__(256) void k_agg(
    const uint_t* __restrict__ Hb, const float* __restrict__ AS, const float* __restrict__ AD,
    const int* __restrict__ rp, const int* __restrict__ col,
    const float* __restrict__ bias, float* __restrict__ OUT, int n)
{
    int t = threadIdx.x, lane = t & 63;
    int p = lane & 15;          // position within quarter
    int qb = lane & 48;         // quarter base lane (0,16,32,48)
    int w0 = 2*p;
    int c00 = 32*(w0>>4)+(w0&15), c01 = c00+16;
    int c10 = c00+1, c11 = c00+17;
    float b00 = bias[c00], b01 = bias[c01], b10 = bias[c10], b11 = bias[c11];
    int wv  = (blockIdx.x*256 + t) >> 6;
    int nwv = gridDim.x*4;
    for(int base = wv*4; base < n; base += nwv*4){
        int dq = min(base + (qb>>4), n-1);
        float ad = AD[dq];
        float wself = __expf(lrelu(AS[dq] + ad));
        uint2 hd = *(const uint2*)&Hb[(size_t)dq*32 + w0];
        float4 acc;
        acc.x = cvt_h(hd.x,0)*wself; acc.y = cvt_h(hd.x,16)*wself;
        acc.z = cvt_h(hd.y,0)*wself; acc.w = cvt_h(hd.y,16)*wself;
        float sacc = 0.f;
        int beg = rp[dq], end = rp[dq+1];
        int cnt = end - beg;
        int nit = (cnt + 15) >> 4;
        nit = max(nit, __shfl_xor(nit, 16, 64));
        nit = max(nit, __shfl_xor(nit, 32, 64));
        for(int it = 0; it < nit; it++){
            int j = beg + it*16 + p;
            bool valid = j < end;
            int sj = dq;
            if(cnt > 0) sj = col[valid ? j : end - 1];
            float wj = 0.f;
            if(valid) wj = __expf(lrelu(AS[sj] + ad));
            sacc += wj;
            int ccnt = cnt - it*16;
            ccnt = ccnt < 0 ? 0 : (ccnt > 16 ? 16 : ccnt);
            int emax = ccnt;
            emax = max(emax, __shfl_xor(emax, 16, 64));
            emax = max(emax, __shfl_xor(emax, 32, 64));
            int e = 0;
            for(; e + 4 <= emax; e += 4){
                float wq0 = __shfl(wj, qb+e,   64);
                float wq1 = __shfl(wj, qb+e+1, 64);
                float wq2 = __shfl(wj, qb+e+2, 64);
                float wq3 = __shfl(wj, qb+e+3, 64);
                int   sq0 = __shfl(sj, qb+e,   64);
                int   sq1 = __shfl(sj, qb+e+1, 64);
                int   sq2 = __shfl(sj, qb+e+2, 64);
                int   sq3 = __shfl(sj, qb+e+3, 64);
                uint2 v0 = *(const uint2*)&Hb[(size_t)sq0*32 + w0];
                uint2 v1 = *(const uint2*)&Hb[(size_t)sq1*32 + w0];
                uint2 v2 = *(const uint2*)&Hb[(size_t)sq2*32 + w0];
                uint2 v3 = *(const uint2*)&Hb[(size_t)sq3*32 + w0];
                acc.x = fmaf(wq0, cvt_h(v0.x,0),  acc.x);
                acc.y = fmaf(wq0, cvt_h(v0.x,16), acc.y);
                acc.z = fmaf(wq0, cvt_h(v0.y,0),  acc.z);
                acc.w = fmaf(wq0, cvt_h(v0.y,16), acc.w);
                acc.x = fmaf(wq1, cvt_h(v1.x,0),  acc.x);
                acc.y = fmaf(wq1, cvt_h(v1.x,16), acc.y);
                acc.z = fmaf(wq1, cvt_h(v1.y,0),  acc.z);
                acc.w = fmaf(wq1, cvt_h(v1.y,16), acc.w);
                acc.x = fmaf(wq2, cvt_h(v2.x,0),  acc.x);
                acc.y = fmaf(wq2, cvt_h(v2.x,16), acc.y);
                acc.z = fmaf(wq2, cvt_h(v2.y,0),  acc.z);
                acc.w = fmaf(wq2, cvt_h(v2.y,16), acc.w);
                acc.x = fmaf(wq3, cvt_h(v3.x,0),  acc.x);
                acc.y = fmaf(wq3, cvt_h(v3.x,16), acc.y);
                acc.z = fmaf(wq3, cvt_h(v3.y,0),  acc.z);
                acc.w = fmaf(wq3, cvt_h(v3.y,16), acc.w);
            }
            for(; e < emax; e++){
                float wq = __shfl(wj, qb+e, 64);
                int   sq = __shfl(sj, qb+e, 64);
                uint2 v = *(const uint2*)&Hb[(size_t)sq*32 + w0];
                acc.x = fmaf(wq, cvt_h(v.x,0),  acc.x);
                acc.y = fmaf(wq, cvt_h(v.x,16), acc.y);
                acc.z = fmaf(wq, cvt_h(v.y,0),  acc.z);
                acc.w = fmaf(wq, cvt_h(v.y,16), acc.w);
            }
        }
        sacc += __shfl_xor(sacc, 1, 64);
        sacc += __shfl_xor(sacc, 2, 64);
        sacc += __shfl_xor(sacc, 4, 64);
        sacc += __shfl_xor(sacc, 8, 64);
        float s = wself + sacc;
        float inv = 1.f/(s + 1e-16f);
        if(base + (qb>>4) < n){
            OUT[(size_t)dq*HD + c00] = fmaf(acc.x, inv, b00);
            OUT[(size_t)dq*HD + c01] = fmaf(acc.y, inv, b01);
            OUT[(size_t)dq*HD + c10] = fmaf(acc.z, inv, b10);
            OUT[(size_t)dq*HD + c11] = fmaf(acc.w, inv, b11);
        }
    }
}

// ---------------- vn segment sum: hb-grouped, pure register accumulation ----------------
__global__ __launch_bounds__(256) void k_vsum(const float* __restrict__ OUT, const int* __restrict__ perm,
                                              const int* __restrict__ vrp, float* __restrict__ vnS){
    int t = threadIdx.x, lane = t & 63, w = t >> 6;
    int g = blockIdx.x >> 3, sub = blockIdx.x & 7;
    int wig = sub*4 + w;                  // wave index in group: 0..31
    int beg = vrp[g], end = vrp[g+1];
    float a0=0.f, a1=0.f, a2=0.f, a3=0.f;
    int i = beg + wig;
    for(; i + 96 < end; i += 128){
        int p0 = perm[i], p1 = perm[i+32], p2 = perm[i+64], p3 = perm[i+96];
        a0 += OUT[(size_t)p0*HD + lane];
        a1 += OUT[(size_t)p1*HD + lane];
        a2 += OUT[(size_t)p2*HD + lane];
        a3 += OUT[(size_t)p3*HD + lane];
    }
    for(; i < end; i += 32) a0 += OUT[(size_t)perm[i]*HD + lane];
    float a = (a0+a1)+(a2+a3);
    unsafeAtomicAdd(&vnS[g*HD + lane], a);   // 32 contenders per address
}

// ---------------- vn update: one wave per vn row; LDS-broadcast MLPs ----------------
__global__ __launch_bounds__(64) void k_vn(
    const float* __restrict__ vnS, const float* __restrict__ vne,
    const float* __restrict__ W1, const float* __restrict__ B1,
    const float* __restrict__ W2, const float* __restrict__ B2,
    float* __restrict__ vnD)
{
    __shared__ float sx[HD];
    int lane = threadIdx.x;
    int r = blockIdx.x;                 // vn row 0..HNUM-1
    float ve = vne[lane];
    float a = vnS[r*HD + lane] + ve + ve;   // segsum + vn_direct0 + vn_root0
    for(int j=0;j<NMLP;j++){
        const float* w1 = W1 + j*HD*HD; const float* b1 = B1 + j*HD;
        const float* w2 = W2 + j*HD*HD; const float* b2 = B2 + j*HD;
        __syncthreads();
        sx[lane] = a;
        __syncthreads();
        float t = b1[lane];
        #pragma unroll
        for(int in=0;in<HD;in++) t = fmaf(sx[in], w1[in*HD + lane], t);
        t = fmaxf(t, 0.f);
        __syncthreads();
        sx[lane] = t;
        __syncthreads();
        float u = b2[lane];
        #pragma unroll
        for(int in=0;in<HD;in++) u = fmaf(sx[in], w2[in*HD + lane], u);
        a = fmaxf(u, 0.f);
    }
    vnD[r*HD + lane] = a;
}

extern "C" void kernel_launch(void* const* d_in, const int* in_sizes, int n_in,
                              void* d_out, int out_size, void* d_ws, size_t ws_size,
                              hipStream_t stream)
{
    const float* x   = (const float*)d_in[0];
    const int*   ei  = (const int*)d_in[1];
    const int*   hb  = (const int*)d_in[2];
    const float* W0  = (const float*)d_in[5];
    const float* as0 = (const float*)d_in[6];
    const float* ad0 = (const float*)d_in[7];
    const float* b0  = (const float*)d_in[8];
    const float* Wl  = (const float*)d_in[9];
    const float* asl = (const float*)d_in[10];
    const float* adl = (const float*)d_in[11];
    const float* bl  = (const float*)d_in[12];
    const float* vne = (const float*)d_in[13];
    const float* mW1 = (const float*)d_in[14];
    const float* mb1 = (const float*)d_in[15];
    const float* mW2 = (const float*)d_in[16];
    const float* mb2 = (const float*)d_in[17];

    int N = in_sizes[0]/HD;
    int E = in_sizes[1]/2;
    const int* src = ei;
    const int* dst = ei + E;
    int NB = (N + (1<<BSH) - 1) >> BSH;

    char* p = (char*)d_ws;
    float* f_h   = (float*)p; p += (size_t)N*HD*4;   // fp16 H (lower half) + CSR alias
    float* f_as  = (float*)p; p += (size_t)N*4;
    float* f_ad  = (float*)p; p += (size_t)N*4;
    float* f_vnD = (float*)p; p += HNUM*HD*4;
    float* f_vnS = (float*)p; p += HNUM*HD*4;        // zeroed with i_vcnt below
    int*   i_vcnt= (int*)p;   p += HNUM*4;
    int*   i_vrp = (int*)p;   p += (HNUM+1)*4;
    int*   i_vcur= (int*)p;   p += HNUM*4;
    int*   i_perm= (int*)p;   p += (size_t)N*4;
    int*   i_rp  = (int*)p;   p += (size_t)(N+1)*4;
    int*   i_gb  = (int*)p;   p += MAXNB*4;
    int*   i_bb  = (int*)p;   p += MAXNB*4;
    int*   i_gc  = (int*)p;   p += MAXNB*4;
    int*   i_col = (int*)p;   p += (size_t)E*4;
    uint4* Wf3   = (uint4*)p; p += 3*512*16;
    float* waf3  = (float*)p; p += 3*8*64*4*4;
    uint_t* bdata= (uint_t*)f_h;                      // alias: f_h not live during CSR build
    uint_t* Hw   = (uint_t*)f_h;                      // N*32 dwords = lower 12.8 MB

    float* outb = (float*)d_out;

    // one-time weight pack (3 blocks = 3 layers)
    k_wcvt<<<3, 256, 0, stream>>>(W0, as0, ad0, Wl, asl, adl, Wf3, waf3);

    hipMemsetAsync(i_gb, 0, MAXNB*4, stream);
    hipMemsetAsync(f_vnS, 0, HNUM*HD*4 + HNUM*4, stream);   // vnS + vcnt
    // edge CSR
    k_bcnt <<<512, 256, 0, stream>>>(dst, i_gb, E, NB);
    k_bscan<<<1, 512, 0, stream>>>(i_gb, i_bb, i_gc, NB);
    k_bin  <<<(E+EPB-1)/EPB, 256, 0, stream>>>(src, dst, i_gc, bdata, E, NB);
    k_bfuse<<<NB, 256, 0, stream>>>(bdata, i_bb, i_gb, i_rp, i_col, N, NB, E);
    // vn-group permutation (counting sort of nodes by hb)
    k_vcnt <<<128, 256, 0, stream>>>(hb, i_vcnt, N);
    k_vscan<<<1, 128, 0, stream>>>(i_vcnt, i_vrp, i_vcur, N);
    k_vbin <<<(N+2047)/2048, 256, 0, stream>>>(hb, i_vcur, i_perm, N);

    int ga = 4096;
    int gg = 768;
    // conv0: GAT(x, W0)
    k_gemm<<<gg, 256, 0, stream>>>(x, nullptr, nullptr, hb, Wf3, waf3, Hw, f_as, f_ad, N);
    k_agg <<<ga, 256, 0, stream>>>(Hw, f_as, f_ad, i_rp, i_col, b0, outb, N);
    // conv1: GAT(out0 + vn_emb, Wl[0])
    k_gemm<<<gg, 256, 0, stream>>>(outb, vne, nullptr, hb, Wf3 + 512, waf3 + 2048, Hw, f_as, f_ad, N);
    k_agg <<<ga, 256, 0, stream>>>(Hw, f_as, f_ad, i_rp, i_col, bl, outb, N);
    // vn update: vnD = MLPs(segsum(out1) + 2*vne)  -- grouped register sum
    k_vsum<<<HNUM*8, 256, 0, stream>>>(outb, i_perm, i_vrp, f_vnS);
    k_vn  <<<HNUM, 64, 0, stream>>>(f_vnS, vne, mW1, mb1, mW2, mb2, f_vnD);
    // conv2: GAT(out1 + vnD[hb], Wl[1]) -> final output
    k_gemm<<<gg, 256, 0, stream>>>(outb, nullptr, f_vnD, hb, Wf3 + 1024, waf3 + 4096, Hw, f_as, f_ad, N);
    k_agg <<<ga, 256, 0, stream>>>(Hw, f_as, f_ad, i_rp, i_col, bl + HD, outb, N);
}